// Round 2
// baseline (6047.111 us; speedup 1.0000x reference)
//
#include <hip/hip_runtime.h>
#include <hip/hip_bf16.h>
#include <math.h>

#define H_ 1024
#define NH_ 16
#define HD_ 64
#define I_ 4096
#define E_ 8
#define B_ 2
#define S_ 2048
#define T_ 4096

#define MAXSLOTS 9216   // 2*T + 8*128 pad
#define MAXTILES 72     // MAXSLOTS/128

typedef __attribute__((ext_vector_type(8))) short short8v;
typedef __attribute__((ext_vector_type(4))) float f32x4;

#define GLOAD16(g, l) __builtin_amdgcn_global_load_lds((const __attribute__((address_space(1))) void*)(g), (__attribute__((address_space(3))) void*)(l), 16, 0, 0)

static __device__ inline unsigned short f2bf(float x) {
    __hip_bfloat16 h = __float2bfloat16(x);
    unsigned short u;
    __builtin_memcpy(&u, &h, 2);
    return u;
}

// ---------------- zero ----------------
__global__ void zero_kernel(float* __restrict__ p, int n) {
    int i = blockIdx.x * blockDim.x + threadIdx.x;
    if (i < n) p[i] = 0.f;
}

// ---------------- fp32 GEMM: 64x64 tile, 128 thr, 8x4 acc ----------------
// MODE 0: C = A@B ; MODE 1: C = A@B + bias
template<int MODE>
__global__ __launch_bounds__(128) void gemm_f32(
    const float* __restrict__ A, const float* __restrict__ Bw,
    float* __restrict__ C, const float* __restrict__ bias, int N, int K)
{
    __shared__ float As[16][68];
    __shared__ float Bs[16][68];
    const int bx = blockIdx.x, by = blockIdx.y;
    const int tid = threadIdx.x;
    const int tx = tid & 15, ty = tid >> 4;   // tx 0..15 (n*4), ty 0..7 (m*8)

    float acc[8][4];
    #pragma unroll
    for (int i=0;i<8;i++)
        #pragma unroll
        for (int j=0;j<4;j++) acc[i][j]=0.f;

    for (int k0 = 0; k0 < K; k0 += 16) {
        __syncthreads();
        #pragma unroll
        for (int t=0;t<8;t++) {
            int lin = t*128 + tid;
            int m = lin >> 4, kk = lin & 15;
            As[kk][m] = A[(size_t)(by*64 + m)*K + k0 + kk];
        }
        #pragma unroll
        for (int t=0;t<8;t++) {
            int lin = t*128 + tid;
            int kk = lin >> 6, n = lin & 63;
            Bs[kk][n] = Bw[(size_t)(k0+kk)*N + bx*64 + n];
        }
        __syncthreads();
        #pragma unroll
        for (int kk=0; kk<16; ++kk) {
            float a8[8], b4[4];
            *(float4*)&a8[0] = *(const float4*)&As[kk][ty*8];
            *(float4*)&a8[4] = *(const float4*)&As[kk][ty*8+4];
            *(float4*)&b4[0] = *(const float4*)&Bs[kk][tx*4];
            #pragma unroll
            for (int i=0;i<8;i++)
                #pragma unroll
                for (int j=0;j<4;j++)
                    acc[i][j] = fmaf(a8[i], b4[j], acc[i][j]);
        }
    }

    #pragma unroll
    for (int i=0;i<8;i++) {
        int row = by*64 + ty*8 + i;
        int col = bx*64 + tx*4;
        float4 v;
        v.x = acc[i][0]; v.y = acc[i][1]; v.z = acc[i][2]; v.w = acc[i][3];
        if (MODE == 1) {
            v.x += bias[col]; v.y += bias[col+1]; v.z += bias[col+2]; v.w += bias[col+3];
        }
        *(float4*)&C[(size_t)row*N + col] = v;
    }
}

// ---------------- transpose + f32->bf16: in [K][N] -> out [N][K] ----------------
__global__ __launch_bounds__(256) void transpose_bf16(
    const float* __restrict__ in, __hip_bfloat16* __restrict__ outp, int K, int N)
{
    __shared__ float t[64][65];
    size_t eoff = (size_t)blockIdx.z * (size_t)K * (size_t)N;
    int k0 = blockIdx.y*64, n0 = blockIdx.x*64;
    int tid = threadIdx.x;
    #pragma unroll
    for (int it=0; it<16; ++it) {
        int lin = it*256 + tid;
        int r = lin >> 6, c = lin & 63;
        t[r][c] = in[eoff + (size_t)(k0+r)*N + n0 + c];
    }
    __syncthreads();
    #pragma unroll
    for (int it=0; it<16; ++it) {
        int lin = it*256 + tid;
        int r = lin >> 6, c = lin & 63;   // r = n-local, c = k-local
        outp[eoff + (size_t)(n0+r)*K + k0 + c] = __float2bfloat16(t[c][r]);
    }
}

// ---------------- MFMA MoE GEMM: 128x128 tile, BK=64, 4 waves ----------------
// MODE 2: y1 = gelu(gather(hs_b) @ W1t^T)  -> bf16
// MODE 3: moe_out[tok] += w * (y1 @ W2t^T) -> f32 atomic
// Bt is B^T per expert: [N][K] bf16.
template<int MODE, bool PE>
__global__ __launch_bounds__(256) void moe_mfma(
    const __hip_bfloat16* __restrict__ A,
    const __hip_bfloat16* __restrict__ Bt,
    __hip_bfloat16* __restrict__ y1,
    float* __restrict__ moe_out,
    const int* __restrict__ slot_token,
    const float* __restrict__ slot_w,
    const int* __restrict__ tile_expert,
    const int* __restrict__ cnt_ptr,     // PE: &cnt_pad[e] ; FULL: &ntiles_tot
    const int* __restrict__ base_ptr,    // PE: &base[e]
    int N, int K)
{
    const int tid = threadIdx.x;
    const int w = tid >> 6, lane = tid & 63;
    const int bx = blockIdx.x;

    int slot0, y1row0;
    const __hip_bfloat16* Bp;
    if (PE) {
        int tloc = blockIdx.y;
        if ((tloc << 7) >= *cnt_ptr) return;
        slot0 = *base_ptr + (tloc << 7);
        y1row0 = tloc << 7;
        Bp = Bt;
    } else {
        int gt = blockIdx.y;
        if (gt >= *cnt_ptr) return;
        int e = tile_expert[gt];
        Bp = Bt + (size_t)e * (size_t)K * (size_t)N;
        slot0 = gt << 7;
        y1row0 = gt << 7;
    }

    __shared__ __align__(16) char smem[32768];  // A @0 (16KB), B @16384 (16KB)

    const int laneg = lane >> 3;            // 0..7 (row within 8-row group)
    const int k2sw = ((lane & 7) ^ laneg) << 4;  // inverse-swizzled k2 byte offset

    // token gather rows (MODE 2) / A row bases
    int tokq[4];
    if (MODE == 2) {
        #pragma unroll
        for (int qq=0;qq<4;qq++) {
            int t0 = slot_token[slot0 + (w*4+qq)*8 + laneg];
            tokq[qq] = t0 < 0 ? 0 : t0;
        }
    }

    f32x4 acc[4][4];
    #pragma unroll
    for (int m=0;m<4;m++)
        #pragma unroll
        for (int n=0;n<4;n++) acc[m][n] = (f32x4){0.f,0.f,0.f,0.f};

    const int l15 = lane & 15;
    const int l4  = lane >> 4;      // 0..3
    const int wr = w >> 1, wc = w & 1;

    for (int k0 = 0; k0 < K; k0 += 64) {
        __syncthreads();
        // stage A tile: rows 0..127, k2 logical 0..127 bytes
        #pragma unroll
        for (int qq=0;qq<4;qq++) {
            const char* ga;
            if (MODE == 2) {
                ga = (const char*)A + (((size_t)tokq[qq])*K + k0)*2 + k2sw;
            } else {
                int row = y1row0 + (w*4+qq)*8 + laneg;
                ga = (const char*)A + ((size_t)row*K + k0)*2 + k2sw;
            }
            GLOAD16(ga, smem + (w*4+qq)*1024);
        }
        // stage B^T tile
        #pragma unroll
        for (int qq=0;qq<4;qq++) {
            int row = bx*128 + (w*4+qq)*8 + laneg;
            const char* gb = (const char*)Bp + ((size_t)row*K + k0)*2 + k2sw;
            GLOAD16(gb, smem + 16384 + (w*4+qq)*1024);
        }
        __syncthreads();

        short8v a_frag[4][2], b_frag[4][2];
        #pragma unroll
        for (int m=0;m<4;m++) {
            int row = wr*64 + m*16 + l15;
            int rb = row << 7;
            #pragma unroll
            for (int s=0;s<2;s++) {
                int off = rb + ((s*64 + (l4<<4)) ^ ((row&7)<<4));
                a_frag[m][s] = *(const short8v*)(smem + off);
            }
        }
        #pragma unroll
        for (int n=0;n<4;n++) {
            int row = wc*64 + n*16 + l15;
            int rb = row << 7;
            #pragma unroll
            for (int s=0;s<2;s++) {
                int off = rb + ((s*64 + (l4<<4)) ^ ((row&7)<<4));
                b_frag[n][s] = *(const short8v*)(smem + 16384 + off);
            }
        }
        #pragma unroll
        for (int m=0;m<4;m++)
            #pragma unroll
            for (int n=0;n<4;n++) {
                acc[m][n] = __builtin_amdgcn_mfma_f32_16x16x32_bf16(a_frag[m][0], b_frag[n][0], acc[m][n], 0, 0, 0);
                acc[m][n] = __builtin_amdgcn_mfma_f32_16x16x32_bf16(a_frag[m][1], b_frag[n][1], acc[m][n], 0, 0, 0);
            }
    }

    // epilogue: D col = lane&15, row = (lane>>4)*4 + j
    #pragma unroll
    for (int m=0;m<4;m++) {
        #pragma unroll
        for (int j=0;j<4;j++) {
            int orow = wr*64 + m*16 + l4*4 + j;
            if (MODE == 3) {
                int slot = slot0 + orow;
                int tok = slot_token[slot];
                if (tok < 0) continue;
                float sw = slot_w[slot];
                #pragma unroll
                for (int n=0;n<4;n++) {
                    int ocol = bx*128 + wc*64 + n*16 + l15;
                    atomicAdd(&moe_out[(size_t)tok*H_ + ocol], sw * acc[m][n][j]);
                }
            } else {
                #pragma unroll
                for (int n=0;n<4;n++) {
                    int ocol = bx*128 + wc*64 + n*16 + l15;
                    float val = acc[m][n][j];
                    float g = 0.5f*val*(1.f + erff(val*0.70710678118654752f));
                    y1[(size_t)(y1row0 + orow)*N + ocol] = __float2bfloat16(g);
                }
            }
        }
    }
}

// ---------------- RoPE (in-place on q,k; fp32) ----------------
__global__ void rope_kernel(float* __restrict__ q, float* __restrict__ k) {
    int idx = blockIdx.x * blockDim.x + threadIdx.x;  // T*NH*32
    int i = idx & 31;
    int n = (idx >> 5) & (NH_-1);
    int t = idx >> 9;
    int pos = t & (S_ - 1);
    float inv = powf(10000.f, -((float)(2*i) / 64.f));
    float ang = (float)pos * inv;
    float c = cosf(ang), s = sinf(ang);
    size_t base = (size_t)t*H_ + (size_t)n*64;
    float q1 = q[base+i], q2 = q[base+i+32];
    q[base+i]    = q1*c - q2*s;
    q[base+i+32] = q2*c + q1*s;
    float k1 = k[base+i], k2 = k[base+i+32];
    k[base+i]    = k1*c - k2*s;
    k[base+i+32] = k2*c + k1*s;
}

// ---------------- attention: flash-style, 32 q rows/block, fp32 ----------------
__global__ __launch_bounds__(256) void attn_kernel(
    const float* __restrict__ q, const float* __restrict__ k,
    const float* __restrict__ v, float* __restrict__ ctx)
{
    const int qt = blockIdx.x;
    const int n  = blockIdx.y;
    const int b  = blockIdx.z;
    const int tid = threadIdx.x;
    const int w = tid >> 6;
    const int lane = tid & 63;

    __shared__ float Kt[64*65];          // [d][j]
    __shared__ float Vt[64*65];          // [j][d]
    __shared__ float q_s[4][8][64];
    __shared__ float p_s[4][8][64];

    const size_t headoff = (size_t)b*S_*H_ + (size_t)n*64;

    float mrun[8], lrun[8], acc[8];
    #pragma unroll
    for (int r=0;r<8;r++) {
        int qrow = qt*32 + w*8 + r;
        q_s[w][r][lane] = q[headoff + (size_t)qrow*H_ + lane];
        mrun[r] = -1e30f; lrun[r] = 0.f; acc[r] = 0.f;
    }

    for (int kt=0; kt<S_/64; ++kt) {
        __syncthreads();
        #pragma unroll
        for (int it=0; it<16; ++it) {
            int lin = it*256 + tid;
            int r = lin >> 6, c = lin & 63;
            size_t g = headoff + (size_t)(kt*64+r)*H_ + c;
            Kt[c*65 + r] = k[g];
            Vt[r*65 + c] = v[g];
        }
        __syncthreads();

        float s8[8] = {0,0,0,0,0,0,0,0};
        #pragma unroll
        for (int d4=0; d4<16; ++d4) {
            float kv[4];
            #pragma unroll
            for (int dd=0; dd<4; ++dd) kv[dd] = Kt[(d4*4+dd)*65 + lane];
            #pragma unroll
            for (int r=0;r<8;r++) {
                const float4 qv = *(const float4*)&q_s[w][r][d4*4];
                s8[r] = fmaf(qv.x, kv[0], fmaf(qv.y, kv[1], fmaf(qv.z, kv[2], fmaf(qv.w, kv[3], s8[r]))));
            }
        }
        float alpha[8];
        #pragma unroll
        for (int r=0;r<8;r++) {
            float sv = s8[r] * 0.125f;
            float mt = sv;
            #pragma unroll
            for (int off=32; off; off>>=1) mt = fmaxf(mt, __shfl_xor(mt, off));
            float mnew = fmaxf(mrun[r], mt);
            float pv = __expf(sv - mnew);
            float ps = pv;
            #pragma unroll
            for (int off=32; off; off>>=1) ps += __shfl_xor(ps, off);
            alpha[r] = __expf(mrun[r] - mnew);
            lrun[r] = lrun[r]*alpha[r] + ps;
            mrun[r] = mnew;
            p_s[w][r][lane] = pv;
        }
        // p_s is wave-private: in-wave LDS RAW ordering suffices, no barrier

        float add[8] = {0,0,0,0,0,0,0,0};
        #pragma unroll
        for (int j4=0; j4<16; ++j4) {
            float vv[4];
            #pragma unroll
            for (int jj=0; jj<4; ++jj) vv[jj] = Vt[(j4*4+jj)*65 + lane];
            #pragma unroll
            for (int r=0;r<8;r++) {
                const float4 pv4 = *(const float4*)&p_s[w][r][j4*4];
                add[r] = fmaf(pv4.x, vv[0], fmaf(pv4.y, vv[1], fmaf(pv4.z, vv[2], fmaf(pv4.w, vv[3], add[r]))));
            }
        }
        #pragma unroll
        for (int r=0;r<8;r++) acc[r] = acc[r]*alpha[r] + add[r];
    }
    #pragma unroll
    for (int r=0;r<8;r++) {
        int qrow = qt*32 + w*8 + r;
        ctx[headoff + (size_t)qrow*H_ + lane] = acc[r] / lrun[r];
    }
}

// ---------------- layernorm (residual fused, optional bf16 out) ----------------
__global__ __launch_bounds__(256) void ln_kernel(
    const float* __restrict__ a, const float* __restrict__ res,
    const float* __restrict__ g, const float* __restrict__ beta,
    float* __restrict__ out, __hip_bfloat16* __restrict__ outb)
{
    int row = blockIdx.x, tid = threadIdx.x;
    const float4 va = ((const float4*)(a + (size_t)row*H_))[tid];
    const float4 vr = ((const float4*)(res + (size_t)row*H_))[tid];
    float x0=va.x+vr.x, x1=va.y+vr.y, x2=va.z+vr.z, x3=va.w+vr.w;
    float s  = x0+x1+x2+x3;
    float ss = x0*x0 + x1*x1 + x2*x2 + x3*x3;
    #pragma unroll
    for (int off=32; off; off>>=1) { s += __shfl_xor(s, off); ss += __shfl_xor(ss, off); }
    __shared__ float red[8];
    if ((tid&63)==0) { red[tid>>6]=s; red[4+(tid>>6)]=ss; }
    __syncthreads();
    if (tid==0) { red[0]=red[0]+red[1]+red[2]+red[3]; red[4]=red[4]+red[5]+red[6]+red[7]; }
    __syncthreads();
    float mu  = red[0] * (1.f/H_);
    float var = red[4] * (1.f/H_) - mu*mu;
    float rs = rsqrtf(fmaxf(var, 0.f) + 1e-12f);
    const float4 vg = ((const float4*)g)[tid];
    const float4 vb = ((const float4*)beta)[tid];
    float4 vo;
    vo.x = (x0-mu)*rs*vg.x + vb.x;
    vo.y = (x1-mu)*rs*vg.y + vb.y;
    vo.z = (x2-mu)*rs*vg.z + vb.z;
    vo.w = (x3-mu)*rs*vg.w + vb.w;
    ((float4*)(out + (size_t)row*H_))[tid] = vo;
    if (outb) {
        unsigned int p0 = (unsigned)f2bf(vo.x) | ((unsigned)f2bf(vo.y) << 16);
        unsigned int p1 = (unsigned)f2bf(vo.z) | ((unsigned)f2bf(vo.w) << 16);
        ((uint2*)(outb + (size_t)row*H_))[tid] = make_uint2(p0, p1);
    }
}

// ---------------- router ----------------
__global__ __launch_bounds__(256) void router_kernel(
    const float* __restrict__ hs, const float* __restrict__ Wg,
    int* __restrict__ tok_e, float* __restrict__ tok_w,
    int* __restrict__ counts, float* __restrict__ P_sum)
{
    int t = blockIdx.x*4 + (threadIdx.x >> 6);
    int lane = threadIdx.x & 63;
    const float* row = hs + (size_t)t * H_;
    float acc[E_];
    #pragma unroll
    for (int e=0;e<E_;e++) acc[e]=0.f;
    for (int it=0; it<16; ++it) {
        int i = it*64 + lane;
        float xv = row[i];
        const float* wg = Wg + (size_t)i*E_;
        #pragma unroll
        for (int e=0;e<E_;e++) acc[e] = fmaf(xv, wg[e], acc[e]);
    }
    #pragma unroll
    for (int e=0;e<E_;e++) {
        float vv = acc[e];
        #pragma unroll
        for (int off=32; off; off>>=1) vv += __shfl_xor(vv, off);
        acc[e] = vv;
    }
    if (lane==0) {
        float mx = acc[0];
        #pragma unroll
        for (int e=1;e<E_;e++) mx = fmaxf(mx, acc[e]);
        float p[E_], se=0.f;
        #pragma unroll
        for (int e=0;e<E_;e++){ p[e] = expf(acc[e]-mx); se += p[e]; }
        float isv = 1.f/se;
        #pragma unroll
        for (int e=0;e<E_;e++){ p[e]*=isv; atomicAdd(&P_sum[e], p[e]); }
        int e1=0;
        #pragma unroll
        for (int e=1;e<E_;e++) if (p[e] > p[e1]) e1=e;
        int e2 = (e1==0)?1:0;
        #pragma unroll
        for (int e=0;e<E_;e++) if (e!=e1 && p[e] > p[e2]) e2=e;
        float w1=p[e1], w2=p[e2], si=1.f/(w1+w2);
        tok_e[t*2]=e1; tok_e[t*2+1]=e2;
        tok_w[t*2]=w1*si; tok_w[t*2+1]=w2*si;
        atomicAdd(&counts[e1],1); atomicAdd(&counts[e2],1);
    }
}

__global__ void router_finalize(
    const int* __restrict__ counts, const float* __restrict__ P_sum,
    int* __restrict__ base, int* __restrict__ cursor,
    int* __restrict__ cnt_pad, int* __restrict__ ntiles,
    int* __restrict__ slot_token, int* __restrict__ tile_expert,
    float* __restrict__ aux_out)
{
    __shared__ int sbase[E_+1];
    if (threadIdx.x == 0) {
        int bacc = 0;
        float aux = 0.f;
        for (int e=0;e<E_;e++) {
            sbase[e] = bacc; base[e] = bacc;
            int cp = (counts[e] + 127) & ~127;
            cnt_pad[e] = cp;
            bacc += cp;
            cursor[e] = 0;
            aux += ((float)counts[e]/(float)T_) * (P_sum[e]/(float)T_);
        }
        sbase[E_] = bacc;
        *ntiles = bacc >> 7;
        *aux_out = (float)E_ * aux;
    }
    __syncthreads();
    for (int sIdx = (int)threadIdx.x; sIdx < MAXSLOTS; sIdx += (int)blockDim.x)
        slot_token[sIdx] = -1;
    for (int tt = (int)threadIdx.x; tt < MAXTILES; tt += (int)blockDim.x) {
        int s = tt*128;
        int e = E_-1;
        for (int qe=0; qe<E_; ++qe) if (s < sbase[qe+1]) { e = qe; break; }
        tile_expert[tt] = e;
    }
}

__global__ void scatter_slots(
    const int* __restrict__ tok_e, const float* __restrict__ tok_w,
    const int* __restrict__ base, int* __restrict__ cursor,
    int* __restrict__ slot_token, float* __restrict__ slot_w)
{
    int t = blockIdx.x*blockDim.x + threadIdx.x;
    if (t >= T_) return;
    #pragma unroll
    for (int j=0;j<2;j++) {
        int e = tok_e[t*2+j];
        int pos = atomicAdd(&cursor[e], 1);
        int s = base[e] + pos;
        slot_token[s] = t;
        slot_w[s] = tok_w[t*2+j];
    }
}

extern "C" void kernel_launch(void* const* d_in, const int* in_sizes, int n_in,
                              void* d_out, int out_size, void* d_ws, size_t ws_size,
                              hipStream_t stream)
{
    const float* x    = (const float*)d_in[0];
    const float* Wq   = (const float*)d_in[1];
    const float* Wk   = (const float*)d_in[2];
    const float* Wv   = (const float*)d_in[3];
    const float* Wd   = (const float*)d_in[4];
    const float* bd   = (const float*)d_in[5];
    const float* ln1g = (const float*)d_in[6];
    const float* ln1b = (const float*)d_in[7];
    const float* Wg   = (const float*)d_in[8];
    const float* W1   = (const float*)d_in[9];
    const float* W2   = (const float*)d_in[10];
    const float* ln2g = (const float*)d_in[11];
    const float* ln2b = (const float*)d_in[12];
    float* out = (float*)d_out;

    float* f0 = (float*)d_ws;
    const size_t M1 = 1u << 20;
    float* qb   = f0;            // q -> attn_out
    float* kb   = f0 + 4*M1;     // k -> hs
    float* vb   = f0 + 8*M1;     // v -> moe_out
    float* ctxb = f0 + 12*M1;
    __hip_bfloat16* hs_b = (__hip_bfloat16*)(f0 + 16*M1);   // 4M bf16

    float* misc = f0 + 18*M1;
    int*   misc_i = (int*)misc;
    int*   tok_e   = misc_i;                 // 8192
    float* tok_w   = misc + 8192;            // 8192
    int*   slot_tok= misc_i + 16384;         // 9216
    float* slot_w  = misc + 25600;           // 9216
    int*   counts  = misc_i + 34816;         // 8
    float* P_sum   = misc + 34824;           // 8
    int*   cursor  = misc_i + 34832;         // 8
    int*   basep   = misc_i + 34840;         // 8
    int*   cnt_pad = misc_i + 34848;         // 8
    int*   ntiles  = misc_i + 34856;         // 1
    int*   tile_ex = misc_i + 34857;         // 72

    float* wreg = f0 + 18*M1 + 65536;
    const bool FULL = ws_size >= (size_t)300*1024*1024;

    dim3 blk(256);
    dim3 blk128(128);

    // QKV projections (fp32)
    gemm_f32<0><<<dim3(H_/64, T_/64), blk128, 0, stream>>>(x, Wq, qb, nullptr, H_, H_);
    gemm_f32<0><<<dim3(H_/64, T_/64), blk128, 0, stream>>>(x, Wk, kb, nullptr, H_, H_);
    gemm_f32<0><<<dim3(H_/64, T_/64), blk128, 0, stream>>>(x, Wv, vb, nullptr, H_, H_);

    rope_kernel<<<(T_*NH_*32)/256, blk, 0, stream>>>(qb, kb);

    attn_kernel<<<dim3(S_/32, NH_, B_), blk, 0, stream>>>(qb, kb, vb, ctxb);

    // attn_out = ctx@Wd + bd (into q buffer); then moe_out (v buffer) can be zeroed
    gemm_f32<1><<<dim3(H_/64, T_/64), blk128, 0, stream>>>(ctxb, Wd, qb, bd, H_, H_);

    zero_kernel<<<(T_*H_)/256, blk, 0, stream>>>(vb, T_*H_);
    zero_kernel<<<1, blk, 0, stream>>>(misc + 34816, 16);

    // hs = LN1(attn_out + x) -> kb (f32) + hs_b (bf16)
    ln_kernel<<<T_, blk, 0, stream>>>(qb, x, ln1g, ln1b, kb, hs_b);

    router_kernel<<<T_/4, blk, 0, stream>>>(kb, Wg, tok_e, tok_w, counts, P_sum);
    router_finalize<<<1, blk, 0, stream>>>(counts, P_sum, basep, cursor, cnt_pad, ntiles,
                                           slot_tok, tile_ex, out + (size_t)T_*H_);
    scatter_slots<<<T_/256, blk, 0, stream>>>(tok_e, tok_w, basep, cursor, slot_tok, slot_w);

    if (FULL) {
        // wreg: W1t 16M f32 | W2t 16M | y1 (72*128*4096 bf16 = 18.875M f32 ?? exactly 18,874,368 floats)
        __hip_bfloat16* W1t = (__hip_bfloat16*)wreg;
        __hip_bfloat16* W2t = (__hip_bfloat16*)(wreg + 16*M1);
        __hip_bfloat16* y1  = (__hip_bfloat16*)(wreg + 32*M1);
        transpose_bf16<<<dim3(I_/64, H_/64, E_), blk, 0, stream>>>(W1, W1t, H_, I_);
        transpose_bf16<<<dim3(H_/64, I_/64, E_), blk, 0, stream>>>(W2, W2t, I_, H_);
        moe_mfma<2,false><<<dim3(I_/128, MAXTILES), blk, 0, stream>>>(
            hs_b, W1t, y1, nullptr, slot_tok, slot_w, tile_ex, ntiles, nullptr, I_, H_);
        moe_mfma<3,false><<<dim3(H_/128, MAXTILES), blk, 0, stream>>>(
            y1, W2t, nullptr, vb, slot_tok, slot_w, tile_ex, ntiles, nullptr, H_, I_);
    } else {
        __hip_bfloat16* w1t = (__hip_bfloat16*)wreg;                 // 2M f32 = 4M bf16
        __hip_bfloat16* w2t = (__hip_bfloat16*)(wreg + 2*M1);        // 2M f32
        __hip_bfloat16* y1  = (__hip_bfloat16*)(wreg + 4*M1);        // 8M f32 = 32 tiles
        for (int e=0; e<E_; ++e) {
            transpose_bf16<<<dim3(I_/64, H_/64, 1), blk, 0, stream>>>(W1 + (size_t)e*H_*I_, w1t, H_, I_);
            moe_mfma<2,true><<<dim3(I_/128, 32), blk, 0, stream>>>(
                hs_b, w1t, y1, nullptr, slot_tok, slot_w, nullptr, cnt_pad+e, basep+e, I_, H_);
            transpose_bf16<<<dim3(H_/64, I_/64, 1), blk, 0, stream>>>(W2 + (size_t)e*I_*H_, w2t, I_, H_);
            moe_mfma<3,true><<<dim3(H_/128, 32), blk, 0, stream>>>(
                y1, w2t, nullptr, vb, slot_tok, slot_w, nullptr, cnt_pad+e, basep+e, H_, I_);
        }
    }

    // out = LN2(hs + moe_out)
    ln_kernel<<<T_, blk, 0, stream>>>(vb, kb, ln2g, ln2b, out, nullptr);
}

// Round 3
// 2802.593 us; speedup vs baseline: 2.1577x; 2.1577x over previous
//
#include <hip/hip_runtime.h>
#include <hip/hip_bf16.h>
#include <math.h>

#define H_ 1024
#define NH_ 16
#define HD_ 64
#define I_ 4096
#define E_ 8
#define B_ 2
#define S_ 2048
#define T_ 4096

#define MAXSLOTS 9216   // 2*T + 8*128 pad
#define MAXTILES 72     // MAXSLOTS/128

typedef __attribute__((ext_vector_type(8))) short short8v;
typedef __attribute__((ext_vector_type(4))) float f32x4;

#define GLOAD16(g, l) __builtin_amdgcn_global_load_lds((const __attribute__((address_space(1))) void*)(g), (__attribute__((address_space(3))) void*)(l), 16, 0, 0)

static __device__ inline unsigned short f2bf(float x) {
    __hip_bfloat16 h = __float2bfloat16(x);
    unsigned short u;
    __builtin_memcpy(&u, &h, 2);
    return u;
}

// ---------------- zero ----------------
__global__ void zero_kernel(float* __restrict__ p, int n) {
    int i = blockIdx.x * blockDim.x + threadIdx.x;
    if (i < n) p[i] = 0.f;
}

// ---------------- fp32 GEMM: 64x64 tile, 128 thr, 8x4 acc ----------------
// MODE 0: C = A@B ; MODE 1: C = A@B + bias
template<int MODE>
__global__ __launch_bounds__(128) void gemm_f32(
    const float* __restrict__ A, const float* __restrict__ Bw,
    float* __restrict__ C, const float* __restrict__ bias, int N, int K)
{
    __shared__ float As[16][68];
    __shared__ float Bs[16][68];
    const int bx = blockIdx.x, by = blockIdx.y;
    const int tid = threadIdx.x;
    const int tx = tid & 15, ty = tid >> 4;   // tx 0..15 (n*4), ty 0..7 (m*8)

    float acc[8][4];
    #pragma unroll
    for (int i=0;i<8;i++)
        #pragma unroll
        for (int j=0;j<4;j++) acc[i][j]=0.f;

    for (int k0 = 0; k0 < K; k0 += 16) {
        __syncthreads();
        #pragma unroll
        for (int t=0;t<8;t++) {
            int lin = t*128 + tid;
            int m = lin >> 4, kk = lin & 15;
            As[kk][m] = A[(size_t)(by*64 + m)*K + k0 + kk];
        }
        #pragma unroll
        for (int t=0;t<8;t++) {
            int lin = t*128 + tid;
            int kk = lin >> 6, n = lin & 63;
            Bs[kk][n] = Bw[(size_t)(k0+kk)*N + bx*64 + n];
        }
        __syncthreads();
        #pragma unroll
        for (int kk=0; kk<16; ++kk) {
            float a8[8], b4[4];
            *(float4*)&a8[0] = *(const float4*)&As[kk][ty*8];
            *(float4*)&a8[4] = *(const float4*)&As[kk][ty*8+4];
            *(float4*)&b4[0] = *(const float4*)&Bs[kk][tx*4];
            #pragma unroll
            for (int i=0;i<8;i++)
                #pragma unroll
                for (int j=0;j<4;j++)
                    acc[i][j] = fmaf(a8[i], b4[j], acc[i][j]);
        }
    }

    #pragma unroll
    for (int i=0;i<8;i++) {
        int row = by*64 + ty*8 + i;
        int col = bx*64 + tx*4;
        float4 v;
        v.x = acc[i][0]; v.y = acc[i][1]; v.z = acc[i][2]; v.w = acc[i][3];
        if (MODE == 1) {
            v.x += bias[col]; v.y += bias[col+1]; v.z += bias[col+2]; v.w += bias[col+3];
        }
        *(float4*)&C[(size_t)row*N + col] = v;
    }
}

// ---------------- transpose + f32->bf16: in [K][N] -> out [N][K] ----------------
__global__ __launch_bounds__(256) void transpose_bf16(
    const float* __restrict__ in, __hip_bfloat16* __restrict__ outp, int K, int N)
{
    __shared__ float t[64][65];
    size_t eoff = (size_t)blockIdx.z * (size_t)K * (size_t)N;
    int k0 = blockIdx.y*64, n0 = blockIdx.x*64;
    int tid = threadIdx.x;
    #pragma unroll
    for (int it=0; it<16; ++it) {
        int lin = it*256 + tid;
        int r = lin >> 6, c = lin & 63;
        t[r][c] = in[eoff + (size_t)(k0+r)*N + n0 + c];
    }
    __syncthreads();
    #pragma unroll
    for (int it=0; it<16; ++it) {
        int lin = it*256 + tid;
        int r = lin >> 6, c = lin & 63;   // r = n-local, c = k-local
        outp[eoff + (size_t)(n0+r)*K + k0 + c] = __float2bfloat16(t[c][r]);
    }
}

// ---------------- MFMA MoE GEMM: 128x128 tile, BK=64, 4 waves ----------------
// MODE 2: y1 = gelu(gather(hs_b) @ W1t^T)  -> bf16
// MODE 3: moe_out[tok] += w * (y1 @ W2t^T) -> f32 atomic
// Bt is B^T per expert: [N][K] bf16.
template<int MODE, bool PE>
__global__ __launch_bounds__(256) void moe_mfma(
    const __hip_bfloat16* __restrict__ A,
    const __hip_bfloat16* __restrict__ Bt,
    __hip_bfloat16* __restrict__ y1,
    float* __restrict__ moe_out,
    const int* __restrict__ slot_token,
    const float* __restrict__ slot_w,
    const int* __restrict__ tile_expert,
    const int* __restrict__ cnt_ptr,     // PE: &cnt_pad[e] ; FULL: &ntiles_tot
    const int* __restrict__ base_ptr,    // PE: &base[e]
    int N, int K)
{
    const int tid = threadIdx.x;
    const int w = tid >> 6, lane = tid & 63;
    const int bx = blockIdx.x;

    int slot0, y1row0;
    const __hip_bfloat16* Bp;
    if (PE) {
        int tloc = blockIdx.y;
        if ((tloc << 7) >= *cnt_ptr) return;
        slot0 = *base_ptr + (tloc << 7);
        y1row0 = tloc << 7;
        Bp = Bt;
    } else {
        int gt = blockIdx.y;
        if (gt >= *cnt_ptr) return;
        int e = tile_expert[gt];
        Bp = Bt + (size_t)e * (size_t)K * (size_t)N;
        slot0 = gt << 7;
        y1row0 = gt << 7;
    }

    __shared__ __align__(16) char smem[32768];  // A @0 (16KB), B @16384 (16KB)

    const int laneg = lane >> 3;            // 0..7 (row within 8-row group)
    const int k2sw = ((lane & 7) ^ laneg) << 4;  // inverse-swizzled k2 byte offset

    // token gather rows (MODE 2) / A row bases
    int tokq[4];
    if (MODE == 2) {
        #pragma unroll
        for (int qq=0;qq<4;qq++) {
            int t0 = slot_token[slot0 + (w*4+qq)*8 + laneg];
            tokq[qq] = t0 < 0 ? 0 : t0;
        }
    }

    f32x4 acc[4][4];
    #pragma unroll
    for (int m=0;m<4;m++)
        #pragma unroll
        for (int n=0;n<4;n++) acc[m][n] = (f32x4){0.f,0.f,0.f,0.f};

    const int l15 = lane & 15;
    const int l4  = lane >> 4;      // 0..3
    const int wr = w >> 1, wc = w & 1;

    for (int k0 = 0; k0 < K; k0 += 64) {
        __syncthreads();
        // stage A tile
        #pragma unroll
        for (int qq=0;qq<4;qq++) {
            const char* ga;
            if (MODE == 2) {
                ga = (const char*)A + (((size_t)tokq[qq])*K + k0)*2 + k2sw;
            } else {
                int row = y1row0 + (w*4+qq)*8 + laneg;
                ga = (const char*)A + ((size_t)row*K + k0)*2 + k2sw;
            }
            GLOAD16(ga, smem + (w*4+qq)*1024);
        }
        // stage B^T tile
        #pragma unroll
        for (int qq=0;qq<4;qq++) {
            int row = bx*128 + (w*4+qq)*8 + laneg;
            const char* gb = (const char*)Bp + ((size_t)row*K + k0)*2 + k2sw;
            GLOAD16(gb, smem + 16384 + (w*4+qq)*1024);
        }
        __syncthreads();

        short8v a_frag[4][2], b_frag[4][2];
        #pragma unroll
        for (int m=0;m<4;m++) {
            int row = wr*64 + m*16 + l15;
            int rb = row << 7;
            #pragma unroll
            for (int s=0;s<2;s++) {
                int off = rb + ((s*64 + (l4<<4)) ^ ((row&7)<<4));
                a_frag[m][s] = *(const short8v*)(smem + off);
            }
        }
        #pragma unroll
        for (int n=0;n<4;n++) {
            int row = wc*64 + n*16 + l15;
            int rb = row << 7;
            #pragma unroll
            for (int s=0;s<2;s++) {
                int off = rb + ((s*64 + (l4<<4)) ^ ((row&7)<<4));
                b_frag[n][s] = *(const short8v*)(smem + 16384 + off);
            }
        }
        #pragma unroll
        for (int m=0;m<4;m++)
            #pragma unroll
            for (int n=0;n<4;n++) {
                acc[m][n] = __builtin_amdgcn_mfma_f32_16x16x32_bf16(a_frag[m][0], b_frag[n][0], acc[m][n], 0, 0, 0);
                acc[m][n] = __builtin_amdgcn_mfma_f32_16x16x32_bf16(a_frag[m][1], b_frag[n][1], acc[m][n], 0, 0, 0);
            }
    }

    // epilogue: D col = lane&15, row = (lane>>4)*4 + j
    #pragma unroll
    for (int m=0;m<4;m++) {
        #pragma unroll
        for (int j=0;j<4;j++) {
            int orow = wr*64 + m*16 + l4*4 + j;
            if (MODE == 3) {
                int slot = slot0 + orow;
                int tok = slot_token[slot];
                if (tok < 0) continue;
                float sw = slot_w[slot];
                #pragma unroll
                for (int n=0;n<4;n++) {
                    int ocol = bx*128 + wc*64 + n*16 + l15;
                    atomicAdd(&moe_out[(size_t)tok*H_ + ocol], sw * acc[m][n][j]);
                }
            } else {
                #pragma unroll
                for (int n=0;n<4;n++) {
                    int ocol = bx*128 + wc*64 + n*16 + l15;
                    float val = acc[m][n][j];
                    float g = 0.5f*val*(1.f + erff(val*0.70710678118654752f));
                    y1[(size_t)(y1row0 + orow)*N + ocol] = __float2bfloat16(g);
                }
            }
        }
    }
}

// ---------------- RoPE (in-place on q,k; fp32) ----------------
__global__ void rope_kernel(float* __restrict__ q, float* __restrict__ k) {
    int idx = blockIdx.x * blockDim.x + threadIdx.x;  // T*NH*32
    int i = idx & 31;
    int n = (idx >> 5) & (NH_-1);
    int t = idx >> 9;
    int pos = t & (S_ - 1);
    // 1/10000^(2i/64) = exp2(-(i/32)*log2(10000))
    float inv = exp2f((float)i * (-13.287712379549449f / 32.f));
    float ang = (float)pos * inv;
    float c = cosf(ang), s = sinf(ang);
    size_t base = (size_t)t*H_ + (size_t)n*64;
    float q1 = q[base+i], q2 = q[base+i+32];
    q[base+i]    = q1*c - q2*s;
    q[base+i+32] = q2*c + q1*s;
    float k1 = k[base+i], k2 = k[base+i+32];
    k[base+i]    = k1*c - k2*s;
    k[base+i+32] = k2*c + k1*s;
}

// ---------------- attention: flash-style, 16 q rows/block (round-1 structure
// + float4 wave-uniform q/p reads). fp32 throughout (routing sensitivity). ----------------
__global__ __launch_bounds__(256) void attn_kernel(
    const float* __restrict__ q, const float* __restrict__ k,
    const float* __restrict__ v, float* __restrict__ ctx)
{
    const int qt = blockIdx.x;
    const int n  = blockIdx.y;
    const int b  = blockIdx.z;
    const int tid = threadIdx.x;
    const int w = tid >> 6;
    const int lane = tid & 63;

    __shared__ float Kt[64*65];          // [d][j] transposed, pad-65
    __shared__ float Vt[64*65];          // [j][d], pad-65
    __shared__ float q_s[4][4][64];
    __shared__ float p_s[4][4][64];

    const size_t headoff = (size_t)b*S_*H_ + (size_t)n*64;

    float mrun[4], lrun[4], acc[4];
    #pragma unroll
    for (int r=0;r<4;r++) {
        int qrow = qt*16 + w*4 + r;
        q_s[w][r][lane] = q[headoff + (size_t)qrow*H_ + lane];
        mrun[r] = -1e30f; lrun[r] = 0.f; acc[r] = 0.f;
    }

    for (int kt=0; kt<S_/64; ++kt) {
        __syncthreads();
        #pragma unroll
        for (int it=0; it<16; ++it) {
            int lin = it*256 + tid;
            int r = lin >> 6, c = lin & 63;
            size_t g = headoff + (size_t)(kt*64+r)*H_ + c;
            Kt[c*65 + r] = k[g];
            Vt[r*65 + c] = v[g];
        }
        __syncthreads();

        // scores: lane = k-row j of this tile
        float s4[4] = {0.f,0.f,0.f,0.f};
        #pragma unroll
        for (int d4=0; d4<16; ++d4) {
            float kv[4];
            #pragma unroll
            for (int dd=0; dd<4; ++dd) kv[dd] = Kt[(d4*4+dd)*65 + lane];
            #pragma unroll
            for (int r=0;r<4;r++) {
                const float4 qv = *(const float4*)&q_s[w][r][d4*4];
                s4[r] = fmaf(qv.x, kv[0], fmaf(qv.y, kv[1], fmaf(qv.z, kv[2], fmaf(qv.w, kv[3], s4[r]))));
            }
        }
        float alpha[4];
        #pragma unroll
        for (int r=0;r<4;r++) {
            float sv = s4[r] * 0.125f;
            float mt = sv;
            #pragma unroll
            for (int off=32; off; off>>=1) mt = fmaxf(mt, __shfl_xor(mt, off));
            float mnew = fmaxf(mrun[r], mt);
            float pv = __expf(sv - mnew);
            float ps = pv;
            #pragma unroll
            for (int off=32; off; off>>=1) ps += __shfl_xor(ps, off);
            alpha[r] = __expf(mrun[r] - mnew);
            lrun[r] = lrun[r]*alpha[r] + ps;
            mrun[r] = mnew;
            p_s[w][r][lane] = pv;
        }
        __syncthreads();   // p_s visible before cross-lane read (round-1 placement)

        // ctx: lane = dim d
        float add[4] = {0.f,0.f,0.f,0.f};
        #pragma unroll
        for (int j4=0; j4<16; ++j4) {
            float vv[4];
            #pragma unroll
            for (int jj=0; jj<4; ++jj) vv[jj] = Vt[(j4*4+jj)*65 + lane];
            #pragma unroll
            for (int r=0;r<4;r++) {
                const float4 pv4 = *(const float4*)&p_s[w][r][j4*4];
                add[r] = fmaf(pv4.x, vv[0], fmaf(pv4.y, vv[1], fmaf(pv4.z, vv[2], fmaf(pv4.w, vv[3], add[r]))));
            }
        }
        #pragma unroll
        for (int r=0;r<4;r++) acc[r] = acc[r]*alpha[r] + add[r];
    }
    #pragma unroll
    for (int r=0;r<4;r++) {
        int qrow = qt*16 + w*4 + r;
        ctx[headoff + (size_t)qrow*H_ + lane] = acc[r] / lrun[r];
    }
}

// ---------------- layernorm (residual fused, optional bf16 out) ----------------
__global__ __launch_bounds__(256) void ln_kernel(
    const float* __restrict__ a, const float* __restrict__ res,
    const float* __restrict__ g, const float* __restrict__ beta,
    float* __restrict__ out, __hip_bfloat16* __restrict__ outb)
{
    int row = blockIdx.x, tid = threadIdx.x;
    const float4 va = ((const float4*)(a + (size_t)row*H_))[tid];
    const float4 vr = ((const float4*)(res + (size_t)row*H_))[tid];
    float x0=va.x+vr.x, x1=va.y+vr.y, x2=va.z+vr.z, x3=va.w+vr.w;
    float s  = x0+x1+x2+x3;
    float ss = x0*x0 + x1*x1 + x2*x2 + x3*x3;
    #pragma unroll
    for (int off=32; off; off>>=1) { s += __shfl_xor(s, off); ss += __shfl_xor(ss, off); }
    __shared__ float red[8];
    if ((tid&63)==0) { red[tid>>6]=s; red[4+(tid>>6)]=ss; }
    __syncthreads();
    if (tid==0) { red[0]=red[0]+red[1]+red[2]+red[3]; red[4]=red[4]+red[5]+red[6]+red[7]; }
    __syncthreads();
    float mu  = red[0] * (1.f/H_);
    float var = red[4] * (1.f/H_) - mu*mu;
    float rs = rsqrtf(fmaxf(var, 0.f) + 1e-12f);
    const float4 vg = ((const float4*)g)[tid];
    const float4 vb = ((const float4*)beta)[tid];
    float4 vo;
    vo.x = (x0-mu)*rs*vg.x + vb.x;
    vo.y = (x1-mu)*rs*vg.y + vb.y;
    vo.z = (x2-mu)*rs*vg.z + vb.z;
    vo.w = (x3-mu)*rs*vg.w + vb.w;
    ((float4*)(out + (size_t)row*H_))[tid] = vo;
    if (outb) {
        unsigned int p0 = (unsigned)f2bf(vo.x) | ((unsigned)f2bf(vo.y) << 16);
        unsigned int p1 = (unsigned)f2bf(vo.z) | ((unsigned)f2bf(vo.w) << 16);
        ((uint2*)(outb + (size_t)row*H_))[tid] = make_uint2(p0, p1);
    }
}

// ---------------- router ----------------
__global__ __launch_bounds__(256) void router_kernel(
    const float* __restrict__ hs, const float* __restrict__ Wg,
    int* __restrict__ tok_e, float* __restrict__ tok_w,
    int* __restrict__ counts, float* __restrict__ P_sum)
{
    int t = blockIdx.x*4 + (threadIdx.x >> 6);
    int lane = threadIdx.x & 63;
    const float* row = hs + (size_t)t * H_;
    float acc[E_];
    #pragma unroll
    for (int e=0;e<E_;e++) acc[e]=0.f;
    for (int it=0; it<16; ++it) {
        int i = it*64 + lane;
        float xv = row[i];
        const float* wg = Wg + (size_t)i*E_;
        #pragma unroll
        for (int e=0;e<E_;e++) acc[e] = fmaf(xv, wg[e], acc[e]);
    }
    #pragma unroll
    for (int e=0;e<E_;e++) {
        float vv = acc[e];
        #pragma unroll
        for (int off=32; off; off>>=1) vv += __shfl_xor(vv, off);
        acc[e] = vv;
    }
    if (lane==0) {
        float mx = acc[0];
        #pragma unroll
        for (int e=1;e<E_;e++) mx = fmaxf(mx, acc[e]);
        float p[E_], se=0.f;
        #pragma unroll
        for (int e=0;e<E_;e++){ p[e] = expf(acc[e]-mx); se += p[e]; }
        float isv = 1.f/se;
        #pragma unroll
        for (int e=0;e<E_;e++){ p[e]*=isv; atomicAdd(&P_sum[e], p[e]); }
        int e1=0;
        #pragma unroll
        for (int e=1;e<E_;e++) if (p[e] > p[e1]) e1=e;
        int e2 = (e1==0)?1:0;
        #pragma unroll
        for (int e=0;e<E_;e++) if (e!=e1 && p[e] > p[e2]) e2=e;
        float w1=p[e1], w2=p[e2], si=1.f/(w1+w2);
        tok_e[t*2]=e1; tok_e[t*2+1]=e2;
        tok_w[t*2]=w1*si; tok_w[t*2+1]=w2*si;
        atomicAdd(&counts[e1],1); atomicAdd(&counts[e2],1);
    }
}

__global__ void router_finalize(
    const int* __restrict__ counts, const float* __restrict__ P_sum,
    int* __restrict__ base, int* __restrict__ cursor,
    int* __restrict__ cnt_pad, int* __restrict__ ntiles,
    int* __restrict__ slot_token, int* __restrict__ tile_expert,
    float* __restrict__ aux_out)
{
    __shared__ int sbase[E_+1];
    if (threadIdx.x == 0) {
        int bacc = 0;
        float aux = 0.f;
        for (int e=0;e<E_;e++) {
            sbase[e] = bacc; base[e] = bacc;
            int cp = (counts[e] + 127) & ~127;
            cnt_pad[e] = cp;
            bacc += cp;
            cursor[e] = 0;
            aux += ((float)counts[e]/(float)T_) * (P_sum[e]/(float)T_);
        }
        sbase[E_] = bacc;
        *ntiles = bacc >> 7;
        *aux_out = (float)E_ * aux;
    }
    __syncthreads();
    for (int sIdx = (int)threadIdx.x; sIdx < MAXSLOTS; sIdx += (int)blockDim.x)
        slot_token[sIdx] = -1;
    for (int tt = (int)threadIdx.x; tt < MAXTILES; tt += (int)blockDim.x) {
        int s = tt*128;
        int e = E_-1;
        for (int qe=0; qe<E_; ++qe) if (s < sbase[qe+1]) { e = qe; break; }
        tile_expert[tt] = e;
    }
}

__global__ void scatter_slots(
    const int* __restrict__ tok_e, const float* __restrict__ tok_w,
    const int* __restrict__ base, int* __restrict__ cursor,
    int* __restrict__ slot_token, float* __restrict__ slot_w)
{
    int t = blockIdx.x*blockDim.x + threadIdx.x;
    if (t >= T_) return;
    #pragma unroll
    for (int j=0;j<2;j++) {
        int e = tok_e[t*2+j];
        int pos = atomicAdd(&cursor[e], 1);
        int s = base[e] + pos;
        slot_token[s] = t;
        slot_w[s] = tok_w[t*2+j];
    }
}

extern "C" void kernel_launch(void* const* d_in, const int* in_sizes, int n_in,
                              void* d_out, int out_size, void* d_ws, size_t ws_size,
                              hipStream_t stream)
{
    const float* x    = (const float*)d_in[0];
    const float* Wq   = (const float*)d_in[1];
    const float* Wk   = (const float*)d_in[2];
    const float* Wv   = (const float*)d_in[3];
    const float* Wd   = (const float*)d_in[4];
    const float* bd   = (const float*)d_in[5];
    const float* ln1g = (const float*)d_in[6];
    const float* ln1b = (const float*)d_in[7];
    const float* Wg   = (const float*)d_in[8];
    const float* W1   = (const float*)d_in[9];
    const float* W2   = (const float*)d_in[10];
    const float* ln2g = (const float*)d_in[11];
    const float* ln2b = (const float*)d_in[12];
    float* out = (float*)d_out;

    float* f0 = (float*)d_ws;
    const size_t M1 = 1u << 20;
    float* qb   = f0;            // q -> attn_out
    float* kb   = f0 + 4*M1;     // k -> hs
    float* vb   = f0 + 8*M1;     // v -> moe_out
    float* ctxb = f0 + 12*M1;
    __hip_bfloat16* hs_b = (__hip_bfloat16*)(f0 + 16*M1);   // 4M bf16

    float* misc = f0 + 18*M1;
    int*   misc_i = (int*)misc;
    int*   tok_e   = misc_i;                 // 8192
    float* tok_w   = misc + 8192;            // 8192
    int*   slot_tok= misc_i + 16384;         // 9216
    float* slot_w  = misc + 25600;           // 9216
    int*   counts  = misc_i + 34816;         // 8
    float* P_sum   = misc + 34824;           // 8
    int*   cursor  = misc_i + 34832;         // 8
    int*   basep   = misc_i + 34840;         // 8
    int*   cnt_pad = misc_i + 34848;         // 8
    int*   ntiles  = misc_i + 34856;         // 1
    int*   tile_ex = misc_i + 34857;         // 72

    float* wreg = f0 + 18*M1 + 65536;
    const bool FULL = ws_size >= (size_t)300*1024*1024;

    dim3 blk(256);
    dim3 blk128(128);

    // QKV projections (fp32)
    gemm_f32<0><<<dim3(H_/64, T_/64), blk128, 0, stream>>>(x, Wq, qb, nullptr, H_, H_);
    gemm_f32<0><<<dim3(H_/64, T_/64), blk128, 0, stream>>>(x, Wk, kb, nullptr, H_, H_);
    gemm_f32<0><<<dim3(H_/64, T_/64), blk128, 0, stream>>>(x, Wv, vb, nullptr, H_, H_);

    rope_kernel<<<(T_*NH_*32)/256, blk, 0, stream>>>(qb, kb);

    attn_kernel<<<dim3(S_/16, NH_, B_), blk, 0, stream>>>(qb, kb, vb, ctxb);

    // attn_out = ctx@Wd + bd (into q buffer); then moe_out (v buffer) can be zeroed
    gemm_f32<1><<<dim3(H_/64, T_/64), blk128, 0, stream>>>(ctxb, Wd, qb, bd, H_, H_);

    zero_kernel<<<(T_*H_)/256, blk, 0, stream>>>(vb, T_*H_);
    zero_kernel<<<1, blk, 0, stream>>>(misc + 34816, 16);

    // hs = LN1(attn_out + x) -> kb (f32) + hs_b (bf16)
    ln_kernel<<<T_, blk, 0, stream>>>(qb, x, ln1g, ln1b, kb, hs_b);

    router_kernel<<<T_/4, blk, 0, stream>>>(kb, Wg, tok_e, tok_w, counts, P_sum);
    router_finalize<<<1, blk, 0, stream>>>(counts, P_sum, basep, cursor, cnt_pad, ntiles,
                                           slot_tok, tile_ex, out + (size_t)T_*H_);
    scatter_slots<<<T_/256, blk, 0, stream>>>(tok_e, tok_w, basep, cursor, slot_tok, slot_w);

    if (FULL) {
        __hip_bfloat16* W1t = (__hip_bfloat16*)wreg;
        __hip_bfloat16* W2t = (__hip_bfloat16*)(wreg + 16*M1);
        __hip_bfloat16* y1  = (__hip_bfloat16*)(wreg + 32*M1);
        transpose_bf16<<<dim3(I_/64, H_/64, E_), blk, 0, stream>>>(W1, W1t, H_, I_);
        transpose_bf16<<<dim3(H_/64, I_/64, E_), blk, 0, stream>>>(W2, W2t, I_, H_);
        moe_mfma<2,false><<<dim3(I_/128, MAXTILES), blk, 0, stream>>>(
            hs_b, W1t, y1, nullptr, slot_tok, slot_w, tile_ex, ntiles, nullptr, I_, H_);
        moe_mfma<3,false><<<dim3(H_/128, MAXTILES), blk, 0, stream>>>(
            y1, W2t, nullptr, vb, slot_tok, slot_w, tile_ex, ntiles, nullptr, H_, I_);
    } else {
        __hip_bfloat16* w1t = (__hip_bfloat16*)wreg;                 // 2M f32 = 4M bf16
        __hip_bfloat16* w2t = (__hip_bfloat16*)(wreg + 2*M1);        // 2M f32
        __hip_bfloat16* y1  = (__hip_bfloat16*)(wreg + 4*M1);        // 8M f32 = 32 tiles
        for (int e=0; e<E_; ++e) {
            transpose_bf16<<<dim3(I_/64, H_/64, 1), blk, 0, stream>>>(W1 + (size_t)e*H_*I_, w1t, H_, I_);
            moe_mfma<2,true><<<dim3(I_/128, 32), blk, 0, stream>>>(
                hs_b, w1t, y1, nullptr, slot_tok, slot_w, nullptr, cnt_pad+e, basep+e, I_, H_);
            transpose_bf16<<<dim3(H_/64, I_/64, 1), blk, 0, stream>>>(W2 + (size_t)e*I_*H_, w2t, I_, H_);
            moe_mfma<3,true><<<dim3(H_/128, 32), blk, 0, stream>>>(
                y1, w2t, nullptr, vb, slot_tok, slot_w, nullptr, cnt_pad+e, basep+e, H_, I_);
        }
    }

    // out = LN2(hs + moe_out)
    ln_kernel<<<T_, blk, 0, stream>>>(vb, kb, ln2g, ln2b, out, nullptr);
}

// Round 4
// 1777.850 us; speedup vs baseline: 3.4014x; 1.5764x over previous
//
#include <hip/hip_runtime.h>
#include <hip/hip_bf16.h>
#include <math.h>

#define H_ 1024
#define NH_ 16
#define HD_ 64
#define I_ 4096
#define E_ 8
#define B_ 2
#define S_ 2048
#define T_ 4096

#define MAXSLOTS 9216   // 2*T + 8*128 pad
#define MAXTILES 72     // MAXSLOTS/128

typedef __attribute__((ext_vector_type(8))) short short8v;
typedef __attribute__((ext_vector_type(4))) float f32x4;

#define GLOAD16(g, l) __builtin_amdgcn_global_load_lds((const __attribute__((address_space(1))) void*)(g), (__attribute__((address_space(3))) void*)(l), 16, 0, 0)

static __device__ inline unsigned short f2bf(float x) {
    __hip_bfloat16 h = __float2bfloat16(x);
    unsigned short u;
    __builtin_memcpy(&u, &h, 2);
    return u;
}
static __device__ inline float bf2f(unsigned short u) {
    __hip_bfloat16 h;
    __builtin_memcpy(&h, &u, 2);
    return __bfloat162float(h);
}

// ---------------- zero ----------------
__global__ void zero_kernel(float* __restrict__ p, int n) {
    int i = blockIdx.x * blockDim.x + threadIdx.x;
    if (i < n) p[i] = 0.f;
}

// ---------------- fp32 GEMM: 64x64 tile, 128 thr, 8x4 acc ----------------
template<int MODE>
__global__ __launch_bounds__(128) void gemm_f32(
    const float* __restrict__ A, const float* __restrict__ Bw,
    float* __restrict__ C, const float* __restrict__ bias, int N, int K)
{
    __shared__ float As[16][68];
    __shared__ float Bs[16][68];
    const int bx = blockIdx.x, by = blockIdx.y;
    const int tid = threadIdx.x;
    const int tx = tid & 15, ty = tid >> 4;

    float acc[8][4];
    #pragma unroll
    for (int i=0;i<8;i++)
        #pragma unroll
        for (int j=0;j<4;j++) acc[i][j]=0.f;

    for (int k0 = 0; k0 < K; k0 += 16) {
        __syncthreads();
        #pragma unroll
        for (int t=0;t<8;t++) {
            int lin = t*128 + tid;
            int m = lin >> 4, kk = lin & 15;
            As[kk][m] = A[(size_t)(by*64 + m)*K + k0 + kk];
        }
        #pragma unroll
        for (int t=0;t<8;t++) {
            int lin = t*128 + tid;
            int kk = lin >> 6, n = lin & 63;
            Bs[kk][n] = Bw[(size_t)(k0+kk)*N + bx*64 + n];
        }
        __syncthreads();
        #pragma unroll
        for (int kk=0; kk<16; ++kk) {
            float a8[8], b4[4];
            *(float4*)&a8[0] = *(const float4*)&As[kk][ty*8];
            *(float4*)&a8[4] = *(const float4*)&As[kk][ty*8+4];
            *(float4*)&b4[0] = *(const float4*)&Bs[kk][tx*4];
            #pragma unroll
            for (int i=0;i<8;i++)
                #pragma unroll
                for (int j=0;j<4;j++)
                    acc[i][j] = fmaf(a8[i], b4[j], acc[i][j]);
        }
    }

    #pragma unroll
    for (int i=0;i<8;i++) {
        int row = by*64 + ty*8 + i;
        int col = bx*64 + tx*4;
        float4 v;
        v.x = acc[i][0]; v.y = acc[i][1]; v.z = acc[i][2]; v.w = acc[i][3];
        if (MODE == 1) {
            v.x += bias[col]; v.y += bias[col+1]; v.z += bias[col+2]; v.w += bias[col+3];
        }
        *(float4*)&C[(size_t)row*N + col] = v;
    }
}

// ---------------- transpose + f32->bf16: in [K][N] -> out [N][K] ----------------
__global__ __launch_bounds__(256) void transpose_bf16(
    const float* __restrict__ in, __hip_bfloat16* __restrict__ outp, int K, int N)
{
    __shared__ float t[64][65];
    size_t eoff = (size_t)blockIdx.z * (size_t)K * (size_t)N;
    int k0 = blockIdx.y*64, n0 = blockIdx.x*64;
    int tid = threadIdx.x;
    #pragma unroll
    for (int it=0; it<16; ++it) {
        int lin = it*256 + tid;
        int r = lin >> 6, c = lin & 63;
        t[r][c] = in[eoff + (size_t)(k0+r)*N + n0 + c];
    }
    __syncthreads();
    #pragma unroll
    for (int it=0; it<16; ++it) {
        int lin = it*256 + tid;
        int r = lin >> 6, c = lin & 63;
        outp[eoff + (size_t)(n0+r)*K + k0 + c] = __float2bfloat16(t[c][r]);
    }
}

// ---------------- MFMA MoE GEMM (unchanged, verified) ----------------
template<int MODE, bool PE>
__global__ __launch_bounds__(256) void moe_mfma(
    const __hip_bfloat16* __restrict__ A,
    const __hip_bfloat16* __restrict__ Bt,
    __hip_bfloat16* __restrict__ y1,
    float* __restrict__ moe_out,
    const int* __restrict__ slot_token,
    const float* __restrict__ slot_w,
    const int* __restrict__ tile_expert,
    const int* __restrict__ cnt_ptr,
    const int* __restrict__ base_ptr,
    int N, int K)
{
    const int tid = threadIdx.x;
    const int w = tid >> 6, lane = tid & 63;
    const int bx = blockIdx.x;

    int slot0, y1row0;
    const __hip_bfloat16* Bp;
    if (PE) {
        int tloc = blockIdx.y;
        if ((tloc << 7) >= *cnt_ptr) return;
        slot0 = *base_ptr + (tloc << 7);
        y1row0 = tloc << 7;
        Bp = Bt;
    } else {
        int gt = blockIdx.y;
        if (gt >= *cnt_ptr) return;
        int e = tile_expert[gt];
        Bp = Bt + (size_t)e * (size_t)K * (size_t)N;
        slot0 = gt << 7;
        y1row0 = gt << 7;
    }

    __shared__ __align__(16) char smem[32768];

    const int laneg = lane >> 3;
    const int k2sw = ((lane & 7) ^ laneg) << 4;

    int tokq[4];
    if (MODE == 2) {
        #pragma unroll
        for (int qq=0;qq<4;qq++) {
            int t0 = slot_token[slot0 + (w*4+qq)*8 + laneg];
            tokq[qq] = t0 < 0 ? 0 : t0;
        }
    }

    f32x4 acc[4][4];
    #pragma unroll
    for (int m=0;m<4;m++)
        #pragma unroll
        for (int n=0;n<4;n++) acc[m][n] = (f32x4){0.f,0.f,0.f,0.f};

    const int l15 = lane & 15;
    const int l4  = lane >> 4;
    const int wr = w >> 1, wc = w & 1;

    for (int k0 = 0; k0 < K; k0 += 64) {
        __syncthreads();
        #pragma unroll
        for (int qq=0;qq<4;qq++) {
            const char* ga;
            if (MODE == 2) {
                ga = (const char*)A + (((size_t)tokq[qq])*K + k0)*2 + k2sw;
            } else {
                int row = y1row0 + (w*4+qq)*8 + laneg;
                ga = (const char*)A + ((size_t)row*K + k0)*2 + k2sw;
            }
            GLOAD16(ga, smem + (w*4+qq)*1024);
        }
        #pragma unroll
        for (int qq=0;qq<4;qq++) {
            int row = bx*128 + (w*4+qq)*8 + laneg;
            const char* gb = (const char*)Bp + ((size_t)row*K + k0)*2 + k2sw;
            GLOAD16(gb, smem + 16384 + (w*4+qq)*1024);
        }
        __syncthreads();

        short8v a_frag[4][2], b_frag[4][2];
        #pragma unroll
        for (int m=0;m<4;m++) {
            int row = wr*64 + m*16 + l15;
            int rb = row << 7;
            #pragma unroll
            for (int s=0;s<2;s++) {
                int off = rb + ((s*64 + (l4<<4)) ^ ((row&7)<<4));
                a_frag[m][s] = *(const short8v*)(smem + off);
            }
        }
        #pragma unroll
        for (int n=0;n<4;n++) {
            int row = wc*64 + n*16 + l15;
            int rb = row << 7;
            #pragma unroll
            for (int s=0;s<2;s++) {
                int off = rb + ((s*64 + (l4<<4)) ^ ((row&7)<<4));
                b_frag[n][s] = *(const short8v*)(smem + 16384 + off);
            }
        }
        #pragma unroll
        for (int m=0;m<4;m++)
            #pragma unroll
            for (int n=0;n<4;n++) {
                acc[m][n] = __builtin_amdgcn_mfma_f32_16x16x32_bf16(a_frag[m][0], b_frag[n][0], acc[m][n], 0, 0, 0);
                acc[m][n] = __builtin_amdgcn_mfma_f32_16x16x32_bf16(a_frag[m][1], b_frag[n][1], acc[m][n], 0, 0, 0);
            }
    }

    #pragma unroll
    for (int m=0;m<4;m++) {
        #pragma unroll
        for (int j=0;j<4;j++) {
            int orow = wr*64 + m*16 + l4*4 + j;
            if (MODE == 3) {
                int slot = slot0 + orow;
                int tok = slot_token[slot];
                if (tok < 0) continue;
                float sw = slot_w[slot];
                #pragma unroll
                for (int n=0;n<4;n++) {
                    int ocol = bx*128 + wc*64 + n*16 + l15;
                    atomicAdd(&moe_out[(size_t)tok*H_ + ocol], sw * acc[m][n][j]);
                }
            } else {
                #pragma unroll
                for (int n=0;n<4;n++) {
                    int ocol = bx*128 + wc*64 + n*16 + l15;
                    float val = acc[m][n][j];
                    float g = 0.5f*val*(1.f + erff(val*0.70710678118654752f));
                    y1[(size_t)(y1row0 + orow)*N + ocol] = __float2bfloat16(g);
                }
            }
        }
    }
}

// ---------------- RoPE (in-place on q,k; fp32) ----------------
__global__ void rope_kernel(float* __restrict__ q, float* __restrict__ k) {
    int idx = blockIdx.x * blockDim.x + threadIdx.x;
    int i = idx & 31;
    int n = (idx >> 5) & (NH_-1);
    int t = idx >> 9;
    int pos = t & (S_ - 1);
    float inv = exp2f((float)i * (-13.287712379549449f / 32.f));
    float ang = (float)pos * inv;
    float c = cosf(ang), s = sinf(ang);
    size_t base = (size_t)t*H_ + (size_t)n*64;
    float q1 = q[base+i], q2 = q[base+i+32];
    q[base+i]    = q1*c - q2*s;
    q[base+i+32] = q2*c + q1*s;
    float k1 = k[base+i], k2 = k[base+i+32];
    k[base+i]    = k1*c - k2*s;
    k[base+i+32] = k2*c + k1*s;
}

// ---------------- MFMA attention: bf16x3 split (fp32-accurate) ----------------
// 64 q-rows/block, 4 waves (16 rows each), K/V tiles of 64.
// Swizzled LDS rows: 128B pitch, byte ^= ((row&7)<<4).
__global__ __launch_bounds__(256, 3) void attn_mfma(
    const float* __restrict__ q, const float* __restrict__ k,
    const float* __restrict__ v, float* __restrict__ ctx)
{
    const int qt = blockIdx.x;   // 0..31
    const int hn = blockIdx.y;
    const int b  = blockIdx.z;
    const int tid = threadIdx.x;
    const int w = tid >> 6, lane = tid & 63;
    const int l15 = lane & 15, l4 = lane >> 4;

    __shared__ __align__(16) char smem[49152];
    const int KHo = 0, KLo = 8192, VHo = 16384, VLo = 24576, PHo = 32768, PLo = 40960;

    const size_t headoff = (size_t)b*S_*H_ + (size_t)hn*64;

    // staging mapping: row j = w*16+l15, dims d = l4*16 + [0..16)
    const int sj = w*16 + l15;
    const int sd = l4*16;
    const int swz_j = (sj & 7) << 4;

    // ---- prologue: stage Q (scaled 0.125) into P region (wave-private rows), load frags ----
    {
        const float* g = q + headoff + (size_t)(qt*64 + sj)*H_ + sd;
        float xv[16];
        *(float4*)&xv[0]  = *(const float4*)(g);
        *(float4*)&xv[4]  = *(const float4*)(g+4);
        *(float4*)&xv[8]  = *(const float4*)(g+8);
        *(float4*)&xv[12] = *(const float4*)(g+12);
        #pragma unroll
        for (int i=0;i<8;i++) {
            float a = xv[2*i]*0.125f, b2 = xv[2*i+1]*0.125f;
            unsigned short ah = f2bf(a), bh = f2bf(b2);
            unsigned short al = f2bf(a - bf2f(ah)), bl = f2bf(b2 - bf2f(bh));
            int off = sj*128 + ((l4*32 + 4*i) ^ swz_j);
            *(unsigned*)(smem + PHo + off) = (unsigned)ah | ((unsigned)bh << 16);
            *(unsigned*)(smem + PLo + off) = (unsigned)al | ((unsigned)bl << 16);
        }
    }
    asm volatile("s_waitcnt lgkmcnt(0)" ::: "memory");
    short8v qh[2], ql[2];
    {
        int row = w*16 + l15;
        int rsw = (row & 7) << 4;
        #pragma unroll
        for (int s=0;s<2;s++) {
            int off = row*128 + ((s*64 + l4*16) ^ rsw);
            qh[s] = *(const short8v*)(smem + PHo + off);
            ql[s] = *(const short8v*)(smem + PLo + off);
        }
    }

    f32x4 acc[4];
    #pragma unroll
    for (int db=0;db<4;db++) acc[db] = (f32x4){0.f,0.f,0.f,0.f};
    float mrun[4], lrun[4];
    #pragma unroll
    for (int j=0;j<4;j++) { mrun[j] = -1e30f; lrun[j] = 0.f; }

    for (int kt=0; kt<S_/64; ++kt) {
        __syncthreads();   // prior tile's K/V reads done
        // ---- stage K (row-major) ----
        {
            const float* g = k + headoff + (size_t)(kt*64 + sj)*H_ + sd;
            float xv[16];
            *(float4*)&xv[0]  = *(const float4*)(g);
            *(float4*)&xv[4]  = *(const float4*)(g+4);
            *(float4*)&xv[8]  = *(const float4*)(g+8);
            *(float4*)&xv[12] = *(const float4*)(g+12);
            #pragma unroll
            for (int i=0;i<8;i++) {
                float a = xv[2*i], b2 = xv[2*i+1];
                unsigned short ah = f2bf(a), bh = f2bf(b2);
                unsigned short al = f2bf(a - bf2f(ah)), bl = f2bf(b2 - bf2f(bh));
                int off = sj*128 + ((l4*32 + 4*i) ^ swz_j);
                *(unsigned*)(smem + KHo + off) = (unsigned)ah | ((unsigned)bh << 16);
                *(unsigned*)(smem + KLo + off) = (unsigned)al | ((unsigned)bl << 16);
            }
        }
        // ---- stage V transposed: Vt[d][j] ----
        {
            const float* g = v + headoff + (size_t)(kt*64 + sj)*H_ + sd;
            float xv[16];
            *(float4*)&xv[0]  = *(const float4*)(g);
            *(float4*)&xv[4]  = *(const float4*)(g+4);
            *(float4*)&xv[8]  = *(const float4*)(g+8);
            *(float4*)&xv[12] = *(const float4*)(g+12);
            #pragma unroll
            for (int dd=0;dd<16;dd++) {
                int d = sd + dd;
                float a = xv[dd];
                unsigned short ah = f2bf(a);
                unsigned short al = f2bf(a - bf2f(ah));
                int off = d*128 + ((sj*2) ^ ((d&7)<<4));
                *(unsigned short*)(smem + VHo + off) = ah;
                *(unsigned short*)(smem + VLo + off) = al;
            }
        }
        __syncthreads();   // staged tile visible

        // ---- QK^T: S = Q·K^T (3-term split), wave w rows, 4 col-blocks ----
        f32x4 s_acc[4];
        #pragma unroll
        for (int cb=0;cb<4;cb++) {
            s_acc[cb] = (f32x4){0.f,0.f,0.f,0.f};
            int row = cb*16 + l15;
            int rsw = (row & 7) << 4;
            #pragma unroll
            for (int s=0;s<2;s++) {
                int off = row*128 + ((s*64 + l4*16) ^ rsw);
                short8v khf = *(const short8v*)(smem + KHo + off);
                short8v klf = *(const short8v*)(smem + KLo + off);
                s_acc[cb] = __builtin_amdgcn_mfma_f32_16x16x32_bf16(qh[s], khf, s_acc[cb], 0, 0, 0);
                s_acc[cb] = __builtin_amdgcn_mfma_f32_16x16x32_bf16(qh[s], klf, s_acc[cb], 0, 0, 0);
                s_acc[cb] = __builtin_amdgcn_mfma_f32_16x16x32_bf16(ql[s], khf, s_acc[cb], 0, 0, 0);
            }
        }

        // ---- online softmax: lane holds rows l4*4+j, cols cb*16+l15 ----
        float mnew[4], alpha[4];
        #pragma unroll
        for (int j=0;j<4;j++) {
            float mt = fmaxf(fmaxf(s_acc[0][j], s_acc[1][j]), fmaxf(s_acc[2][j], s_acc[3][j]));
            #pragma unroll
            for (int m=8;m;m>>=1) mt = fmaxf(mt, __shfl_xor(mt, m));
            float mn = fmaxf(mrun[j], mt);
            mnew[j] = mn;
            alpha[j] = __expf(mrun[j] - mn);
            mrun[j] = mn;
        }
        float pv[4][4];
        float ps[4] = {0.f,0.f,0.f,0.f};
        #pragma unroll
        for (int cb=0;cb<4;cb++)
            #pragma unroll
            for (int j=0;j<4;j++) {
                float p = __expf(s_acc[cb][j] - mnew[j]);
                pv[cb][j] = p;
                ps[j] += p;
            }
        #pragma unroll
        for (int j=0;j<4;j++) {
            float s = ps[j];
            #pragma unroll
            for (int m=8;m;m>>=1) s += __shfl_xor(s, m);
            lrun[j] = lrun[j]*alpha[j] + s;
        }

        // ---- split P -> wave-private LDS rows ----
        #pragma unroll
        for (int cb=0;cb<4;cb++)
            #pragma unroll
            for (int j=0;j<4;j++) {
                int prow = w*16 + l4*4 + j;
                unsigned short hh = f2bf(pv[cb][j]);
                unsigned short ll = f2bf(pv[cb][j] - bf2f(hh));
                int off = prow*128 + (((cb*16 + l15)*2) ^ ((prow&7)<<4));
                *(unsigned short*)(smem + PHo + off) = hh;
                *(unsigned short*)(smem + PLo + off) = ll;
            }
        asm volatile("s_waitcnt lgkmcnt(0)" ::: "memory");
        __builtin_amdgcn_sched_barrier(0);

        // ---- rescale ctx acc ----
        #pragma unroll
        for (int db=0;db<4;db++)
            #pragma unroll
            for (int j=0;j<4;j++) acc[db][j] *= alpha[j];

        // ---- PV: ctx += P·V (3-term split) ----
        short8v pah[2], pal[2];
        {
            int row = w*16 + l15;
            int rsw = (row & 7) << 4;
            #pragma unroll
            for (int s=0;s<2;s++) {
                int off = row*128 + ((s*64 + l4*16) ^ rsw);
                pah[s] = *(const short8v*)(smem + PHo + off);
                pal[s] = *(const short8v*)(smem + PLo + off);
            }
        }
        #pragma unroll
        for (int db=0;db<4;db++) {
            int row = db*16 + l15;
            int rsw = (row & 7) << 4;
            #pragma unroll
            for (int s=0;s<2;s++) {
                int off = row*128 + ((s*64 + l4*16) ^ rsw);
                short8v vhf = *(const short8v*)(smem + VHo + off);
                short8v vlf = *(const short8v*)(smem + VLo + off);
                acc[db] = __builtin_amdgcn_mfma_f32_16x16x32_bf16(pah[s], vhf, acc[db], 0, 0, 0);
                acc[db] = __builtin_amdgcn_mfma_f32_16x16x32_bf16(pah[s], vlf, acc[db], 0, 0, 0);
                acc[db] = __builtin_amdgcn_mfma_f32_16x16x32_bf16(pal[s], vhf, acc[db], 0, 0, 0);
            }
        }
    }

    // ---- epilogue ----
    #pragma unroll
    for (int db=0;db<4;db++)
        #pragma unroll
        for (int j=0;j<4;j++) {
            int qrow = qt*64 + w*16 + l4*4 + j;
            ctx[headoff + (size_t)qrow*H_ + db*16 + l15] = acc[db][j] / lrun[j];
        }
}

// ---------------- layernorm (residual fused, optional bf16 out) ----------------
__global__ __launch_bounds__(256) void ln_kernel(
    const float* __restrict__ a, const float* __restrict__ res,
    const float* __restrict__ g, const float* __restrict__ beta,
    float* __restrict__ out, __hip_bfloat16* __restrict__ outb)
{
    int row = blockIdx.x, tid = threadIdx.x;
    const float4 va = ((const float4*)(a + (size_t)row*H_))[tid];
    const float4 vr = ((const float4*)(res + (size_t)row*H_))[tid];
    float x0=va.x+vr.x, x1=va.y+vr.y, x2=va.z+vr.z, x3=va.w+vr.w;
    float s  = x0+x1+x2+x3;
    float ss = x0*x0 + x1*x1 + x2*x2 + x3*x3;
    #pragma unroll
    for (int off=32; off; off>>=1) { s += __shfl_xor(s, off); ss += __shfl_xor(ss, off); }
    __shared__ float red[8];
    if ((tid&63)==0) { red[tid>>6]=s; red[4+(tid>>6)]=ss; }
    __syncthreads();
    if (tid==0) { red[0]=red[0]+red[1]+red[2]+red[3]; red[4]=red[4]+red[5]+red[6]+red[7]; }
    __syncthreads();
    float mu  = red[0] * (1.f/H_);
    float var = red[4] * (1.f/H_) - mu*mu;
    float rs = rsqrtf(fmaxf(var, 0.f) + 1e-12f);
    const float4 vg = ((const float4*)g)[tid];
    const float4 vb = ((const float4*)beta)[tid];
    float4 vo;
    vo.x = (x0-mu)*rs*vg.x + vb.x;
    vo.y = (x1-mu)*rs*vg.y + vb.y;
    vo.z = (x2-mu)*rs*vg.z + vb.z;
    vo.w = (x3-mu)*rs*vg.w + vb.w;
    ((float4*)(out + (size_t)row*H_))[tid] = vo;
    if (outb) {
        unsigned int p0 = (unsigned)f2bf(vo.x) | ((unsigned)f2bf(vo.y) << 16);
        unsigned int p1 = (unsigned)f2bf(vo.z) | ((unsigned)f2bf(vo.w) << 16);
        ((uint2*)(outb + (size_t)row*H_))[tid] = make_uint2(p0, p1);
    }
}

// ---------------- router ----------------
__global__ __launch_bounds__(256) void router_kernel(
    const float* __restrict__ hs, const float* __restrict__ Wg,
    int* __restrict__ tok_e, float* __restrict__ tok_w,
    int* __restrict__ counts, float* __restrict__ P_sum)
{
    int t = blockIdx.x*4 + (threadIdx.x >> 6);
    int lane = threadIdx.x & 63;
    const float* row = hs + (size_t)t * H_;
    float acc[E_];
    #pragma unroll
    for (int e=0;e<E_;e++) acc[e]=0.f;
    for (int it=0; it<16; ++it) {
        int i = it*64 + lane;
        float xv = row[i];
        const float* wg = Wg + (size_t)i*E_;
        #pragma unroll
        for (int e=0;e<E_;e++) acc[e] = fmaf(xv, wg[e], acc[e]);
    }
    #pragma unroll
    for (int e=0;e<E_;e++) {
        float vv = acc[e];
        #pragma unroll
        for (int off=32; off; off>>=1) vv += __shfl_xor(vv, off);
        acc[e] = vv;
    }
    if (lane==0) {
        float mx = acc[0];
        #pragma unroll
        for (int e=1;e<E_;e++) mx = fmaxf(mx, acc[e]);
        float p[E_], se=0.f;
        #pragma unroll
        for (int e=0;e<E_;e++){ p[e] = expf(acc[e]-mx); se += p[e]; }
        float isv = 1.f/se;
        #pragma unroll
        for (int e=0;e<E_;e++){ p[e]*=isv; atomicAdd(&P_sum[e], p[e]); }
        int e1=0;
        #pragma unroll
        for (int e=1;e<E_;e++) if (p[e] > p[e1]) e1=e;
        int e2 = (e1==0)?1:0;
        #pragma unroll
        for (int e=0;e<E_;e++) if (e!=e1 && p[e] > p[e2]) e2=e;
        float w1=p[e1], w2=p[e2], si=1.f/(w1+w2);
        tok_e[t*2]=e1; tok_e[t*2+1]=e2;
        tok_w[t*2]=w1*si; tok_w[t*2+1]=w2*si;
        atomicAdd(&counts[e1],1); atomicAdd(&counts[e2],1);
    }
}

__global__ void router_finalize(
    const int* __restrict__ counts, const float* __restrict__ P_sum,
    int* __restrict__ base, int* __restrict__ cursor,
    int* __restrict__ cnt_pad, int* __restrict__ ntiles,
    int* __restrict__ slot_token, int* __restrict__ tile_expert,
    float* __restrict__ aux_out)
{
    __shared__ int sbase[E_+1];
    if (threadIdx.x == 0) {
        int bacc = 0;
        float aux = 0.f;
        for (int e=0;e<E_;e++) {
            sbase[e] = bacc; base[e] = bacc;
            int cp = (counts[e] + 127) & ~127;
            cnt_pad[e] = cp;
            bacc += cp;
            cursor[e] = 0;
            aux += ((float)counts[e]/(float)T_) * (P_sum[e]/(float)T_);
        }
        sbase[E_] = bacc;
        *ntiles = bacc >> 7;
        *aux_out = (float)E_ * aux;
    }
    __syncthreads();
    for (int sIdx = (int)threadIdx.x; sIdx < MAXSLOTS; sIdx += (int)blockDim.x)
        slot_token[sIdx] = -1;
    for (int tt = (int)threadIdx.x; tt < MAXTILES; tt += (int)blockDim.x) {
        int s = tt*128;
        int e = E_-1;
        for (int qe=0; qe<E_; ++qe) if (s < sbase[qe+1]) { e = qe; break; }
        tile_expert[tt] = e;
    }
}

__global__ void scatter_slots(
    const int* __restrict__ tok_e, const float* __restrict__ tok_w,
    const int* __restrict__ base, int* __restrict__ cursor,
    int* __restrict__ slot_token, float* __restrict__ slot_w)
{
    int t = blockIdx.x*blockDim.x + threadIdx.x;
    if (t >= T_) return;
    #pragma unroll
    for (int j=0;j<2;j++) {
        int e = tok_e[t*2+j];
        int pos = atomicAdd(&cursor[e], 1);
        int s = base[e] + pos;
        slot_token[s] = t;
        slot_w[s] = tok_w[t*2+j];
    }
}

extern "C" void kernel_launch(void* const* d_in, const int* in_sizes, int n_in,
                              void* d_out, int out_size, void* d_ws, size_t ws_size,
                              hipStream_t stream)
{
    const float* x    = (const float*)d_in[0];
    const float* Wq   = (const float*)d_in[1];
    const float* Wk   = (const float*)d_in[2];
    const float* Wv   = (const float*)d_in[3];
    const float* Wd   = (const float*)d_in[4];
    const float* bd   = (const float*)d_in[5];
    const float* ln1g = (const float*)d_in[6];
    const float* ln1b = (const float*)d_in[7];
    const float* Wg   = (const float*)d_in[8];
    const float* W1   = (const float*)d_in[9];
    const float* W2   = (const float*)d_in[10];
    const float* ln2g = (const float*)d_in[11];
    const float* ln2b = (const float*)d_in[12];
    float* out = (float*)d_out;

    float* f0 = (float*)d_ws;
    const size_t M1 = 1u << 20;
    float* qb   = f0;            // q -> attn_out
    float* kb   = f0 + 4*M1;     // k -> hs
    float* vb   = f0 + 8*M1;     // v -> moe_out
    float* ctxb = f0 + 12*M1;
    __hip_bfloat16* hs_b = (__hip_bfloat16*)(f0 + 16*M1);

    float* misc = f0 + 18*M1;
    int*   misc_i = (int*)misc;
    int*   tok_e   = misc_i;
    float* tok_w   = misc + 8192;
    int*   slot_tok= misc_i + 16384;
    float* slot_w  = misc + 25600;
    int*   counts  = misc_i + 34816;
    float* P_sum   = misc + 34824;
    int*   cursor  = misc_i + 34832;
    int*   basep   = misc_i + 34840;
    int*   cnt_pad = misc_i + 34848;
    int*   ntiles  = misc_i + 34856;
    int*   tile_ex = misc_i + 34857;

    float* wreg = f0 + 18*M1 + 65536;
    const bool FULL = ws_size >= (size_t)300*1024*1024;

    dim3 blk(256);
    dim3 blk128(128);

    gemm_f32<0><<<dim3(H_/64, T_/64), blk128, 0, stream>>>(x, Wq, qb, nullptr, H_, H_);
    gemm_f32<0><<<dim3(H_/64, T_/64), blk128, 0, stream>>>(x, Wk, kb, nullptr, H_, H_);
    gemm_f32<0><<<dim3(H_/64, T_/64), blk128, 0, stream>>>(x, Wv, vb, nullptr, H_, H_);

    rope_kernel<<<(T_*NH_*32)/256, blk, 0, stream>>>(qb, kb);

    attn_mfma<<<dim3(S_/64, NH_, B_), blk, 0, stream>>>(qb, kb, vb, ctxb);

    gemm_f32<1><<<dim3(H_/64, T_/64), blk128, 0, stream>>>(ctxb, Wd, qb, bd, H_, H_);

    zero_kernel<<<(T_*H_)/256, blk, 0, stream>>>(vb, T_*H_);
    zero_kernel<<<1, blk, 0, stream>>>(misc + 34816, 16);

    ln_kernel<<<T_, blk, 0, stream>>>(qb, x, ln1g, ln1b, kb, hs_b);

    router_kernel<<<T_/4, blk, 0, stream>>>(kb, Wg, tok_e, tok_w, counts, P_sum);
    router_finalize<<<1, blk, 0, stream>>>(counts, P_sum, basep, cursor, cnt_pad, ntiles,
                                           slot_tok, tile_ex, out + (size_t)T_*H_);
    scatter_slots<<<T_/256, blk, 0, stream>>>(tok_e, tok_w, basep, cursor, slot_tok, slot_w);

    if (FULL) {
        __hip_bfloat16* W1t = (__hip_bfloat16*)wreg;
        __hip_bfloat16* W2t = (__hip_bfloat16*)(wreg + 16*M1);
        __hip_bfloat16* y1  = (__hip_bfloat16*)(wreg + 32*M1);
        transpose_bf16<<<dim3(I_/64, H_/64, E_), blk, 0, stream>>>(W1, W1t, H_, I_);
        transpose_bf16<<<dim3(H_/64, I_/64, E_), blk, 0, stream>>>(W2, W2t, I_, H_);
        moe_mfma<2,false><<<dim3(I_/128, MAXTILES), blk, 0, stream>>>(
            hs_b, W1t, y1, nullptr, slot_tok, slot_w, tile_ex, ntiles, nullptr, I_, H_);
        moe_mfma<3,false><<<dim3(H_/128, MAXTILES), blk, 0, stream>>>(
            y1, W2t, nullptr, vb, slot_tok, slot_w, tile_ex, ntiles, nullptr, H_, I_);
    } else {
        __hip_bfloat16* w1t = (__hip_bfloat16*)wreg;
        __hip_bfloat16* w2t = (__hip_bfloat16*)(wreg + 2*M1);
        __hip_bfloat16* y1  = (__hip_bfloat16*)(wreg + 4*M1);
        for (int e=0; e<E_; ++e) {
            transpose_bf16<<<dim3(I_/64, H_/64, 1), blk, 0, stream>>>(W1 + (size_t)e*H_*I_, w1t, H_, I_);
            moe_mfma<2,true><<<dim3(I_/128, 32), blk, 0, stream>>>(
                hs_b, w1t, y1, nullptr, slot_tok, slot_w, nullptr, cnt_pad+e, basep+e, I_, H_);
            transpose_bf16<<<dim3(H_/64, I_/64, 1), blk, 0, stream>>>(W2 + (size_t)e*I_*H_, w2t, I_, H_);
            moe_mfma<3,true><<<dim3(H_/128, 32), blk, 0, stream>>>(
                y1, w2t, nullptr, vb, slot_tok, slot_w, nullptr, cnt_pad+e, basep+e, H_, I_);
        }
    }

    ln_kernel<<<T_, blk, 0, stream>>>(vb, kb, ln2g, ln2b, out, nullptr);
}

// Round 5
// 940.400 us; speedup vs baseline: 6.4304x; 1.8905x over previous
//
#include <hip/hip_runtime.h>
#include <hip/hip_bf16.h>
#include <math.h>

#define H_ 1024
#define NH_ 16
#define HD_ 64
#define I_ 4096
#define E_ 8
#define B_ 2
#define S_ 2048
#define T_ 4096

#define MAXSLOTS 9216   // 2*T + 8*128 pad
#define MAXTILES 72     // MAXSLOTS/128

typedef __attribute__((ext_vector_type(8))) short short8v;
typedef __attribute__((ext_vector_type(4))) float f32x4;

#define GLOAD16(g, l) __builtin_amdgcn_global_load_lds((const __attribute__((address_space(1))) void*)(g), (__attribute__((address_space(3))) void*)(l), 16, 0, 0)

static __device__ inline unsigned short f2bf(float x) {
    __hip_bfloat16 h = __float2bfloat16(x);
    unsigned short u;
    __builtin_memcpy(&u, &h, 2);
    return u;
}
static __device__ inline float bf2f(unsigned short u) {
    __hip_bfloat16 h;
    __builtin_memcpy(&h, &u, 2);
    return __bfloat162float(h);
}

// ---------------- zero ----------------
__global__ void zero_kernel(float* __restrict__ p, int n) {
    int i = blockIdx.x * blockDim.x + threadIdx.x;
    if (i < n) p[i] = 0.f;
}

// ---------------- fp32 -> bf16 hi/lo split (elementwise) ----------------
__global__ __launch_bounds__(256) void split_bf16(
    const float* __restrict__ in, __hip_bfloat16* __restrict__ hi,
    __hip_bfloat16* __restrict__ lo, int n4)
{
    int i = blockIdx.x * blockDim.x + threadIdx.x;
    if (i >= n4) return;
    float4 v = ((const float4*)in)[i];
    unsigned short h0 = f2bf(v.x), h1 = f2bf(v.y), h2 = f2bf(v.z), h3 = f2bf(v.w);
    unsigned short l0 = f2bf(v.x - bf2f(h0)), l1 = f2bf(v.y - bf2f(h1));
    unsigned short l2 = f2bf(v.z - bf2f(h2)), l3 = f2bf(v.w - bf2f(h3));
    uint2 ph = make_uint2((unsigned)h0 | ((unsigned)h1 << 16), (unsigned)h2 | ((unsigned)h3 << 16));
    uint2 pl = make_uint2((unsigned)l0 | ((unsigned)l1 << 16), (unsigned)l2 | ((unsigned)l3 << 16));
    *(uint2*)((char*)hi + (size_t)i*8) = ph;
    *(uint2*)((char*)lo + (size_t)i*8) = pl;
}

// ---------------- transpose + split: in [K][N] f32 -> hi,lo [N][K] bf16 ----------------
__global__ __launch_bounds__(256) void transpose_split_bf16(
    const float* __restrict__ in, __hip_bfloat16* __restrict__ oh,
    __hip_bfloat16* __restrict__ ol, int K, int N)
{
    __shared__ float t[64][65];
    int k0 = blockIdx.y*64, n0 = blockIdx.x*64;
    int tid = threadIdx.x;
    #pragma unroll
    for (int it=0; it<16; ++it) {
        int lin = it*256 + tid;
        int r = lin >> 6, c = lin & 63;
        t[r][c] = in[(size_t)(k0+r)*N + n0 + c];
    }
    __syncthreads();
    #pragma unroll
    for (int it=0; it<16; ++it) {
        int lin = it*256 + tid;
        int r = lin >> 6, c = lin & 63;   // r = n-local, c = k-local
        float v = t[c][r];
        unsigned short hh = f2bf(v);
        unsigned short ll = f2bf(v - bf2f(hh));
        size_t o = (size_t)(n0+r)*K + k0 + c;
        oh[o] = *(__hip_bfloat16*)&hh;
        ol[o] = *(__hip_bfloat16*)&ll;
    }
}

// ---------------- transpose + f32->bf16: in [K][N] -> out [N][K] (MoE weights) ----------------
__global__ __launch_bounds__(256) void transpose_bf16(
    const float* __restrict__ in, __hip_bfloat16* __restrict__ outp, int K, int N)
{
    __shared__ float t[64][65];
    size_t eoff = (size_t)blockIdx.z * (size_t)K * (size_t)N;
    int k0 = blockIdx.y*64, n0 = blockIdx.x*64;
    int tid = threadIdx.x;
    #pragma unroll
    for (int it=0; it<16; ++it) {
        int lin = it*256 + tid;
        int r = lin >> 6, c = lin & 63;
        t[r][c] = in[eoff + (size_t)(k0+r)*N + n0 + c];
    }
    __syncthreads();
    #pragma unroll
    for (int it=0; it<16; ++it) {
        int lin = it*256 + tid;
        int r = lin >> 6, c = lin & 63;
        outp[eoff + (size_t)(n0+r)*K + k0 + c] = __float2bfloat16(t[c][r]);
    }
}

// ---------------- bf16x3 GEMM: C = A@B (+bias), fp32-accurate ----------------
// A split hi/lo [M][K] bf16; B^T split hi/lo [N][K] bf16. 128x128 tile, BK=64.
template<bool BIAS>
__global__ __launch_bounds__(256, 2) void gemm_bf16x3(
    const __hip_bfloat16* __restrict__ Ah, const __hip_bfloat16* __restrict__ Al,
    const __hip_bfloat16* __restrict__ Bh, const __hip_bfloat16* __restrict__ Bl,
    float* __restrict__ C, const float* __restrict__ bias, int N, int K)
{
    const int tid = threadIdx.x;
    const int w = tid >> 6, lane = tid & 63;
    const int bx = blockIdx.x, by = blockIdx.y;

    __shared__ __align__(16) char smem[65536];
    const int AH = 0, AL = 16384, BH = 32768, BL = 49152;

    const int laneg = lane >> 3;
    const int k2sw = ((lane & 7) ^ laneg) << 4;
    const int l15 = lane & 15, l4 = lane >> 4;
    const int wr = w >> 1, wc = w & 1;

    f32x4 acc[4][4];
    #pragma unroll
    for (int m=0;m<4;m++)
        #pragma unroll
        for (int n=0;n<4;n++) acc[m][n] = (f32x4){0.f,0.f,0.f,0.f};

    for (int k0 = 0; k0 < K; k0 += 64) {
        __syncthreads();
        #pragma unroll
        for (int qq=0;qq<4;qq++) {
            int arow = by*128 + (w*4+qq)*8 + laneg;
            int brow = bx*128 + (w*4+qq)*8 + laneg;
            size_t aoff = ((size_t)arow*K + k0)*2 + k2sw;
            size_t boff = ((size_t)brow*K + k0)*2 + k2sw;
            GLOAD16((const char*)Ah + aoff, smem + AH + (w*4+qq)*1024);
            GLOAD16((const char*)Al + aoff, smem + AL + (w*4+qq)*1024);
            GLOAD16((const char*)Bh + boff, smem + BH + (w*4+qq)*1024);
            GLOAD16((const char*)Bl + boff, smem + BL + (w*4+qq)*1024);
        }
        __syncthreads();

        short8v ahf[4][2], alf[4][2], bhf[4][2], blf[4][2];
        #pragma unroll
        for (int m=0;m<4;m++) {
            int row = wr*64 + m*16 + l15;
            int rb = row << 7, rsw = (row & 7) << 4;
            #pragma unroll
            for (int s=0;s<2;s++) {
                int off = rb + ((s*64 + (l4<<4)) ^ rsw);
                ahf[m][s] = *(const short8v*)(smem + AH + off);
                alf[m][s] = *(const short8v*)(smem + AL + off);
            }
        }
        #pragma unroll
        for (int n=0;n<4;n++) {
            int row = wc*64 + n*16 + l15;
            int rb = row << 7, rsw = (row & 7) << 4;
            #pragma unroll
            for (int s=0;s<2;s++) {
                int off = rb + ((s*64 + (l4<<4)) ^ rsw);
                bhf[n][s] = *(const short8v*)(smem + BH + off);
                blf[n][s] = *(const short8v*)(smem + BL + off);
            }
        }
        #pragma unroll
        for (int m=0;m<4;m++)
            #pragma unroll
            for (int n=0;n<4;n++)
                #pragma unroll
                for (int s=0;s<2;s++) {
                    acc[m][n] = __builtin_amdgcn_mfma_f32_16x16x32_bf16(ahf[m][s], bhf[n][s], acc[m][n], 0, 0, 0);
                    acc[m][n] = __builtin_amdgcn_mfma_f32_16x16x32_bf16(ahf[m][s], blf[n][s], acc[m][n], 0, 0, 0);
                    acc[m][n] = __builtin_amdgcn_mfma_f32_16x16x32_bf16(alf[m][s], bhf[n][s], acc[m][n], 0, 0, 0);
                }
    }

    #pragma unroll
    for (int m=0;m<4;m++)
        #pragma unroll
        for (int j=0;j<4;j++) {
            int orow = by*128 + wr*64 + m*16 + l4*4 + j;
            #pragma unroll
            for (int n=0;n<4;n++) {
                int ocol = bx*128 + wc*64 + n*16 + l15;
                float v = acc[m][n][j];
                if (BIAS) v += bias[ocol];
                C[(size_t)orow*N + ocol] = v;
            }
        }
}

// ---------------- MFMA MoE GEMM (unchanged, verified) ----------------
template<int MODE, bool PE>
__global__ __launch_bounds__(256) void moe_mfma(
    const __hip_bfloat16* __restrict__ A,
    const __hip_bfloat16* __restrict__ Bt,
    __hip_bfloat16* __restrict__ y1,
    float* __restrict__ moe_out,
    const int* __restrict__ slot_token,
    const float* __restrict__ slot_w,
    const int* __restrict__ tile_expert,
    const int* __restrict__ cnt_ptr,
    const int* __restrict__ base_ptr,
    int N, int K)
{
    const int tid = threadIdx.x;
    const int w = tid >> 6, lane = tid & 63;
    const int bx = blockIdx.x;

    int slot0, y1row0;
    const __hip_bfloat16* Bp;
    if (PE) {
        int tloc = blockIdx.y;
        if ((tloc << 7) >= *cnt_ptr) return;
        slot0 = *base_ptr + (tloc << 7);
        y1row0 = tloc << 7;
        Bp = Bt;
    } else {
        int gt = blockIdx.y;
        if (gt >= *cnt_ptr) return;
        int e = tile_expert[gt];
        Bp = Bt + (size_t)e * (size_t)K * (size_t)N;
        slot0 = gt << 7;
        y1row0 = gt << 7;
    }

    __shared__ __align__(16) char smem[32768];

    const int laneg = lane >> 3;
    const int k2sw = ((lane & 7) ^ laneg) << 4;

    int tokq[4];
    if (MODE == 2) {
        #pragma unroll
        for (int qq=0;qq<4;qq++) {
            int t0 = slot_token[slot0 + (w*4+qq)*8 + laneg];
            tokq[qq] = t0 < 0 ? 0 : t0;
        }
    }

    f32x4 acc[4][4];
    #pragma unroll
    for (int m=0;m<4;m++)
        #pragma unroll
        for (int n=0;n<4;n++) acc[m][n] = (f32x4){0.f,0.f,0.f,0.f};

    const int l15 = lane & 15;
    const int l4  = lane >> 4;
    const int wr = w >> 1, wc = w & 1;

    for (int k0 = 0; k0 < K; k0 += 64) {
        __syncthreads();
        #pragma unroll
        for (int qq=0;qq<4;qq++) {
            const char* ga;
            if (MODE == 2) {
                ga = (const char*)A + (((size_t)tokq[qq])*K + k0)*2 + k2sw;
            } else {
                int row = y1row0 + (w*4+qq)*8 + laneg;
                ga = (const char*)A + ((size_t)row*K + k0)*2 + k2sw;
            }
            GLOAD16(ga, smem + (w*4+qq)*1024);
        }
        #pragma unroll
        for (int qq=0;qq<4;qq++) {
            int row = bx*128 + (w*4+qq)*8 + laneg;
            const char* gb = (const char*)Bp + ((size_t)row*K + k0)*2 + k2sw;
            GLOAD16(gb, smem + 16384 + (w*4+qq)*1024);
        }
        __syncthreads();

        short8v a_frag[4][2], b_frag[4][2];
        #pragma unroll
        for (int m=0;m<4;m++) {
            int row = wr*64 + m*16 + l15;
            int rb = row << 7;
            #pragma unroll
            for (int s=0;s<2;s++) {
                int off = rb + ((s*64 + (l4<<4)) ^ ((row&7)<<4));
                a_frag[m][s] = *(const short8v*)(smem + off);
            }
        }
        #pragma unroll
        for (int n=0;n<4;n++) {
            int row = wc*64 + n*16 + l15;
            int rb = row << 7;
            #pragma unroll
            for (int s=0;s<2;s++) {
                int off = rb + ((s*64 + (l4<<4)) ^ ((row&7)<<4));
                b_frag[n][s] = *(const short8v*)(smem + 16384 + off);
            }
        }
        #pragma unroll
        for (int m=0;m<4;m++)
            #pragma unroll
            for (int n=0;n<4;n++) {
                acc[m][n] = __builtin_amdgcn_mfma_f32_16x16x32_bf16(a_frag[m][0], b_frag[n][0], acc[m][n], 0, 0, 0);
                acc[m][n] = __builtin_amdgcn_mfma_f32_16x16x32_bf16(a_frag[m][1], b_frag[n][1], acc[m][n], 0, 0, 0);
            }
    }

    #pragma unroll
    for (int m=0;m<4;m++) {
        #pragma unroll
        for (int j=0;j<4;j++) {
            int orow = wr*64 + m*16 + l4*4 + j;
            if (MODE == 3) {
                int slot = slot0 + orow;
                int tok = slot_token[slot];
                if (tok < 0) continue;
                float sw = slot_w[slot];
                #pragma unroll
                for (int n=0;n<4;n++) {
                    int ocol = bx*128 + wc*64 + n*16 + l15;
                    atomicAdd(&moe_out[(size_t)tok*H_ + ocol], sw * acc[m][n][j]);
                }
            } else {
                #pragma unroll
                for (int n=0;n<4;n++) {
                    int ocol = bx*128 + wc*64 + n*16 + l15;
                    float val = acc[m][n][j];
                    float g = 0.5f*val*(1.f + erff(val*0.70710678118654752f));
                    y1[(size_t)(y1row0 + orow)*N + ocol] = __float2bfloat16(g);
                }
            }
        }
    }
}

// ---------------- RoPE (in-place on q,k; fp32) ----------------
__global__ void rope_kernel(float* __restrict__ q, float* __restrict__ k) {
    int idx = blockIdx.x * blockDim.x + threadIdx.x;
    int i = idx & 31;
    int n = (idx >> 5) & (NH_-1);
    int t = idx >> 9;
    int pos = t & (S_ - 1);
    float inv = exp2f((float)i * (-13.287712379549449f / 32.f));
    float ang = (float)pos * inv;
    float c = cosf(ang), s = sinf(ang);
    size_t base = (size_t)t*H_ + (size_t)n*64;
    float q1 = q[base+i], q2 = q[base+i+32];
    q[base+i]    = q1*c - q2*s;
    q[base+i+32] = q2*c + q1*s;
    float k1 = k[base+i], k2 = k[base+i+32];
    k[base+i]    = k1*c - k2*s;
    k[base+i+32] = k2*c + k1*s;
}

// ---------------- MFMA attention: bf16x3 split (verified round 4) ----------------
__global__ __launch_bounds__(256, 3) void attn_mfma(
    const float* __restrict__ q, const float* __restrict__ k,
    const float* __restrict__ v, float* __restrict__ ctx)
{
    const int qt = blockIdx.x;
    const int hn = blockIdx.y;
    const int b  = blockIdx.z;
    const int tid = threadIdx.x;
    const int w = tid >> 6, lane = tid & 63;
    const int l15 = lane & 15, l4 = lane >> 4;

    __shared__ __align__(16) char smem[49152];
    const int KHo = 0, KLo = 8192, VHo = 16384, VLo = 24576, PHo = 32768, PLo = 40960;

    const size_t headoff = (size_t)b*S_*H_ + (size_t)hn*64;

    const int sj = w*16 + l15;
    const int sd = l4*16;
    const int swz_j = (sj & 7) << 4;

    {
        const float* g = q + headoff + (size_t)(qt*64 + sj)*H_ + sd;
        float xv[16];
        *(float4*)&xv[0]  = *(const float4*)(g);
        *(float4*)&xv[4]  = *(const float4*)(g+4);
        *(float4*)&xv[8]  = *(const float4*)(g+8);
        *(float4*)&xv[12] = *(const float4*)(g+12);
        #pragma unroll
        for (int i=0;i<8;i++) {
            float a = xv[2*i]*0.125f, b2 = xv[2*i+1]*0.125f;
            unsigned short ah = f2bf(a), bh = f2bf(b2);
            unsigned short al = f2bf(a - bf2f(ah)), bl = f2bf(b2 - bf2f(bh));
            int off = sj*128 + ((l4*32 + 4*i) ^ swz_j);
            *(unsigned*)(smem + PHo + off) = (unsigned)ah | ((unsigned)bh << 16);
            *(unsigned*)(smem + PLo + off) = (unsigned)al | ((unsigned)bl << 16);
        }
    }
    asm volatile("s_waitcnt lgkmcnt(0)" ::: "memory");
    short8v qh[2], ql[2];
    {
        int row = w*16 + l15;
        int rsw = (row & 7) << 4;
        #pragma unroll
        for (int s=0;s<2;s++) {
            int off = row*128 + ((s*64 + l4*16) ^ rsw);
            qh[s] = *(const short8v*)(smem + PHo + off);
            ql[s] = *(const short8v*)(smem + PLo + off);
        }
    }

    f32x4 acc[4];
    #pragma unroll
    for (int db=0;db<4;db++) acc[db] = (f32x4){0.f,0.f,0.f,0.f};
    float mrun[4], lrun[4];
    #pragma unroll
    for (int j=0;j<4;j++) { mrun[j] = -1e30f; lrun[j] = 0.f; }

    for (int kt=0; kt<S_/64; ++kt) {
        __syncthreads();
        {
            const float* g = k + headoff + (size_t)(kt*64 + sj)*H_ + sd;
            float xv[16];
            *(float4*)&xv[0]  = *(const float4*)(g);
            *(float4*)&xv[4]  = *(const float4*)(g+4);
            *(float4*)&xv[8]  = *(const float4*)(g+8);
            *(float4*)&xv[12] = *(const float4*)(g+12);
            #pragma unroll
            for (int i=0;i<8;i++) {
                float a = xv[2*i], b2 = xv[2*i+1];
                unsigned short ah = f2bf(a), bh = f2bf(b2);
                unsigned short al = f2bf(a - bf2f(ah)), bl = f2bf(b2 - bf2f(bh));
                int off = sj*128 + ((l4*32 + 4*i) ^ swz_j);
                *(unsigned*)(smem + KHo + off) = (unsigned)ah | ((unsigned)bh << 16);
                *(unsigned*)(smem + KLo + off) = (unsigned)al | ((unsigned)bl << 16);
            }
        }
        {
            const float* g = v + headoff + (size_t)(kt*64 + sj)*H_ + sd;
            float xv[16];
            *(float4*)&xv[0]  = *(const float4*)(g);
            *(float4*)&xv[4]  = *(const float4*)(g+4);
            *(float4*)&xv[8]  = *(const float4*)(g+8);
            *(float4*)&xv[12] = *(const float4*)(g+12);
            #pragma unroll
            for (int dd=0;dd<16;dd++) {
                int d = sd + dd;
                float a = xv[dd];
                unsigned short ah = f2bf(a);
                unsigned short al = f2bf(a - bf2f(ah));
                int off = d*128 + ((sj*2) ^ ((d&7)<<4));
                *(unsigned short*)(smem + VHo + off) = ah;
                *(unsigned short*)(smem + VLo + off) = al;
            }
        }
        __syncthreads();

        f32x4 s_acc[4];
        #pragma unroll
        for (int cb=0;cb<4;cb++) {
            s_acc[cb] = (f32x4){0.f,0.f,0.f,0.f};
            int row = cb*16 + l15;
            int rsw = (row & 7) << 4;
            #pragma unroll
            for (int s=0;s<2;s++) {
                int off = row*128 + ((s*64 + l4*16) ^ rsw);
                short8v khf = *(const short8v*)(smem + KHo + off);
                short8v klf = *(const short8v*)(smem + KLo + off);
                s_acc[cb] = __builtin_amdgcn_mfma_f32_16x16x32_bf16(qh[s], khf, s_acc[cb], 0, 0, 0);
                s_acc[cb] = __builtin_amdgcn_mfma_f32_16x16x32_bf16(qh[s], klf, s_acc[cb], 0, 0, 0);
                s_acc[cb] = __builtin_amdgcn_mfma_f32_16x16x32_bf16(ql[s], khf, s_acc[cb], 0, 0, 0);
            }
        }

        float mnew[4], alpha[4];
        #pragma unroll
        for (int j=0;j<4;j++) {
            float mt = fmaxf(fmaxf(s_acc[0][j], s_acc[1][j]), fmaxf(s_acc[2][j], s_acc[3][j]));
            #pragma unroll
            for (int m=8;m;m>>=1) mt = fmaxf(mt, __shfl_xor(mt, m));
            float mn = fmaxf(mrun[j], mt);
            mnew[j] = mn;
            alpha[j] = __expf(mrun[j] - mn);
            mrun[j] = mn;
        }
        float pv[4][4];
        float ps[4] = {0.f,0.f,0.f,0.f};
        #pragma unroll
        for (int cb=0;cb<4;cb++)
            #pragma unroll
            for (int j=0;j<4;j++) {
                float p = __expf(s_acc[cb][j] - mnew[j]);
                pv[cb][j] = p;
                ps[j] += p;
            }
        #pragma unroll
        for (int j=0;j<4;j++) {
            float s = ps[j];
            #pragma unroll
            for (int m=8;m;m>>=1) s += __shfl_xor(s, m);
            lrun[j] = lrun[j]*alpha[j] + s;
        }

        #pragma unroll
        for (int cb=0;cb<4;cb++)
            #pragma unroll
            for (int j=0;j<4;j++) {
                int prow = w*16 + l4*4 + j;
                unsigned short hh = f2bf(pv[cb][j]);
                unsigned short ll = f2bf(pv[cb][j] - bf2f(hh));
                int off = prow*128 + (((cb*16 + l15)*2) ^ ((prow&7)<<4));
                *(unsigned short*)(smem + PHo + off) = hh;
                *(unsigned short*)(smem + PLo + off) = ll;
            }
        asm volatile("s_waitcnt lgkmcnt(0)" ::: "memory");
        __builtin_amdgcn_sched_barrier(0);

        #pragma unroll
        for (int db=0;db<4;db++)
            #pragma unroll
            for (int j=0;j<4;j++) acc[db][j] *= alpha[j];

        short8v pah[2], pal[2];
        {
            int row = w*16 + l15;
            int rsw = (row & 7) << 4;
            #pragma unroll
            for (int s=0;s<2;s++) {
                int off = row*128 + ((s*64 + l4*16) ^ rsw);
                pah[s] = *(const short8v*)(smem + PHo + off);
                pal[s] = *(const short8v*)(smem + PLo + off);
            }
        }
        #pragma unroll
        for (int db=0;db<4;db++) {
            int row = db*16 + l15;
            int rsw = (row & 7) << 4;
            #pragma unroll
            for (int s=0;s<2;s++) {
                int off = row*128 + ((s*64 + l4*16) ^ rsw);
                short8v vhf = *(const short8v*)(smem + VHo + off);
                short8v vlf = *(const short8v*)(smem + VLo + off);
                acc[db] = __builtin_amdgcn_mfma_f32_16x16x32_bf16(pah[s], vhf, acc[db], 0, 0, 0);
                acc[db] = __builtin_amdgcn_mfma_f32_16x16x32_bf16(pah[s], vlf, acc[db], 0, 0, 0);
                acc[db] = __builtin_amdgcn_mfma_f32_16x16x32_bf16(pal[s], vhf, acc[db], 0, 0, 0);
            }
        }
    }

    #pragma unroll
    for (int db=0;db<4;db++)
        #pragma unroll
        for (int j=0;j<4;j++) {
            int qrow = qt*64 + w*16 + l4*4 + j;
            ctx[headoff + (size_t)qrow*H_ + db*16 + l15] = acc[db][j] / lrun[j];
        }
}

// ---------------- layernorm (residual fused, optional bf16 out) ----------------
__global__ __launch_bounds__(256) void ln_kernel(
    const float* __restrict__ a, const float* __restrict__ res,
    const float* __restrict__ g, const float* __restrict__ beta,
    float* __restrict__ out, __hip_bfloat16* __restrict__ outb)
{
    int row = blockIdx.x, tid = threadIdx.x;
    const float4 va = ((const float4*)(a + (size_t)row*H_))[tid];
    const float4 vr = ((const float4*)(res + (size_t)row*H_))[tid];
    float x0=va.x+vr.x, x1=va.y+vr.y, x2=va.z+vr.z, x3=va.w+vr.w;
    float s  = x0+x1+x2+x3;
    float ss = x0*x0 + x1*x1 + x2*x2 + x3*x3;
    #pragma unroll
    for (int off=32; off; off>>=1) { s += __shfl_xor(s, off); ss += __shfl_xor(ss, off); }
    __shared__ float red[8];
    if ((tid&63)==0) { red[tid>>6]=s; red[4+(tid>>6)]=ss; }
    __syncthreads();
    if (tid==0) { red[0]=red[0]+red[1]+red[2]+red[3]; red[4]=red[4]+red[5]+red[6]+red[7]; }
    __syncthreads();
    float mu  = red[0] * (1.f/H_);
    float var = red[4] * (1.f/H_) - mu*mu;
    float rs = rsqrtf(fmaxf(var, 0.f) + 1e-12f);
    const float4 vg = ((const float4*)g)[tid];
    const float4 vb = ((const float4*)beta)[tid];
    float4 vo;
    vo.x = (x0-mu)*rs*vg.x + vb.x;
    vo.y = (x1-mu)*rs*vg.y + vb.y;
    vo.z = (x2-mu)*rs*vg.z + vb.z;
    vo.w = (x3-mu)*rs*vg.w + vb.w;
    ((float4*)(out + (size_t)row*H_))[tid] = vo;
    if (outb) {
        unsigned int p0 = (unsigned)f2bf(vo.x) | ((unsigned)f2bf(vo.y) << 16);
        unsigned int p1 = (unsigned)f2bf(vo.z) | ((unsigned)f2bf(vo.w) << 16);
        ((uint2*)(outb + (size_t)row*H_))[tid] = make_uint2(p0, p1);
    }
}

// ---------------- router: 64 blocks x 64 tokens, register-accumulated stats ----------------
__global__ __launch_bounds__(256) void router_kernel(
    const float* __restrict__ hs, const float* __restrict__ Wg,
    int* __restrict__ tok_e, float* __restrict__ tok_w,
    int* __restrict__ counts, float* __restrict__ P_sum)
{
    const int w = threadIdx.x >> 6, lane = threadIdx.x & 63;
    float psum[E_];
    int cnt[E_];
    #pragma unroll
    for (int e=0;e<E_;e++){ psum[e]=0.f; cnt[e]=0; }

    for (int it=0; it<16; ++it) {
        int t = blockIdx.x*64 + it*4 + w;
        const float* row = hs + (size_t)t * H_;
        float acc[E_];
        #pragma unroll
        for (int e=0;e<E_;e++) acc[e]=0.f;
        for (int i16=0; i16<16; ++i16) {
            int i = i16*64 + lane;
            float xv = row[i];
            const float* wg = Wg + (size_t)i*E_;
            #pragma unroll
            for (int e=0;e<E_;e++) acc[e] = fmaf(xv, wg[e], acc[e]);
        }
        #pragma unroll
        for (int e=0;e<E_;e++) {
            float vv = acc[e];
            #pragma unroll
            for (int off=32; off; off>>=1) vv += __shfl_xor(vv, off);
            acc[e] = vv;
        }
        float mx = acc[0];
        #pragma unroll
        for (int e=1;e<E_;e++) mx = fmaxf(mx, acc[e]);
        float p[E_], se=0.f;
        #pragma unroll
        for (int e=0;e<E_;e++){ p[e] = __expf(acc[e]-mx); se += p[e]; }
        float isv = 1.f/se;
        #pragma unroll
        for (int e=0;e<E_;e++){ p[e]*=isv; psum[e] += p[e]; }
        int e1=0;
        #pragma unroll
        for (int e=1;e<E_;e++) if (p[e] > p[e1]) e1=e;
        int e2 = (e1==0)?1:0;
        #pragma unroll
        for (int e=0;e<E_;e++) if (e!=e1 && p[e] > p[e2]) e2=e;
        #pragma unroll
        for (int e=0;e<E_;e++) cnt[e] += (e==e1?1:0) + (e==e2?1:0);
        if (lane==0) {
            float w1=p[e1], w2=p[e2], si=1.f/(w1+w2);
            tok_e[t*2]=e1; tok_e[t*2+1]=e2;
            tok_w[t*2]=w1*si; tok_w[t*2+1]=w2*si;
        }
    }
    if (lane==0) {
        #pragma unroll
        for (int e=0;e<E_;e++) {
            atomicAdd(&P_sum[e], psum[e]);
            atomicAdd(&counts[e], cnt[e]);
        }
    }
}

__global__ void router_finalize(
    const int* __restrict__ counts, const float* __restrict__ P_sum,
    int* __restrict__ base, int* __restrict__ cursor,
    int* __restrict__ cnt_pad, int* __restrict__ ntiles,
    int* __restrict__ slot_token, int* __restrict__ tile_expert,
    float* __restrict__ aux_out)
{
    __shared__ int sbase[E_+1];
    if (threadIdx.x == 0) {
        int bacc = 0;
        float aux = 0.f;
        for (int e=0;e<E_;e++) {
            sbase[e] = bacc; base[e] = bacc;
            int cp = (counts[e] + 127) & ~127;
            cnt_pad[e] = cp;
            bacc += cp;
            cursor[e] = 0;
            aux += ((float)counts[e]/(float)T_) * (P_sum[e]/(float)T_);
        }
        sbase[E_] = bacc;
        *ntiles = bacc >> 7;
        *aux_out = (float)E_ * aux;
    }
    __syncthreads();
    for (int sIdx = (int)threadIdx.x; sIdx < MAXSLOTS; sIdx += (int)blockDim.x)
        slot_token[sIdx] = -1;
    for (int tt = (int)threadIdx.x; tt < MAXTILES; tt += (int)blockDim.x) {
        int s = tt*128;
        int e = E_-1;
        for (int qe=0; qe<E_; ++qe) if (s < sbase[qe+1]) { e = qe; break; }
        tile_expert[tt] = e;
    }
}

__global__ void scatter_slots(
    const int* __restrict__ tok_e, const float* __restrict__ tok_w,
    const int* __restrict__ base, int* __restrict__ cursor,
    int* __restrict__ slot_token, float* __restrict__ slot_w)
{
    int t = blockIdx.x*blockDim.x + threadIdx.x;
    if (t >= T_) return;
    #pragma unroll
    for (int j=0;j<2;j++) {
        int e = tok_e[t*2+j];
        int pos = atomicAdd(&cursor[e], 1);
        int s = base[e] + pos;
        slot_token[s] = t;
        slot_w[s] = tok_w[t*2+j];
    }
}

extern "C" void kernel_launch(void* const* d_in, const int* in_sizes, int n_in,
                              void* d_out, int out_size, void* d_ws, size_t ws_size,
                              hipStream_t stream)
{
    const float* x    = (const float*)d_in[0];
    const float* Wq   = (const float*)d_in[1];
    const float* Wk   = (const float*)d_in[2];
    const float* Wv   = (const float*)d_in[3];
    const float* Wd   = (const float*)d_in[4];
    const float* bd   = (const float*)d_in[5];
    const float* ln1g = (const float*)d_in[6];
    const float* ln1b = (const float*)d_in[7];
    const float* Wg   = (const float*)d_in[8];
    const float* W1   = (const float*)d_in[9];
    const float* W2   = (const float*)d_in[10];
    const float* ln2g = (const float*)d_in[11];
    const float* ln2b = (const float*)d_in[12];
    float* out = (float*)d_out;

    float* f0 = (float*)d_ws;
    const size_t M1 = 1u << 20;
    float* qb   = f0;            // q -> attn_out
    float* kb   = f0 + 4*M1;     // k -> hs
    float* vb   = f0 + 8*M1;     // v -> moe_out
    float* ctxb = f0 + 12*M1;
    __hip_bfloat16* hs_b = (__hip_bfloat16*)(f0 + 16*M1);

    float* misc = f0 + 18*M1;
    int*   misc_i = (int*)misc;
    int*   tok_e   = misc_i;
    float* tok_w   = misc + 8192;
    int*   slot_tok= misc_i + 16384;
    float* slot_w  = misc + 25600;
    int*   counts  = misc_i + 34816;
    float* P_sum   = misc + 34824;
    int*   cursor  = misc_i + 34832;
    int*   basep   = misc_i + 34840;
    int*   cnt_pad = misc_i + 34848;
    int*   ntiles  = misc_i + 34856;
    int*   tile_ex = misc_i + 34857;

    float* off_p = f0 + 18*M1 + 65536;
    __hip_bfloat16* xa_hi = (__hip_bfloat16*)(off_p);          // x split, reused for ctx split
    __hip_bfloat16* xa_lo = (__hip_bfloat16*)(off_p + 2*M1);
    const size_t HM = M1/2;                                     // 0.5M floats = 1M bf16
    __hip_bfloat16* wq_h = (__hip_bfloat16*)(off_p + 4*M1);
    __hip_bfloat16* wq_l = (__hip_bfloat16*)(off_p + 4*M1 + HM);
    __hip_bfloat16* wk_h = (__hip_bfloat16*)(off_p + 5*M1);
    __hip_bfloat16* wk_l = (__hip_bfloat16*)(off_p + 5*M1 + HM);
    __hip_bfloat16* wv_h = (__hip_bfloat16*)(off_p + 6*M1);
    __hip_bfloat16* wv_l = (__hip_bfloat16*)(off_p + 6*M1 + HM);
    __hip_bfloat16* wd_h = (__hip_bfloat16*)(off_p + 7*M1);
    __hip_bfloat16* wd_l = (__hip_bfloat16*)(off_p + 7*M1 + HM);

    // wreg ALIASES the weight-split region (dead by MoE time)
    float* wreg = off_p + 4*M1;
    const bool FULL = ws_size >= (size_t)300*1024*1024;

    dim3 blk(256);

    // split x; transpose+split projection weights
    split_bf16<<<(T_*H_/4)/256, blk, 0, stream>>>(x, xa_hi, xa_lo, T_*H_/4);
    transpose_split_bf16<<<dim3(16,16), blk, 0, stream>>>(Wq, wq_h, wq_l, H_, H_);
    transpose_split_bf16<<<dim3(16,16), blk, 0, stream>>>(Wk, wk_h, wk_l, H_, H_);
    transpose_split_bf16<<<dim3(16,16), blk, 0, stream>>>(Wv, wv_h, wv_l, H_, H_);
    transpose_split_bf16<<<dim3(16,16), blk, 0, stream>>>(Wd, wd_h, wd_l, H_, H_);

    // QKV projections (bf16x3 MFMA)
    gemm_bf16x3<false><<<dim3(H_/128, T_/128), blk, 0, stream>>>(xa_hi, xa_lo, wq_h, wq_l, qb, nullptr, H_, H_);
    gemm_bf16x3<false><<<dim3(H_/128, T_/128), blk, 0, stream>>>(xa_hi, xa_lo, wk_h, wk_l, kb, nullptr, H_, H_);
    gemm_bf16x3<false><<<dim3(H_/128, T_/128), blk, 0, stream>>>(xa_hi, xa_lo, wv_h, wv_l, vb, nullptr, H_, H_);

    rope_kernel<<<(T_*NH_*32)/256, blk, 0, stream>>>(qb, kb);

    attn_mfma<<<dim3(S_/64, NH_, B_), blk, 0, stream>>>(qb, kb, vb, ctxb);

    // attn_out = ctx@Wd + bd (bf16x3): split ctx (reusing xa buffers), then GEMM into qb
    split_bf16<<<(T_*H_/4)/256, blk, 0, stream>>>(ctxb, xa_hi, xa_lo, T_*H_/4);
    gemm_bf16x3<true><<<dim3(H_/128, T_/128), blk, 0, stream>>>(xa_hi, xa_lo, wd_h, wd_l, qb, bd, H_, H_);

    zero_kernel<<<(T_*H_)/256, blk, 0, stream>>>(vb, T_*H_);
    zero_kernel<<<1, blk, 0, stream>>>(misc + 34816, 16);

    ln_kernel<<<T_, blk, 0, stream>>>(qb, x, ln1g, ln1b, kb, hs_b);

    router_kernel<<<T_/64, blk, 0, stream>>>(kb, Wg, tok_e, tok_w, counts, P_sum);
    router_finalize<<<1, blk, 0, stream>>>(counts, P_sum, basep, cursor, cnt_pad, ntiles,
                                           slot_tok, tile_ex, out + (size_t)T_*H_);
    scatter_slots<<<T_/256, blk, 0, stream>>>(tok_e, tok_w, basep, cursor, slot_tok, slot_w);

    if (FULL) {
        __hip_bfloat16* W1t = (__hip_bfloat16*)wreg;
        __hip_bfloat16* W2t = (__hip_bfloat16*)(wreg + 16*M1);
        __hip_bfloat16* y1  = (__hip_bfloat16*)(wreg + 32*M1);
        transpose_bf16<<<dim3(I_/64, H_/64, E_), blk, 0, stream>>>(W1, W1t, H_, I_);
        transpose_bf16<<<dim3(H_/64, I_/64, E_), blk, 0, stream>>>(W2, W2t, I_, H_);
        moe_mfma<2,false><<<dim3(I_/128, MAXTILES), blk, 0, stream>>>(
            hs_b, W1t, y1, nullptr, slot_tok, slot_w, tile_ex, ntiles, nullptr, I_, H_);
        moe_mfma<3,false><<<dim3(H_/128, MAXTILES), blk, 0, stream>>>(
            y1, W2t, nullptr, vb, slot_tok, slot_w, tile_ex, ntiles, nullptr, H_, I_);
    } else {
        __hip_bfloat16* w1t = (__hip_bfloat16*)wreg;
        __hip_bfloat16* w2t = (__hip_bfloat16*)(wreg + 2*M1);
        __hip_bfloat16* y1  = (__hip_bfloat16*)(wreg + 4*M1);
        for (int e=0; e<E_; ++e) {
            transpose_bf16<<<dim3(I_/64, H_/64, 1), blk, 0, stream>>>(W1 + (size_t)e*H_*I_, w1t, H_, I_);
            moe_mfma<2,true><<<dim3(I_/128, 32), blk, 0, stream>>>(
                hs_b, w1t, y1, nullptr, slot_tok, slot_w, nullptr, cnt_pad+e, basep+e, I_, H_);
            transpose_bf16<<<dim3(H_/64, I_/64, 1), blk, 0, stream>>>(W2 + (size_t)e*I_*H_, w2t, I_, H_);
            moe_mfma<3,true><<<dim3(H_/128, 32), blk, 0, stream>>>(
                y1, w2t, nullptr, vb, slot_tok, slot_w, nullptr, cnt_pad+e, basep+e, H_, I_);
        }
    }

    ln_kernel<<<T_, blk, 0, stream>>>(vb, kb, ln2g, ln2b, out, nullptr);
}

// Round 6
// 884.342 us; speedup vs baseline: 6.8380x; 1.0634x over previous
//
#include <hip/hip_runtime.h>
#include <hip/hip_bf16.h>
#include <math.h>

#define H_ 1024
#define NH_ 16
#define HD_ 64
#define I_ 4096
#define E_ 8
#define B_ 2
#define S_ 2048
#define T_ 4096

#define MAXSLOTS 9216   // 2*T + 8*128 pad
#define MAXTILES 72     // MAXSLOTS/128

typedef __attribute__((ext_vector_type(8))) short short8v;
typedef __attribute__((ext_vector_type(4))) float f32x4;

#define GLOAD16(g, l) __builtin_amdgcn_global_load_lds((const __attribute__((address_space(1))) void*)(g), (__attribute__((address_space(3))) void*)(l), 16, 0, 0)

static __device__ inline unsigned short f2bf(float x) {
    __hip_bfloat16 h = __float2bfloat16(x);
    unsigned short u;
    __builtin_memcpy(&u, &h, 2);
    return u;
}
static __device__ inline float bf2f(unsigned short u) {
    __hip_bfloat16 h;
    __builtin_memcpy(&h, &u, 2);
    return __bfloat162float(h);
}

// ---------------- zero ----------------
__global__ void zero_kernel(float* __restrict__ p, int n) {
    int i = blockIdx.x * blockDim.x + threadIdx.x;
    if (i < n) p[i] = 0.f;
}

// ---------------- fp32 -> bf16 hi/lo split (elementwise) ----------------
__global__ __launch_bounds__(256) void split_bf16(
    const float* __restrict__ in, __hip_bfloat16* __restrict__ hi,
    __hip_bfloat16* __restrict__ lo, int n4)
{
    int i = blockIdx.x * blockDim.x + threadIdx.x;
    if (i >= n4) return;
    float4 v = ((const float4*)in)[i];
    unsigned short h0 = f2bf(v.x), h1 = f2bf(v.y), h2 = f2bf(v.z), h3 = f2bf(v.w);
    unsigned short l0 = f2bf(v.x - bf2f(h0)), l1 = f2bf(v.y - bf2f(h1));
    unsigned short l2 = f2bf(v.z - bf2f(h2)), l3 = f2bf(v.w - bf2f(h3));
    uint2 ph = make_uint2((unsigned)h0 | ((unsigned)h1 << 16), (unsigned)h2 | ((unsigned)h3 << 16));
    uint2 pl = make_uint2((unsigned)l0 | ((unsigned)l1 << 16), (unsigned)l2 | ((unsigned)l3 << 16));
    *(uint2*)((char*)hi + (size_t)i*8) = ph;
    *(uint2*)((char*)lo + (size_t)i*8) = pl;
}

// ---------------- transpose + split: in [K][N] f32 -> hi,lo [N][K] bf16 ----------------
__global__ __launch_bounds__(256) void transpose_split_bf16(
    const float* __restrict__ in, __hip_bfloat16* __restrict__ oh,
    __hip_bfloat16* __restrict__ ol, int K, int N)
{
    __shared__ float t[64][65];
    int k0 = blockIdx.y*64, n0 = blockIdx.x*64;
    int tid = threadIdx.x;
    #pragma unroll
    for (int it=0; it<16; ++it) {
        int lin = it*256 + tid;
        int r = lin >> 6, c = lin & 63;
        t[r][c] = in[(size_t)(k0+r)*N + n0 + c];
    }
    __syncthreads();
    #pragma unroll
    for (int it=0; it<16; ++it) {
        int lin = it*256 + tid;
        int r = lin >> 6, c = lin & 63;   // r = n-local, c = k-local
        float v = t[c][r];
        unsigned short hh = f2bf(v);
        unsigned short ll = f2bf(v - bf2f(hh));
        size_t o = (size_t)(n0+r)*K + k0 + c;
        oh[o] = *(__hip_bfloat16*)&hh;
        ol[o] = *(__hip_bfloat16*)&ll;
    }
}

// ---------------- transpose + f32->bf16: in [K][N] -> out [N][K] (MoE weights) ----------------
__global__ __launch_bounds__(256) void transpose_bf16(
    const float* __restrict__ in, __hip_bfloat16* __restrict__ outp, int K, int N)
{
    __shared__ float t[64][65];
    size_t eoff = (size_t)blockIdx.z * (size_t)K * (size_t)N;
    int k0 = blockIdx.y*64, n0 = blockIdx.x*64;
    int tid = threadIdx.x;
    #pragma unroll
    for (int it=0; it<16; ++it) {
        int lin = it*256 + tid;
        int r = lin >> 6, c = lin & 63;
        t[r][c] = in[eoff + (size_t)(k0+r)*N + n0 + c];
    }
    __syncthreads();
    #pragma unroll
    for (int it=0; it<16; ++it) {
        int lin = it*256 + tid;
        int r = lin >> 6, c = lin & 63;
        outp[eoff + (size_t)(n0+r)*K + k0 + c] = __float2bfloat16(t[c][r]);
    }
}

// ---------------- bf16x3 GEMM: C = A@B (+bias), fp32-accurate ----------------
template<bool BIAS>
__global__ __launch_bounds__(256, 2) void gemm_bf16x3(
    const __hip_bfloat16* __restrict__ Ah, const __hip_bfloat16* __restrict__ Al,
    const __hip_bfloat16* __restrict__ Bh, const __hip_bfloat16* __restrict__ Bl,
    float* __restrict__ C, const float* __restrict__ bias, int N, int K)
{
    const int tid = threadIdx.x;
    const int w = tid >> 6, lane = tid & 63;
    const int bx = blockIdx.x, by = blockIdx.y;

    __shared__ __align__(16) char smem[65536];
    const int AH = 0, AL = 16384, BH = 32768, BL = 49152;

    const int laneg = lane >> 3;
    const int k2sw = ((lane & 7) ^ laneg) << 4;
    const int l15 = lane & 15, l4 = lane >> 4;
    const int wr = w >> 1, wc = w & 1;

    f32x4 acc[4][4];
    #pragma unroll
    for (int m=0;m<4;m++)
        #pragma unroll
        for (int n=0;n<4;n++) acc[m][n] = (f32x4){0.f,0.f,0.f,0.f};

    for (int k0 = 0; k0 < K; k0 += 64) {
        __syncthreads();
        #pragma unroll
        for (int qq=0;qq<4;qq++) {
            int arow = by*128 + (w*4+qq)*8 + laneg;
            int brow = bx*128 + (w*4+qq)*8 + laneg;
            size_t aoff = ((size_t)arow*K + k0)*2 + k2sw;
            size_t boff = ((size_t)brow*K + k0)*2 + k2sw;
            GLOAD16((const char*)Ah + aoff, smem + AH + (w*4+qq)*1024);
            GLOAD16((const char*)Al + aoff, smem + AL + (w*4+qq)*1024);
            GLOAD16((const char*)Bh + boff, smem + BH + (w*4+qq)*1024);
            GLOAD16((const char*)Bl + boff, smem + BL + (w*4+qq)*1024);
        }
        __syncthreads();

        short8v ahf[4][2], alf[4][2], bhf[4][2], blf[4][2];
        #pragma unroll
        for (int m=0;m<4;m++) {
            int row = wr*64 + m*16 + l15;
            int rb = row << 7, rsw = (row & 7) << 4;
            #pragma unroll
            for (int s=0;s<2;s++) {
                int off = rb + ((s*64 + (l4<<4)) ^ rsw);
                ahf[m][s] = *(const short8v*)(smem + AH + off);
                alf[m][s] = *(const short8v*)(smem + AL + off);
            }
        }
        #pragma unroll
        for (int n=0;n<4;n++) {
            int row = wc*64 + n*16 + l15;
            int rb = row << 7, rsw = (row & 7) << 4;
            #pragma unroll
            for (int s=0;s<2;s++) {
                int off = rb + ((s*64 + (l4<<4)) ^ rsw);
                bhf[n][s] = *(const short8v*)(smem + BH + off);
                blf[n][s] = *(const short8v*)(smem + BL + off);
            }
        }
        #pragma unroll
        for (int m=0;m<4;m++)
            #pragma unroll
            for (int n=0;n<4;n++)
                #pragma unroll
                for (int s=0;s<2;s++) {
                    acc[m][n] = __builtin_amdgcn_mfma_f32_16x16x32_bf16(ahf[m][s], bhf[n][s], acc[m][n], 0, 0, 0);
                    acc[m][n] = __builtin_amdgcn_mfma_f32_16x16x32_bf16(ahf[m][s], blf[n][s], acc[m][n], 0, 0, 0);
                    acc[m][n] = __builtin_amdgcn_mfma_f32_16x16x32_bf16(alf[m][s], bhf[n][s], acc[m][n], 0, 0, 0);
                }
    }

    #pragma unroll
    for (int m=0;m<4;m++)
        #pragma unroll
        for (int j=0;j<4;j++) {
            int orow = by*128 + wr*64 + m*16 + l4*4 + j;
            #pragma unroll
            for (int n=0;n<4;n++) {
                int ocol = bx*128 + wc*64 + n*16 + l15;
                float v = acc[m][n][j];
                if (BIAS) v += bias[ocol];
                C[(size_t)orow*N + ocol] = v;
            }
        }
}

// ---------------- MFMA MoE GEMM (unchanged, verified) ----------------
template<int MODE, bool PE>
__global__ __launch_bounds__(256) void moe_mfma(
    const __hip_bfloat16* __restrict__ A,
    const __hip_bfloat16* __restrict__ Bt,
    __hip_bfloat16* __restrict__ y1,
    float* __restrict__ moe_out,
    const int* __restrict__ slot_token,
    const float* __restrict__ slot_w,
    const int* __restrict__ tile_expert,
    const int* __restrict__ cnt_ptr,
    const int* __restrict__ base_ptr,
    int N, int K)
{
    const int tid = threadIdx.x;
    const int w = tid >> 6, lane = tid & 63;
    const int bx = blockIdx.x;

    int slot0, y1row0;
    const __hip_bfloat16* Bp;
    if (PE) {
        int tloc = blockIdx.y;
        if ((tloc << 7) >= *cnt_ptr) return;
        slot0 = *base_ptr + (tloc << 7);
        y1row0 = tloc << 7;
        Bp = Bt;
    } else {
        int gt = blockIdx.y;
        if (gt >= *cnt_ptr) return;
        int e = tile_expert[gt];
        Bp = Bt + (size_t)e * (size_t)K * (size_t)N;
        slot0 = gt << 7;
        y1row0 = gt << 7;
    }

    __shared__ __align__(16) char smem[32768];

    const int laneg = lane >> 3;
    const int k2sw = ((lane & 7) ^ laneg) << 4;

    int tokq[4];
    if (MODE == 2) {
        #pragma unroll
        for (int qq=0;qq<4;qq++) {
            int t0 = slot_token[slot0 + (w*4+qq)*8 + laneg];
            tokq[qq] = t0 < 0 ? 0 : t0;
        }
    }

    f32x4 acc[4][4];
    #pragma unroll
    for (int m=0;m<4;m++)
        #pragma unroll
        for (int n=0;n<4;n++) acc[m][n] = (f32x4){0.f,0.f,0.f,0.f};

    const int l15 = lane & 15;
    const int l4  = lane >> 4;
    const int wr = w >> 1, wc = w & 1;

    for (int k0 = 0; k0 < K; k0 += 64) {
        __syncthreads();
        #pragma unroll
        for (int qq=0;qq<4;qq++) {
            const char* ga;
            if (MODE == 2) {
                ga = (const char*)A + (((size_t)tokq[qq])*K + k0)*2 + k2sw;
            } else {
                int row = y1row0 + (w*4+qq)*8 + laneg;
                ga = (const char*)A + ((size_t)row*K + k0)*2 + k2sw;
            }
            GLOAD16(ga, smem + (w*4+qq)*1024);
        }
        #pragma unroll
        for (int qq=0;qq<4;qq++) {
            int row = bx*128 + (w*4+qq)*8 + laneg;
            const char* gb = (const char*)Bp + ((size_t)row*K + k0)*2 + k2sw;
            GLOAD16(gb, smem + 16384 + (w*4+qq)*1024);
        }
        __syncthreads();

        short8v a_frag[4][2], b_frag[4][2];
        #pragma unroll
        for (int m=0;m<4;m++) {
            int row = wr*64 + m*16 + l15;
            int rb = row << 7;
            #pragma unroll
            for (int s=0;s<2;s++) {
                int off = rb + ((s*64 + (l4<<4)) ^ ((row&7)<<4));
                a_frag[m][s] = *(const short8v*)(smem + off);
            }
        }
        #pragma unroll
        for (int n=0;n<4;n++) {
            int row = wc*64 + n*16 + l15;
            int rb = row << 7;
            #pragma unroll
            for (int s=0;s<2;s++) {
                int off = rb + ((s*64 + (l4<<4)) ^ ((row&7)<<4));
                b_frag[n][s] = *(const short8v*)(smem + 16384 + off);
            }
        }
        #pragma unroll
        for (int m=0;m<4;m++)
            #pragma unroll
            for (int n=0;n<4;n++) {
                acc[m][n] = __builtin_amdgcn_mfma_f32_16x16x32_bf16(a_frag[m][0], b_frag[n][0], acc[m][n], 0, 0, 0);
                acc[m][n] = __builtin_amdgcn_mfma_f32_16x16x32_bf16(a_frag[m][1], b_frag[n][1], acc[m][n], 0, 0, 0);
            }
    }

    #pragma unroll
    for (int m=0;m<4;m++) {
        #pragma unroll
        for (int j=0;j<4;j++) {
            int orow = wr*64 + m*16 + l4*4 + j;
            if (MODE == 3) {
                int slot = slot0 + orow;
                int tok = slot_token[slot];
                if (tok < 0) continue;
                float sw = slot_w[slot];
                #pragma unroll
                for (int n=0;n<4;n++) {
                    int ocol = bx*128 + wc*64 + n*16 + l15;
                    atomicAdd(&moe_out[(size_t)tok*H_ + ocol], sw * acc[m][n][j]);
                }
            } else {
                #pragma unroll
                for (int n=0;n<4;n++) {
                    int ocol = bx*128 + wc*64 + n*16 + l15;
                    float val = acc[m][n][j];
                    float g = 0.5f*val*(1.f + erff(val*0.70710678118654752f));
                    y1[(size_t)(y1row0 + orow)*N + ocol] = __float2bfloat16(g);
                }
            }
        }
    }
}

// ---------------- RoPE + split: fp32 q,k -> rotated bf16 hi/lo, head-major ----------------
// q scaled by 0.125 (softmax scale folded in). Layout: [(b*NH+n)*S + pos][64].
__global__ void rope_split_kernel(
    const float* __restrict__ q, const float* __restrict__ k,
    __hip_bfloat16* __restrict__ qh, __hip_bfloat16* __restrict__ ql,
    __hip_bfloat16* __restrict__ kh, __hip_bfloat16* __restrict__ kl)
{
    int idx = blockIdx.x * blockDim.x + threadIdx.x;  // T*NH*32
    int i = idx & 31;
    int n = (idx >> 5) & (NH_-1);
    int t = idx >> 9;
    int b = t >> 11;
    int pos = t & (S_ - 1);
    float inv = exp2f((float)i * (-13.287712379549449f / 32.f));
    float ang = (float)pos * inv;
    float c = cosf(ang), s = sinf(ang);
    size_t base = (size_t)t*H_ + (size_t)n*64;
    size_t obase = ((size_t)(b*NH_ + n)*S_ + pos)*64;

    float q1 = q[base+i], q2 = q[base+i+32];
    float qo1 = (q1*c - q2*s)*0.125f;
    float qo2 = (q2*c + q1*s)*0.125f;
    unsigned short h1 = f2bf(qo1), h2 = f2bf(qo2);
    qh[obase+i]    = *(__hip_bfloat16*)&h1;
    qh[obase+i+32] = *(__hip_bfloat16*)&h2;
    unsigned short lo1 = f2bf(qo1 - bf2f(h1)), lo2 = f2bf(qo2 - bf2f(h2));
    ql[obase+i]    = *(__hip_bfloat16*)&lo1;
    ql[obase+i+32] = *(__hip_bfloat16*)&lo2;

    float k1 = k[base+i], k2 = k[base+i+32];
    float ko1 = k1*c - k2*s;
    float ko2 = k2*c + k1*s;
    unsigned short kh1 = f2bf(ko1), kh2 = f2bf(ko2);
    kh[obase+i]    = *(__hip_bfloat16*)&kh1;
    kh[obase+i+32] = *(__hip_bfloat16*)&kh2;
    unsigned short kl1 = f2bf(ko1 - bf2f(kh1)), kl2 = f2bf(ko2 - bf2f(kh2));
    kl[obase+i]    = *(__hip_bfloat16*)&kl1;
    kl[obase+i+32] = *(__hip_bfloat16*)&kl2;
}

// ---------------- V transpose + split: fp32 [t][h] -> bf16 hi/lo [(b*NH+n)*64 + d][S] ----------------
__global__ __launch_bounds__(256) void vsplit_t_kernel(
    const float* __restrict__ v,
    __hip_bfloat16* __restrict__ vth, __hip_bfloat16* __restrict__ vtl)
{
    __shared__ float t[64][65];
    const int s0 = blockIdx.x*64;
    const int hn = blockIdx.y;
    const int b  = blockIdx.z;
    const int tid = threadIdx.x;
    #pragma unroll
    for (int it=0; it<16; ++it) {
        int lin = it*256 + tid;
        int r = lin >> 6, c = lin & 63;
        t[r][c] = v[(size_t)(b*S_ + s0 + r)*H_ + hn*64 + c];
    }
    __syncthreads();
    size_t obase = (size_t)(b*NH_ + hn)*64*S_;
    #pragma unroll
    for (int it=0; it<16; ++it) {
        int lin = it*256 + tid;
        int d = lin >> 6, c = lin & 63;   // d = dim, c = seq-local
        float x = t[c][d];
        unsigned short hh = f2bf(x);
        unsigned short ll = f2bf(x - bf2f(hh));
        size_t o = obase + (size_t)d*S_ + s0 + c;
        vth[o] = *(__hip_bfloat16*)&hh;
        vtl[o] = *(__hip_bfloat16*)&ll;
    }
}

// ---------------- MFMA attention: bf16x3, pre-split inputs, gload_lds staging ----------------
__global__ __launch_bounds__(256, 3) void attn_mfma(
    const __hip_bfloat16* __restrict__ qh, const __hip_bfloat16* __restrict__ ql,
    const __hip_bfloat16* __restrict__ kh, const __hip_bfloat16* __restrict__ kl,
    const __hip_bfloat16* __restrict__ vth, const __hip_bfloat16* __restrict__ vtl,
    float* __restrict__ ctx)
{
    const int qt = blockIdx.x;
    const int hn = blockIdx.y;
    const int b  = blockIdx.z;
    const int tid = threadIdx.x;
    const int w = tid >> 6, lane = tid & 63;
    const int l15 = lane & 15, l4 = lane >> 4;
    const int laneg = lane >> 3;
    const int k2sw = ((lane & 7) ^ laneg) << 4;

    __shared__ __align__(16) char smem[49152];
    const int KHo = 0, KLo = 8192, VHo = 16384, VLo = 24576, PHo = 32768, PLo = 40960;

    const int head = b*NH_ + hn;
    const size_t kbase = (size_t)head*S_*64;   // qh/ql/kh/kl element base
    const size_t vbase = (size_t)head*64*S_;   // vth/vtl element base

    // ---- prologue: stage Q tile (rows qt*64..+63) into P region, read frags ----
    #pragma unroll
    for (int qq=0;qq<2;qq++) {
        int c = w*2 + qq;
        int row = qt*64 + c*8 + laneg;
        size_t off = (kbase + (size_t)row*64)*2 + k2sw;
        GLOAD16((const char*)qh + off, smem + PHo + c*1024);
        GLOAD16((const char*)ql + off, smem + PLo + c*1024);
    }
    __syncthreads();
    short8v qhf[2], qlf[2];
    {
        int row = w*16 + l15;
        int rsw = (row & 7) << 4;
        #pragma unroll
        for (int s=0;s<2;s++) {
            int off = row*128 + ((s*64 + l4*16) ^ rsw);
            qhf[s] = *(const short8v*)(smem + PHo + off);
            qlf[s] = *(const short8v*)(smem + PLo + off);
        }
    }

    f32x4 acc[4];
    #pragma unroll
    for (int db=0;db<4;db++) acc[db] = (f32x4){0.f,0.f,0.f,0.f};
    float mrun[4], lrun[4];
    #pragma unroll
    for (int j=0;j<4;j++) { mrun[j] = -1e30f; lrun[j] = 0.f; }

    for (int kt=0; kt<S_/64; ++kt) {
        __syncthreads();   // prior tile's LDS reads done (also drains Q-frag reads on kt=0)
        // ---- stage K rows + V^T rows via global_load_lds ----
        #pragma unroll
        for (int qq=0;qq<2;qq++) {
            int c = w*2 + qq;
            int r8 = c*8 + laneg;
            size_t koff = (kbase + (size_t)(kt*64 + r8)*64)*2 + k2sw;
            GLOAD16((const char*)kh + koff, smem + KHo + c*1024);
            GLOAD16((const char*)kl + koff, smem + KLo + c*1024);
            size_t voff = (vbase + (size_t)r8*S_ + kt*64)*2 + k2sw;
            GLOAD16((const char*)vth + voff, smem + VHo + c*1024);
            GLOAD16((const char*)vtl + voff, smem + VLo + c*1024);
        }
        __syncthreads();   // staged tile visible

        // ---- QK^T (3-term split) ----
        f32x4 s_acc[4];
        #pragma unroll
        for (int cb=0;cb<4;cb++) {
            s_acc[cb] = (f32x4){0.f,0.f,0.f,0.f};
            int row = cb*16 + l15;
            int rsw = (row & 7) << 4;
            #pragma unroll
            for (int s=0;s<2;s++) {
                int off = row*128 + ((s*64 + l4*16) ^ rsw);
                short8v khf = *(const short8v*)(smem + KHo + off);
                short8v klf = *(const short8v*)(smem + KLo + off);
                s_acc[cb] = __builtin_amdgcn_mfma_f32_16x16x32_bf16(qhf[s], khf, s_acc[cb], 0, 0, 0);
                s_acc[cb] = __builtin_amdgcn_mfma_f32_16x16x32_bf16(qhf[s], klf, s_acc[cb], 0, 0, 0);
                s_acc[cb] = __builtin_amdgcn_mfma_f32_16x16x32_bf16(qlf[s], khf, s_acc[cb], 0, 0, 0);
            }
        }

        // ---- online softmax ----
        float mnew[4], alpha[4];
        #pragma unroll
        for (int j=0;j<4;j++) {
            float mt = fmaxf(fmaxf(s_acc[0][j], s_acc[1][j]), fmaxf(s_acc[2][j], s_acc[3][j]));
            #pragma unroll
            for (int m=8;m;m>>=1) mt = fmaxf(mt, __shfl_xor(mt, m));
            float mn = fmaxf(mrun[j], mt);
            mnew[j] = mn;
            alpha[j] = __expf(mrun[j] - mn);
            mrun[j] = mn;
        }
        float pv[4][4];
        float ps[4] = {0.f,0.f,0.f,0.f};
        #pragma unroll
        for (int cb=0;cb<4;cb++)
            #pragma unroll
            for (int j=0;j<4;j++) {
                float p = __expf(s_acc[cb][j] - mnew[j]);
                pv[cb][j] = p;
                ps[j] += p;
            }
        #pragma unroll
        for (int j=0;j<4;j++) {
            float s = ps[j];
            #pragma unroll
            for (int m=8;m;m>>=1) s += __shfl_xor(s, m);
            lrun[j] = lrun[j]*alpha[j] + s;
        }

        // ---- split P -> wave-private LDS rows ----
        #pragma unroll
        for (int cb=0;cb<4;cb++)
            #pragma unroll
            for (int j=0;j<4;j++) {
                int prow = w*16 + l4*4 + j;
                unsigned short hh = f2bf(pv[cb][j]);
                unsigned short ll = f2bf(pv[cb][j] - bf2f(hh));
                int off = prow*128 + (((cb*16 + l15)*2) ^ ((prow&7)<<4));
                *(unsigned short*)(smem + PHo + off) = hh;
                *(unsigned short*)(smem + PLo + off) = ll;
            }
        asm volatile("s_waitcnt lgkmcnt(0)" ::: "memory");
        __builtin_amdgcn_sched_barrier(0);

        // ---- rescale ctx acc ----
        #pragma unroll
        for (int db=0;db<4;db++)
            #pragma unroll
            for (int j=0;j<4;j++) acc[db][j] *= alpha[j];

        // ---- PV (3-term split) ----
        short8v pah[2], pal[2];
        {
            int row = w*16 + l15;
            int rsw = (row & 7) << 4;
            #pragma unroll
            for (int s=0;s<2;s++) {
                int off = row*128 + ((s*64 + l4*16) ^ rsw);
                pah[s] = *(const short8v*)(smem + PHo + off);
                pal[s] = *(const short8v*)(smem + PLo + off);
            }
        }
        #pragma unroll
        for (int db=0;db<4;db++) {
            int row = db*16 + l15;
            int rsw = (row & 7) << 4;
            #pragma unroll
            for (int s=0;s<2;s++) {
                int off = row*128 + ((s*64 + l4*16) ^ rsw);
                short8v vhf = *(const short8v*)(smem + VHo + off);
                short8v vlf = *(const short8v*)(smem + VLo + off);
                acc[db] = __builtin_amdgcn_mfma_f32_16x16x32_bf16(pah[s], vhf, acc[db], 0, 0, 0);
                acc[db] = __builtin_amdgcn_mfma_f32_16x16x32_bf16(pah[s], vlf, acc[db], 0, 0, 0);
                acc[db] = __builtin_amdgcn_mfma_f32_16x16x32_bf16(pal[s], vhf, acc[db], 0, 0, 0);
            }
        }
    }

    // ---- epilogue ----
    const size_t headoff = (size_t)b*S_*H_ + (size_t)hn*64;
    #pragma unroll
    for (int db=0;db<4;db++)
        #pragma unroll
        for (int j=0;j<4;j++) {
            int qrow = qt*64 + w*16 + l4*4 + j;
            ctx[headoff + (size_t)qrow*H_ + db*16 + l15] = acc[db][j] / lrun[j];
        }
}

// ---------------- layernorm (residual fused, optional bf16 out) ----------------
__global__ __launch_bounds__(256) void ln_kernel(
    const float* __restrict__ a, const float* __restrict__ res,
    const float* __restrict__ g, const float* __restrict__ beta,
    float* __restrict__ out, __hip_bfloat16* __restrict__ outb)
{
    int row = blockIdx.x, tid = threadIdx.x;
    const float4 va = ((const float4*)(a + (size_t)row*H_))[tid];
    const float4 vr = ((const float4*)(res + (size_t)row*H_))[tid];
    float x0=va.x+vr.x, x1=va.y+vr.y, x2=va.z+vr.z, x3=va.w+vr.w;
    float s  = x0+x1+x2+x3;
    float ss = x0*x0 + x1*x1 + x2*x2 + x3*x3;
    #pragma unroll
    for (int off=32; off; off>>=1) { s += __shfl_xor(s, off); ss += __shfl_xor(ss, off); }
    __shared__ float red[8];
    if ((tid&63)==0) { red[tid>>6]=s; red[4+(tid>>6)]=ss; }
    __syncthreads();
    if (tid==0) { red[0]=red[0]+red[1]+red[2]+red[3]; red[4]=red[4]+red[5]+red[6]+red[7]; }
    __syncthreads();
    float mu  = red[0] * (1.f/H_);
    float var = red[4] * (1.f/H_) - mu*mu;
    float rs = rsqrtf(fmaxf(var, 0.f) + 1e-12f);
    const float4 vg = ((const float4*)g)[tid];
    const float4 vb = ((const float4*)beta)[tid];
    float4 vo;
    vo.x = (x0-mu)*rs*vg.x + vb.x;
    vo.y = (x1-mu)*rs*vg.y + vb.y;
    vo.z = (x2-mu)*rs*vg.z + vb.z;
    vo.w = (x3-mu)*rs*vg.w + vb.w;
    ((float4*)(out + (size_t)row*H_))[tid] = vo;
    if (outb) {
        unsigned int p0 = (unsigned)f2bf(vo.x) | ((unsigned)f2bf(vo.y) << 16);
        unsigned int p1 = (unsigned)f2bf(vo.z) | ((unsigned)f2bf(vo.w) << 16);
        ((uint2*)(outb + (size_t)row*H_))[tid] = make_uint2(p0, p1);
    }
}

// ---------------- router: 64 blocks x 64 tokens, register-accumulated stats ----------------
__global__ __launch_bounds__(256) void router_kernel(
    const float* __restrict__ hs, const float* __restrict__ Wg,
    int* __restrict__ tok_e, float* __restrict__ tok_w,
    int* __restrict__ counts, float* __restrict__ P_sum)
{
    const int w = threadIdx.x >> 6, lane = threadIdx.x & 63;
    float psum[E_];
    int cnt[E_];
    #pragma unroll
    for (int e=0;e<E_;e++){ psum[e]=0.f; cnt[e]=0; }

    for (int it=0; it<16; ++it) {
        int t = blockIdx.x*64 + it*4 + w;
        const float* row = hs + (size_t)t * H_;
        float acc[E_];
        #pragma unroll
        for (int e=0;e<E_;e++) acc[e]=0.f;
        for (int i16=0; i16<16; ++i16) {
            int i = i16*64 + lane;
            float xv = row[i];
            const float* wg = Wg + (size_t)i*E_;
            #pragma unroll
            for (int e=0;e<E_;e++) acc[e] = fmaf(xv, wg[e], acc[e]);
        }
        #pragma unroll
        for (int e=0;e<E_;e++) {
            float vv = acc[e];
            #pragma unroll
            for (int off=32; off; off>>=1) vv += __shfl_xor(vv, off);
            acc[e] = vv;
        }
        float mx = acc[0];
        #pragma unroll
        for (int e=1;e<E_;e++) mx = fmaxf(mx, acc[e]);
        float p[E_], se=0.f;
        #pragma unroll
        for (int e=0;e<E_;e++){ p[e] = __expf(acc[e]-mx); se += p[e]; }
        float isv = 1.f/se;
        #pragma unroll
        for (int e=0;e<E_;e++){ p[e]*=isv; psum[e] += p[e]; }
        int e1=0;
        #pragma unroll
        for (int e=1;e<E_;e++) if (p[e] > p[e1]) e1=e;
        int e2 = (e1==0)?1:0;
        #pragma unroll
        for (int e=0;e<E_;e++) if (e!=e1 && p[e] > p[e2]) e2=e;
        #pragma unroll
        for (int e=0;e<E_;e++) cnt[e] += (e==e1?1:0) + (e==e2?1:0);
        if (lane==0) {
            float w1=p[e1], w2=p[e2], si=1.f/(w1+w2);
            tok_e[t*2]=e1; tok_e[t*2+1]=e2;
            tok_w[t*2]=w1*si; tok_w[t*2+1]=w2*si;
        }
    }
    if (lane==0) {
        #pragma unroll
        for (int e=0;e<E_;e++) {
            atomicAdd(&P_sum[e], psum[e]);
            atomicAdd(&counts[e], cnt[e]);
        }
    }
}

__global__ void router_finalize(
    const int* __restrict__ counts, const float* __restrict__ P_sum,
    int* __restrict__ base, int* __restrict__ cursor,
    int* __restrict__ cnt_pad, int* __restrict__ ntiles,
    int* __restrict__ slot_token, int* __restrict__ tile_expert,
    float* __restrict__ aux_out)
{
    __shared__ int sbase[E_+1];
    if (threadIdx.x == 0) {
        int bacc = 0;
        float aux = 0.f;
        for (int e=0;e<E_;e++) {
            sbase[e] = bacc; base[e] = bacc;
            int cp = (counts[e] + 127) & ~127;
            cnt_pad[e] = cp;
            bacc += cp;
            cursor[e] = 0;
            aux += ((float)counts[e]/(float)T_) * (P_sum[e]/(float)T_);
        }
        sbase[E_] = bacc;
        *ntiles = bacc >> 7;
        *aux_out = (float)E_ * aux;
    }
    __syncthreads();
    for (int sIdx = (int)threadIdx.x; sIdx < MAXSLOTS; sIdx += (int)blockDim.x)
        slot_token[sIdx] = -1;
    for (int tt = (int)threadIdx.x; tt < MAXTILES; tt += (int)blockDim.x) {
        int s = tt*128;
        int e = E_-1;
        for (int qe=0; qe<E_; ++qe) if (s < sbase[qe+1]) { e = qe; break; }
        tile_expert[tt] = e;
    }
}

__global__ void scatter_slots(
    const int* __restrict__ tok_e, const float* __restrict__ tok_w,
    const int* __restrict__ base, int* __restrict__ cursor,
    int* __restrict__ slot_token, float* __restrict__ slot_w)
{
    int t = blockIdx.x*blockDim.x + threadIdx.x;
    if (t >= T_) return;
    #pragma unroll
    for (int j=0;j<2;j++) {
        int e = tok_e[t*2+j];
        int pos = atomicAdd(&cursor[e], 1);
        int s = base[e] + pos;
        slot_token[s] = t;
        slot_w[s] = tok_w[t*2+j];
    }
}

extern "C" void kernel_launch(void* const* d_in, const int* in_sizes, int n_in,
                              void* d_out, int out_size, void* d_ws, size_t ws_size,
                              hipStream_t stream)
{
    const float* x    = (const float*)d_in[0];
    const float* Wq   = (const float*)d_in[1];
    const float* Wk   = (const float*)d_in[2];
    const float* Wv   = (const float*)d_in[3];
    const float* Wd   = (const float*)d_in[4];
    const float* bd   = (const float*)d_in[5];
    const float* ln1g = (const float*)d_in[6];
    const float* ln1b = (const float*)d_in[7];
    const float* Wg   = (const float*)d_in[8];
    const float* W1   = (const float*)d_in[9];
    const float* W2   = (const float*)d_in[10];
    const float* ln2g = (const float*)d_in[11];
    const float* ln2b = (const float*)d_in[12];
    float* out = (float*)d_out;

    float* f0 = (float*)d_ws;
    const size_t M1 = 1u << 20;
    float* qb   = f0;            // q -> attn_out
    float* kb   = f0 + 4*M1;     // k -> hs
    float* vb   = f0 + 8*M1;     // v -> moe_out
    float* ctxb = f0 + 12*M1;
    __hip_bfloat16* hs_b = (__hip_bfloat16*)(f0 + 16*M1);

    float* misc = f0 + 18*M1;
    int*   misc_i = (int*)misc;
    int*   tok_e   = misc_i;
    float* tok_w   = misc + 8192;
    int*   slot_tok= misc_i + 16384;
    float* slot_w  = misc + 25600;
    int*   counts  = misc_i + 34816;
    float* P_sum   = misc + 34824;
    int*   cursor  = misc_i + 34832;
    int*   basep   = misc_i + 34840;
    int*   cnt_pad = misc_i + 34848;
    int*   ntiles  = misc_i + 34856;
    int*   tile_ex = misc_i + 34857;

    float* off_p = f0 + 18*M1 + 65536;
    __hip_bfloat16* xa_hi = (__hip_bfloat16*)(off_p);          // x split, reused for ctx split
    __hip_bfloat16* xa_lo = (__hip_bfloat16*)(off_p + 2*M1);
    const size_t HM = M1/2;
    // attn split buffers (2M1 floats each) — alias the MoE-weight region (temporally disjoint)
    __hip_bfloat16* at_qh = (__hip_bfloat16*)(off_p + 4*M1);
    __hip_bfloat16* at_ql = (__hip_bfloat16*)(off_p + 6*M1);
    __hip_bfloat16* at_kh = (__hip_bfloat16*)(off_p + 8*M1);
    __hip_bfloat16* at_kl = (__hip_bfloat16*)(off_p + 10*M1);
    __hip_bfloat16* at_vh = (__hip_bfloat16*)(off_p + 12*M1);
    __hip_bfloat16* at_vl = (__hip_bfloat16*)(off_p + 14*M1);
    // projection weight splits live past attention (Wd used after) — separate region
    __hip_bfloat16* wq_h = (__hip_bfloat16*)(off_p + 16*M1);
    __hip_bfloat16* wq_l = (__hip_bfloat16*)(off_p + 16*M1 + HM);
    __hip_bfloat16* wk_h = (__hip_bfloat16*)(off_p + 17*M1);
    __hip_bfloat16* wk_l = (__hip_bfloat16*)(off_p + 17*M1 + HM);
    __hip_bfloat16* wv_h = (__hip_bfloat16*)(off_p + 18*M1);
    __hip_bfloat16* wv_l = (__hip_bfloat16*)(off_p + 18*M1 + HM);
    __hip_bfloat16* wd_h = (__hip_bfloat16*)(off_p + 19*M1);
    __hip_bfloat16* wd_l = (__hip_bfloat16*)(off_p + 19*M1 + HM);

    // MoE weight region aliases the attn-split region (dead by MoE time)
    float* wreg = off_p + 4*M1;
    const bool FULL = ws_size >= (size_t)300*1024*1024;

    dim3 blk(256);

    // split x; transpose+split projection weights
    split_bf16<<<(T_*H_/4)/256, blk, 0, stream>>>(x, xa_hi, xa_lo, T_*H_/4);
    transpose_split_bf16<<<dim3(16,16), blk, 0, stream>>>(Wq, wq_h, wq_l, H_, H_);
    transpose_split_bf16<<<dim3(16,16), blk, 0, stream>>>(Wk, wk_h, wk_l, H_, H_);
    transpose_split_bf16<<<dim3(16,16), blk, 0, stream>>>(Wv, wv_h, wv_l, H_, H_);
    transpose_split_bf16<<<dim3(16,16), blk, 0, stream>>>(Wd, wd_h, wd_l, H_, H_);

    // QKV projections (bf16x3 MFMA)
    gemm_bf16x3<false><<<dim3(H_/128, T_/128), blk, 0, stream>>>(xa_hi, xa_lo, wq_h, wq_l, qb, nullptr, H_, H_);
    gemm_bf16x3<false><<<dim3(H_/128, T_/128), blk, 0, stream>>>(xa_hi, xa_lo, wk_h, wk_l, kb, nullptr, H_, H_);
    gemm_bf16x3<false><<<dim3(H_/128, T_/128), blk, 0, stream>>>(xa_hi, xa_lo, wv_h, wv_l, vb, nullptr, H_, H_);

    // RoPE + split q,k ; transpose + split v
    rope_split_kernel<<<(T_*NH_*32)/256, blk, 0, stream>>>(qb, kb, at_qh, at_ql, at_kh, at_kl);
    vsplit_t_kernel<<<dim3(S_/64, NH_, B_), blk, 0, stream>>>(vb, at_vh, at_vl);

    attn_mfma<<<dim3(S_/64, NH_, B_), blk, 0, stream>>>(at_qh, at_ql, at_kh, at_kl, at_vh, at_vl, ctxb);

    // attn_out = ctx@Wd + bd (bf16x3)
    split_bf16<<<(T_*H_/4)/256, blk, 0, stream>>>(ctxb, xa_hi, xa_lo, T_*H_/4);
    gemm_bf16x3<true><<<dim3(H_/128, T_/128), blk, 0, stream>>>(xa_hi, xa_lo, wd_h, wd_l, qb, bd, H_, H_);

    zero_kernel<<<(T_*H_)/256, blk, 0, stream>>>(vb, T_*H_);
    zero_kernel<<<1, blk, 0, stream>>>(misc + 34816, 16);

    ln_kernel<<<T_, blk, 0, stream>>>(qb, x, ln1g, ln1b, kb, hs_b);

    router_kernel<<<T_/64, blk, 0, stream>>>(kb, Wg, tok_e, tok_w, counts, P_sum);
    router_finalize<<<1, blk, 0, stream>>>(counts, P_sum, basep, cursor, cnt_pad, ntiles,
                                           slot_tok, tile_ex, out + (size_t)T_*H_);
    scatter_slots<<<T_/256, blk, 0, stream>>>(tok_e, tok_w, basep, cursor, slot_tok, slot_w);

    if (FULL) {
        __hip_bfloat16* W1t = (__hip_bfloat16*)wreg;
        __hip_bfloat16* W2t = (__hip_bfloat16*)(wreg + 16*M1);
        __hip_bfloat16* y1  = (__hip_bfloat16*)(wreg + 32*M1);
        transpose_bf16<<<dim3(I_/64, H_/64, E_), blk, 0, stream>>>(W1, W1t, H_, I_);
        transpose_bf16<<<dim3(H_/64, I_/64, E_), blk, 0, stream>>>(W2, W2t, I_, H_);
        moe_mfma<2,false><<<dim3(I_/128, MAXTILES), blk, 0, stream>>>(
            hs_b, W1t, y1, nullptr, slot_tok, slot_w, tile_ex, ntiles, nullptr, I_, H_);
        moe_mfma<3,false><<<dim3(H_/128, MAXTILES), blk, 0, stream>>>(
            y1, W2t, nullptr, vb, slot_tok, slot_w, tile_ex, ntiles, nullptr, H_, I_);
    } else {
        __hip_bfloat16* w1t = (__hip_bfloat16*)wreg;
        __hip_bfloat16* w2t = (__hip_bfloat16*)(wreg + 2*M1);
        __hip_bfloat16* y1  = (__hip_bfloat16*)(wreg + 4*M1);
        for (int e=0; e<E_; ++e) {
            transpose_bf16<<<dim3(I_/64, H_/64, 1), blk, 0, stream>>>(W1 + (size_t)e*H_*I_, w1t, H_, I_);
            moe_mfma<2,true><<<dim3(I_/128, 32), blk, 0, stream>>>(
                hs_b, w1t, y1, nullptr, slot_tok, slot_w, nullptr, cnt_pad+e, basep+e, I_, H_);
            transpose_bf16<<<dim3(H_/64, I_/64, 1), blk, 0, stream>>>(W2 + (size_t)e*I_*H_, w2t, I_, H_);
            moe_mfma<3,true><<<dim3(H_/128, 32), blk, 0, stream>>>(
                y1, w2t, nullptr, vb, slot_tok, slot_w, nullptr, cnt_pad+e, basep+e, H_, I_);
        }
    }

    ln_kernel<<<T_, blk, 0, stream>>>(vb, kb, ln2g, ln2b, out, nullptr);
}

// Round 7
// 879.556 us; speedup vs baseline: 6.8752x; 1.0054x over previous
//
#include <hip/hip_runtime.h>
#include <hip/hip_bf16.h>
#include <math.h>

#define H_ 1024
#define NH_ 16
#define HD_ 64
#define I_ 4096
#define E_ 8
#define B_ 2
#define S_ 2048
#define T_ 4096

#define MAXSLOTS 9216   // 2*T + 8*128 pad
#define MAXTILES 72     // MAXSLOTS/128

typedef __attribute__((ext_vector_type(8))) short short8v;
typedef __attribute__((ext_vector_type(4))) float f32x4;

#define GLOAD16(g, l) __builtin_amdgcn_global_load_lds((const __attribute__((address_space(1))) void*)(g), (__attribute__((address_space(3))) void*)(l), 16, 0, 0)

static __device__ inline unsigned short f2bf(float x) {
    __hip_bfloat16 h = __float2bfloat16(x);
    unsigned short u;
    __builtin_memcpy(&u, &h, 2);
    return u;
}
static __device__ inline float bf2f(unsigned short u) {
    __hip_bfloat16 h;
    __builtin_memcpy(&h, &u, 2);
    return __bfloat162float(h);
}

// ---------------- zero ----------------
__global__ void zero_kernel(float* __restrict__ p, int n) {
    int i = blockIdx.x * blockDim.x + threadIdx.x;
    if (i < n) p[i] = 0.f;
}

// ---------------- fp32 -> bf16 hi/lo split (elementwise) ----------------
__global__ __launch_bounds__(256) void split_bf16(
    const float* __restrict__ in, __hip_bfloat16* __restrict__ hi,
    __hip_bfloat16* __restrict__ lo, int n4)
{
    int i = blockIdx.x * blockDim.x + threadIdx.x;
    if (i >= n4) return;
    float4 v = ((const float4*)in)[i];
    unsigned short h0 = f2bf(v.x), h1 = f2bf(v.y), h2 = f2bf(v.z), h3 = f2bf(v.w);
    unsigned short l0 = f2bf(v.x - bf2f(h0)), l1 = f2bf(v.y - bf2f(h1));
    unsigned short l2 = f2bf(v.z - bf2f(h2)), l3 = f2bf(v.w - bf2f(h3));
    uint2 ph = make_uint2((unsigned)h0 | ((unsigned)h1 << 16), (unsigned)h2 | ((unsigned)h3 << 16));
    uint2 pl = make_uint2((unsigned)l0 | ((unsigned)l1 << 16), (unsigned)l2 | ((unsigned)l3 << 16));
    *(uint2*)((char*)hi + (size_t)i*8) = ph;
    *(uint2*)((char*)lo + (size_t)i*8) = pl;
}

// ---------------- transpose + split: in [K][N] f32 -> hi,lo [N][K] bf16 (vectorized) ----------------
__global__ __launch_bounds__(256) void transpose_split_bf16(
    const float* __restrict__ in, __hip_bfloat16* __restrict__ oh,
    __hip_bfloat16* __restrict__ ol, int K, int N)
{
    __shared__ float t[64][65];
    int k0 = blockIdx.y*64, n0 = blockIdx.x*64;
    int tid = threadIdx.x;
    #pragma unroll
    for (int it=0; it<4; ++it) {
        int lin = it*256 + tid;
        int r = lin >> 4, c4 = (lin & 15) << 2;
        float4 v = *(const float4*)&in[(size_t)(k0+r)*N + n0 + c4];
        t[r][c4] = v.x; t[r][c4+1] = v.y; t[r][c4+2] = v.z; t[r][c4+3] = v.w;
    }
    __syncthreads();
    #pragma unroll
    for (int it=0; it<4; ++it) {
        int lin = it*256 + tid;
        int r = lin >> 4, c4 = (lin & 15) << 2;   // r = n-local, c4 = k-local
        float v0 = t[c4][r], v1 = t[c4+1][r], v2 = t[c4+2][r], v3 = t[c4+3][r];
        ushort4 hh, ll;
        hh.x = f2bf(v0); hh.y = f2bf(v1); hh.z = f2bf(v2); hh.w = f2bf(v3);
        ll.x = f2bf(v0 - bf2f(hh.x)); ll.y = f2bf(v1 - bf2f(hh.y));
        ll.z = f2bf(v2 - bf2f(hh.z)); ll.w = f2bf(v3 - bf2f(hh.w));
        size_t o = (size_t)(n0+r)*K + k0 + c4;
        *(ushort4*)&oh[o] = hh;
        *(ushort4*)&ol[o] = ll;
    }
}

// ---------------- transpose + f32->bf16: in [K][N] -> out [N][K] (vectorized) ----------------
__global__ __launch_bounds__(256) void transpose_bf16(
    const float* __restrict__ in, __hip_bfloat16* __restrict__ outp, int K, int N)
{
    __shared__ float t[64][65];
    size_t eoff = (size_t)blockIdx.z * (size_t)K * (size_t)N;
    int k0 = blockIdx.y*64, n0 = blockIdx.x*64;
    int tid = threadIdx.x;
    #pragma unroll
    for (int it=0; it<4; ++it) {
        int lin = it*256 + tid;
        int r = lin >> 4, c4 = (lin & 15) << 2;
        float4 v = *(const float4*)&in[eoff + (size_t)(k0+r)*N + n0 + c4];
        t[r][c4] = v.x; t[r][c4+1] = v.y; t[r][c4+2] = v.z; t[r][c4+3] = v.w;
    }
    __syncthreads();
    #pragma unroll
    for (int it=0; it<4; ++it) {
        int lin = it*256 + tid;
        int r = lin >> 4, c4 = (lin & 15) << 2;
        ushort4 o;
        o.x = f2bf(t[c4][r]);   o.y = f2bf(t[c4+1][r]);
        o.z = f2bf(t[c4+2][r]); o.w = f2bf(t[c4+3][r]);
        *(ushort4*)&outp[eoff + (size_t)(n0+r)*K + k0 + c4] = o;
    }
}

// ---------------- bf16x3 GEMM: C = A@B (+bias), fp32-accurate ----------------
template<bool BIAS>
__global__ __launch_bounds__(256, 2) void gemm_bf16x3(
    const __hip_bfloat16* __restrict__ Ah, const __hip_bfloat16* __restrict__ Al,
    const __hip_bfloat16* __restrict__ Bh, const __hip_bfloat16* __restrict__ Bl,
    float* __restrict__ C, const float* __restrict__ bias, int N, int K)
{
    const int tid = threadIdx.x;
    const int w = tid >> 6, lane = tid & 63;
    const int bx = blockIdx.x, by = blockIdx.y;

    __shared__ __align__(16) char smem[65536];
    const int AH = 0, AL = 16384, BH = 32768, BL = 49152;

    const int laneg = lane >> 3;
    const int k2sw = ((lane & 7) ^ laneg) << 4;
    const int l15 = lane & 15, l4 = lane >> 4;
    const int wr = w >> 1, wc = w & 1;

    f32x4 acc[4][4];
    #pragma unroll
    for (int m=0;m<4;m++)
        #pragma unroll
        for (int n=0;n<4;n++) acc[m][n] = (f32x4){0.f,0.f,0.f,0.f};

    for (int k0 = 0; k0 < K; k0 += 64) {
        __syncthreads();
        #pragma unroll
        for (int qq=0;qq<4;qq++) {
            int arow = by*128 + (w*4+qq)*8 + laneg;
            int brow = bx*128 + (w*4+qq)*8 + laneg;
            size_t aoff = ((size_t)arow*K + k0)*2 + k2sw;
            size_t boff = ((size_t)brow*K + k0)*2 + k2sw;
            GLOAD16((const char*)Ah + aoff, smem + AH + (w*4+qq)*1024);
            GLOAD16((const char*)Al + aoff, smem + AL + (w*4+qq)*1024);
            GLOAD16((const char*)Bh + boff, smem + BH + (w*4+qq)*1024);
            GLOAD16((const char*)Bl + boff, smem + BL + (w*4+qq)*1024);
        }
        __syncthreads();

        short8v ahf[4][2], alf[4][2], bhf[4][2], blf[4][2];
        #pragma unroll
        for (int m=0;m<4;m++) {
            int row = wr*64 + m*16 + l15;
            int rb = row << 7, rsw = (row & 7) << 4;
            #pragma unroll
            for (int s=0;s<2;s++) {
                int off = rb + ((s*64 + (l4<<4)) ^ rsw);
                ahf[m][s] = *(const short8v*)(smem + AH + off);
                alf[m][s] = *(const short8v*)(smem + AL + off);
            }
        }
        #pragma unroll
        for (int n=0;n<4;n++) {
            int row = wc*64 + n*16 + l15;
            int rb = row << 7, rsw = (row & 7) << 4;
            #pragma unroll
            for (int s=0;s<2;s++) {
                int off = rb + ((s*64 + (l4<<4)) ^ rsw);
                bhf[n][s] = *(const short8v*)(smem + BH + off);
                blf[n][s] = *(const short8v*)(smem + BL + off);
            }
        }
        #pragma unroll
        for (int m=0;m<4;m++)
            #pragma unroll
            for (int n=0;n<4;n++)
                #pragma unroll
                for (int s=0;s<2;s++) {
                    acc[m][n] = __builtin_amdgcn_mfma_f32_16x16x32_bf16(ahf[m][s], bhf[n][s], acc[m][n], 0, 0, 0);
                    acc[m][n] = __builtin_amdgcn_mfma_f32_16x16x32_bf16(ahf[m][s], blf[n][s], acc[m][n], 0, 0, 0);
                    acc[m][n] = __builtin_amdgcn_mfma_f32_16x16x32_bf16(alf[m][s], bhf[n][s], acc[m][n], 0, 0, 0);
                }
    }

    #pragma unroll
    for (int m=0;m<4;m++)
        #pragma unroll
        for (int j=0;j<4;j++) {
            int orow = by*128 + wr*64 + m*16 + l4*4 + j;
            #pragma unroll
            for (int n=0;n<4;n++) {
                int ocol = bx*128 + wc*64 + n*16 + l15;
                float v = acc[m][n][j];
                if (BIAS) v += bias[ocol];
                C[(size_t)orow*N + ocol] = v;
            }
        }
}

// ---------------- MFMA MoE GEMM (unchanged, verified) ----------------
template<int MODE, bool PE>
__global__ __launch_bounds__(256) void moe_mfma(
    const __hip_bfloat16* __restrict__ A,
    const __hip_bfloat16* __restrict__ Bt,
    __hip_bfloat16* __restrict__ y1,
    float* __restrict__ moe_out,
    const int* __restrict__ slot_token,
    const float* __restrict__ slot_w,
    const int* __restrict__ tile_expert,
    const int* __restrict__ cnt_ptr,
    const int* __restrict__ base_ptr,
    int N, int K)
{
    const int tid = threadIdx.x;
    const int w = tid >> 6, lane = tid & 63;
    const int bx = blockIdx.x;

    int slot0, y1row0;
    const __hip_bfloat16* Bp;
    if (PE) {
        int tloc = blockIdx.y;
        if ((tloc << 7) >= *cnt_ptr) return;
        slot0 = *base_ptr + (tloc << 7);
        y1row0 = tloc << 7;
        Bp = Bt;
    } else {
        int gt = blockIdx.y;
        if (gt >= *cnt_ptr) return;
        int e = tile_expert[gt];
        Bp = Bt + (size_t)e * (size_t)K * (size_t)N;
        slot0 = gt << 7;
        y1row0 = gt << 7;
    }

    __shared__ __align__(16) char smem[32768];

    const int laneg = lane >> 3;
    const int k2sw = ((lane & 7) ^ laneg) << 4;

    int tokq[4];
    if (MODE == 2) {
        #pragma unroll
        for (int qq=0;qq<4;qq++) {
            int t0 = slot_token[slot0 + (w*4+qq)*8 + laneg];
            tokq[qq] = t0 < 0 ? 0 : t0;
        }
    }

    f32x4 acc[4][4];
    #pragma unroll
    for (int m=0;m<4;m++)
        #pragma unroll
        for (int n=0;n<4;n++) acc[m][n] = (f32x4){0.f,0.f,0.f,0.f};

    const int l15 = lane & 15;
    const int l4  = lane >> 4;
    const int wr = w >> 1, wc = w & 1;

    for (int k0 = 0; k0 < K; k0 += 64) {
        __syncthreads();
        #pragma unroll
        for (int qq=0;qq<4;qq++) {
            const char* ga;
            if (MODE == 2) {
                ga = (const char*)A + (((size_t)tokq[qq])*K + k0)*2 + k2sw;
            } else {
                int row = y1row0 + (w*4+qq)*8 + laneg;
                ga = (const char*)A + ((size_t)row*K + k0)*2 + k2sw;
            }
            GLOAD16(ga, smem + (w*4+qq)*1024);
        }
        #pragma unroll
        for (int qq=0;qq<4;qq++) {
            int row = bx*128 + (w*4+qq)*8 + laneg;
            const char* gb = (const char*)Bp + ((size_t)row*K + k0)*2 + k2sw;
            GLOAD16(gb, smem + 16384 + (w*4+qq)*1024);
        }
        __syncthreads();

        short8v a_frag[4][2], b_frag[4][2];
        #pragma unroll
        for (int m=0;m<4;m++) {
            int row = wr*64 + m*16 + l15;
            int rb = row << 7;
            #pragma unroll
            for (int s=0;s<2;s++) {
                int off = rb + ((s*64 + (l4<<4)) ^ ((row&7)<<4));
                a_frag[m][s] = *(const short8v*)(smem + off);
            }
        }
        #pragma unroll
        for (int n=0;n<4;n++) {
            int row = wc*64 + n*16 + l15;
            int rb = row << 7;
            #pragma unroll
            for (int s=0;s<2;s++) {
                int off = rb + ((s*64 + (l4<<4)) ^ ((row&7)<<4));
                b_frag[n][s] = *(const short8v*)(smem + 16384 + off);
            }
        }
        #pragma unroll
        for (int m=0;m<4;m++)
            #pragma unroll
            for (int n=0;n<4;n++) {
                acc[m][n] = __builtin_amdgcn_mfma_f32_16x16x32_bf16(a_frag[m][0], b_frag[n][0], acc[m][n], 0, 0, 0);
                acc[m][n] = __builtin_amdgcn_mfma_f32_16x16x32_bf16(a_frag[m][1], b_frag[n][1], acc[m][n], 0, 0, 0);
            }
    }

    #pragma unroll
    for (int m=0;m<4;m++) {
        #pragma unroll
        for (int j=0;j<4;j++) {
            int orow = wr*64 + m*16 + l4*4 + j;
            if (MODE == 3) {
                int slot = slot0 + orow;
                int tok = slot_token[slot];
                if (tok < 0) continue;
                float sw = slot_w[slot];
                #pragma unroll
                for (int n=0;n<4;n++) {
                    int ocol = bx*128 + wc*64 + n*16 + l15;
                    atomicAdd(&moe_out[(size_t)tok*H_ + ocol], sw * acc[m][n][j]);
                }
            } else {
                #pragma unroll
                for (int n=0;n<4;n++) {
                    int ocol = bx*128 + wc*64 + n*16 + l15;
                    float val = acc[m][n][j];
                    float g = 0.5f*val*(1.f + erff(val*0.70710678118654752f));
                    y1[(size_t)(y1row0 + orow)*N + ocol] = __float2bfloat16(g);
                }
            }
        }
    }
}

// ---------------- RoPE + split: fp32 q,k -> rotated bf16 hi/lo, head-major ----------------
__global__ void rope_split_kernel(
    const float* __restrict__ q, const float* __restrict__ k,
    __hip_bfloat16* __restrict__ qh, __hip_bfloat16* __restrict__ ql,
    __hip_bfloat16* __restrict__ kh, __hip_bfloat16* __restrict__ kl)
{
    int idx = blockIdx.x * blockDim.x + threadIdx.x;  // T*NH*32
    int i = idx & 31;
    int n = (idx >> 5) & (NH_-1);
    int t = idx >> 9;
    int b = t >> 11;
    int pos = t & (S_ - 1);
    float inv = exp2f((float)i * (-13.287712379549449f / 32.f));
    float ang = (float)pos * inv;
    float c = cosf(ang), s = sinf(ang);
    size_t base = (size_t)t*H_ + (size_t)n*64;
    size_t obase = ((size_t)(b*NH_ + n)*S_ + pos)*64;

    float q1 = q[base+i], q2 = q[base+i+32];
    float qo1 = (q1*c - q2*s)*0.125f;
    float qo2 = (q2*c + q1*s)*0.125f;
    unsigned short h1 = f2bf(qo1), h2 = f2bf(qo2);
    qh[obase+i]    = *(__hip_bfloat16*)&h1;
    qh[obase+i+32] = *(__hip_bfloat16*)&h2;
    unsigned short lo1 = f2bf(qo1 - bf2f(h1)), lo2 = f2bf(qo2 - bf2f(h2));
    ql[obase+i]    = *(__hip_bfloat16*)&lo1;
    ql[obase+i+32] = *(__hip_bfloat16*)&lo2;

    float k1 = k[base+i], k2 = k[base+i+32];
    float ko1 = k1*c - k2*s;
    float ko2 = k2*c + k1*s;
    unsigned short kh1 = f2bf(ko1), kh2 = f2bf(ko2);
    kh[obase+i]    = *(__hip_bfloat16*)&kh1;
    kh[obase+i+32] = *(__hip_bfloat16*)&kh2;
    unsigned short kl1 = f2bf(ko1 - bf2f(kh1)), kl2 = f2bf(ko2 - bf2f(kh2));
    kl[obase+i]    = *(__hip_bfloat16*)&kl1;
    kl[obase+i+32] = *(__hip_bfloat16*)&kl2;
}

// ---------------- V transpose + split ----------------
__global__ __launch_bounds__(256) void vsplit_t_kernel(
    const float* __restrict__ v,
    __hip_bfloat16* __restrict__ vth, __hip_bfloat16* __restrict__ vtl)
{
    __shared__ float t[64][65];
    const int s0 = blockIdx.x*64;
    const int hn = blockIdx.y;
    const int b  = blockIdx.z;
    const int tid = threadIdx.x;
    #pragma unroll
    for (int it=0; it<4; ++it) {
        int lin = it*256 + tid;
        int r = lin >> 4, c4 = (lin & 15) << 2;
        float4 vv = *(const float4*)&v[(size_t)(b*S_ + s0 + r)*H_ + hn*64 + c4];
        t[r][c4] = vv.x; t[r][c4+1] = vv.y; t[r][c4+2] = vv.z; t[r][c4+3] = vv.w;
    }
    __syncthreads();
    size_t obase = (size_t)(b*NH_ + hn)*64*S_;
    #pragma unroll
    for (int it=0; it<4; ++it) {
        int lin = it*256 + tid;
        int d = lin >> 4, c4 = (lin & 15) << 2;   // d = dim, c4 = seq-local
        float v0 = t[c4][d], v1 = t[c4+1][d], v2 = t[c4+2][d], v3 = t[c4+3][d];
        ushort4 hh, ll;
        hh.x = f2bf(v0); hh.y = f2bf(v1); hh.z = f2bf(v2); hh.w = f2bf(v3);
        ll.x = f2bf(v0 - bf2f(hh.x)); ll.y = f2bf(v1 - bf2f(hh.y));
        ll.z = f2bf(v2 - bf2f(hh.z)); ll.w = f2bf(v3 - bf2f(hh.w));
        size_t o = obase + (size_t)d*S_ + s0 + c4;
        *(ushort4*)&vth[o] = hh;
        *(ushort4*)&vtl[o] = ll;
    }
}

// ---------------- MFMA attention: bf16x3, XCD-swizzled grid ----------------
// 1D grid of 1024: xcd = wg&7 gets 4 consecutive heads (K/V stays in that XCD's L2).
__global__ __launch_bounds__(256, 3) void attn_mfma(
    const __hip_bfloat16* __restrict__ qh, const __hip_bfloat16* __restrict__ ql,
    const __hip_bfloat16* __restrict__ kh, const __hip_bfloat16* __restrict__ kl,
    const __hip_bfloat16* __restrict__ vth, const __hip_bfloat16* __restrict__ vtl,
    float* __restrict__ ctx)
{
    const int wg = blockIdx.x;
    const int xcd = wg & 7;
    const int ix = wg >> 3;               // 0..127
    const int head = xcd*4 + (ix >> 5);   // 32 heads, 4 per XCD
    const int qt = ix & 31;
    const int b = head >> 4, hn = head & 15;

    const int tid = threadIdx.x;
    const int w = tid >> 6, lane = tid & 63;
    const int l15 = lane & 15, l4 = lane >> 4;
    const int laneg = lane >> 3;
    const int k2sw = ((lane & 7) ^ laneg) << 4;

    __shared__ __align__(16) char smem[49152];
    const int KHo = 0, KLo = 8192, VHo = 16384, VLo = 24576, PHo = 32768, PLo = 40960;

    const size_t kbase = (size_t)head*S_*64;
    const size_t vbase = (size_t)head*64*S_;

    // ---- prologue: stage Q tile into P region, read frags ----
    #pragma unroll
    for (int qq=0;qq<2;qq++) {
        int c = w*2 + qq;
        int row = qt*64 + c*8 + laneg;
        size_t off = (kbase + (size_t)row*64)*2 + k2sw;
        GLOAD16((const char*)qh + off, smem + PHo + c*1024);
        GLOAD16((const char*)ql + off, smem + PLo + c*1024);
    }
    __syncthreads();
    short8v qhf[2], qlf[2];
    {
        int row = w*16 + l15;
        int rsw = (row & 7) << 4;
        #pragma unroll
        for (int s=0;s<2;s++) {
            int off = row*128 + ((s*64 + l4*16) ^ rsw);
            qhf[s] = *(const short8v*)(smem + PHo + off);
            qlf[s] = *(const short8v*)(smem + PLo + off);
        }
    }

    f32x4 acc[4];
    #pragma unroll
    for (int db=0;db<4;db++) acc[db] = (f32x4){0.f,0.f,0.f,0.f};
    float mrun[4], lrun[4];
    #pragma unroll
    for (int j=0;j<4;j++) { mrun[j] = -1e30f; lrun[j] = 0.f; }

    for (int kt=0; kt<S_/64; ++kt) {
        __syncthreads();
        #pragma unroll
        for (int qq=0;qq<2;qq++) {
            int c = w*2 + qq;
            int r8 = c*8 + laneg;
            size_t koff = (kbase + (size_t)(kt*64 + r8)*64)*2 + k2sw;
            GLOAD16((const char*)kh + koff, smem + KHo + c*1024);
            GLOAD16((const char*)kl + koff, smem + KLo + c*1024);
            size_t voff = (vbase + (size_t)r8*S_ + kt*64)*2 + k2sw;
            GLOAD16((const char*)vth + voff, smem + VHo + c*1024);
            GLOAD16((const char*)vtl + voff, smem + VLo + c*1024);
        }
        __syncthreads();

        // ---- QK^T (3-term split) ----
        f32x4 s_acc[4];
        #pragma unroll
        for (int cb=0;cb<4;cb++) {
            s_acc[cb] = (f32x4){0.f,0.f,0.f,0.f};
            int row = cb*16 + l15;
            int rsw = (row & 7) << 4;
            #pragma unroll
            for (int s=0;s<2;s++) {
                int off = row*128 + ((s*64 + l4*16) ^ rsw);
                short8v khf = *(const short8v*)(smem + KHo + off);
                short8v klf = *(const short8v*)(smem + KLo + off);
                s_acc[cb] = __builtin_amdgcn_mfma_f32_16x16x32_bf16(qhf[s], khf, s_acc[cb], 0, 0, 0);
                s_acc[cb] = __builtin_amdgcn_mfma_f32_16x16x32_bf16(qhf[s], klf, s_acc[cb], 0, 0, 0);
                s_acc[cb] = __builtin_amdgcn_mfma_f32_16x16x32_bf16(qlf[s], khf, s_acc[cb], 0, 0, 0);
            }
        }

        // ---- online softmax ----
        float mnew[4], alpha[4];
        #pragma unroll
        for (int j=0;j<4;j++) {
            float mt = fmaxf(fmaxf(s_acc[0][j], s_acc[1][j]), fmaxf(s_acc[2][j], s_acc[3][j]));
            #pragma unroll
            for (int m=8;m;m>>=1) mt = fmaxf(mt, __shfl_xor(mt, m));
            float mn = fmaxf(mrun[j], mt);
            mnew[j] = mn;
            alpha[j] = __expf(mrun[j] - mn);
            mrun[j] = mn;
        }
        float pv[4][4];
        float ps[4] = {0.f,0.f,0.f,0.f};
        #pragma unroll
        for (int cb=0;cb<4;cb++)
            #pragma unroll
            for (int j=0;j<4;j++) {
                float p = __expf(s_acc[cb][j] - mnew[j]);
                pv[cb][j] = p;
                ps[j] += p;
            }
        #pragma unroll
        for (int j=0;j<4;j++) {
            float s = ps[j];
            #pragma unroll
            for (int m=8;m;m>>=1) s += __shfl_xor(s, m);
            lrun[j] = lrun[j]*alpha[j] + s;
        }

        // ---- split P -> wave-private LDS rows ----
        #pragma unroll
        for (int cb=0;cb<4;cb++)
            #pragma unroll
            for (int j=0;j<4;j++) {
                int prow = w*16 + l4*4 + j;
                unsigned short hh = f2bf(pv[cb][j]);
                unsigned short ll = f2bf(pv[cb][j] - bf2f(hh));
                int off = prow*128 + (((cb*16 + l15)*2) ^ ((prow&7)<<4));
                *(unsigned short*)(smem + PHo + off) = hh;
                *(unsigned short*)(smem + PLo + off) = ll;
            }
        asm volatile("s_waitcnt lgkmcnt(0)" ::: "memory");
        __builtin_amdgcn_sched_barrier(0);

        // ---- rescale ctx acc ----
        #pragma unroll
        for (int db=0;db<4;db++)
            #pragma unroll
            for (int j=0;j<4;j++) acc[db][j] *= alpha[j];

        // ---- PV (3-term split) ----
        short8v pah[2], pal[2];
        {
            int row = w*16 + l15;
            int rsw = (row & 7) << 4;
            #pragma unroll
            for (int s=0;s<2;s++) {
                int off = row*128 + ((s*64 + l4*16) ^ rsw);
                pah[s] = *(const short8v*)(smem + PHo + off);
                pal[s] = *(const short8v*)(smem + PLo + off);
            }
        }
        #pragma unroll
        for (int db=0;db<4;db++) {
            int row = db*16 + l15;
            int rsw = (row & 7) << 4;
            #pragma unroll
            for (int s=0;s<2;s++) {
                int off = row*128 + ((s*64 + l4*16) ^ rsw);
                short8v vhf = *(const short8v*)(smem + VHo + off);
                short8v vlf = *(const short8v*)(smem + VLo + off);
                acc[db] = __builtin_amdgcn_mfma_f32_16x16x32_bf16(pah[s], vhf, acc[db], 0, 0, 0);
                acc[db] = __builtin_amdgcn_mfma_f32_16x16x32_bf16(pah[s], vlf, acc[db], 0, 0, 0);
                acc[db] = __builtin_amdgcn_mfma_f32_16x16x32_bf16(pal[s], vhf, acc[db], 0, 0, 0);
            }
        }
    }

    // ---- epilogue ----
    const size_t headoff = (size_t)b*S_*H_ + (size_t)hn*64;
    #pragma unroll
    for (int db=0;db<4;db++)
        #pragma unroll
        for (int j=0;j<4;j++) {
            int qrow = qt*64 + w*16 + l4*4 + j;
            ctx[headoff + (size_t)qrow*H_ + db*16 + l15] = acc[db][j] / lrun[j];
        }
}

// ---------------- layernorm (residual fused, optional bf16 out) ----------------
__global__ __launch_bounds__(256) void ln_kernel(
    const float* __restrict__ a, const float* __restrict__ res,
    const float* __restrict__ g, const float* __restrict__ beta,
    float* __restrict__ out, __hip_bfloat16* __restrict__ outb)
{
    int row = blockIdx.x, tid = threadIdx.x;
    const float4 va = ((const float4*)(a + (size_t)row*H_))[tid];
    const float4 vr = ((const float4*)(res + (size_t)row*H_))[tid];
    float x0=va.x+vr.x, x1=va.y+vr.y, x2=va.z+vr.z, x3=va.w+vr.w;
    float s  = x0+x1+x2+x3;
    float ss = x0*x0 + x1*x1 + x2*x2 + x3*x3;
    #pragma unroll
    for (int off=32; off; off>>=1) { s += __shfl_xor(s, off); ss += __shfl_xor(ss, off); }
    __shared__ float red[8];
    if ((tid&63)==0) { red[tid>>6]=s; red[4+(tid>>6)]=ss; }
    __syncthreads();
    if (tid==0) { red[0]=red[0]+red[1]+red[2]+red[3]; red[4]=red[4]+red[5]+red[6]+red[7]; }
    __syncthreads();
    float mu  = red[0] * (1.f/H_);
    float var = red[4] * (1.f/H_) - mu*mu;
    float rs = rsqrtf(fmaxf(var, 0.f) + 1e-12f);
    const float4 vg = ((const float4*)g)[tid];
    const float4 vb = ((const float4*)beta)[tid];
    float4 vo;
    vo.x = (x0-mu)*rs*vg.x + vb.x;
    vo.y = (x1-mu)*rs*vg.y + vb.y;
    vo.z = (x2-mu)*rs*vg.z + vb.z;
    vo.w = (x3-mu)*rs*vg.w + vb.w;
    ((float4*)(out + (size_t)row*H_))[tid] = vo;
    if (outb) {
        unsigned int p0 = (unsigned)f2bf(vo.x) | ((unsigned)f2bf(vo.y) << 16);
        unsigned int p1 = (unsigned)f2bf(vo.z) | ((unsigned)f2bf(vo.w) << 16);
        ((uint2*)(outb + (size_t)row*H_))[tid] = make_uint2(p0, p1);
    }
}

// ---------------- router: 64 blocks x 64 tokens, register-accumulated stats ----------------
__global__ __launch_bounds__(256) void router_kernel(
    const float* __restrict__ hs, const float* __restrict__ Wg,
    int* __restrict__ tok_e, float* __restrict__ tok_w,
    int* __restrict__ counts, float* __restrict__ P_sum)
{
    const int w = threadIdx.x >> 6, lane = threadIdx.x & 63;
    float psum[E_];
    int cnt[E_];
    #pragma unroll
    for (int e=0;e<E_;e++){ psum[e]=0.f; cnt[e]=0; }

    for (int it=0; it<16; ++it) {
        int t = blockIdx.x*64 + it*4 + w;
        const float* row = hs + (size_t)t * H_;
        float acc[E_];
        #pragma unroll
        for (int e=0;e<E_;e++) acc[e]=0.f;
        for (int i16=0; i16<16; ++i16) {
            int i = i16*64 + lane;
            float xv = row[i];
            const float* wg = Wg + (size_t)i*E_;
            #pragma unroll
            for (int e=0;e<E_;e++) acc[e] = fmaf(xv, wg[e], acc[e]);
        }
        #pragma unroll
        for (int e=0;e<E_;e++) {
            float vv = acc[e];
            #pragma unroll
            for (int off=32; off; off>>=1) vv += __shfl_xor(vv, off);
            acc[e] = vv;
        }
        float mx = acc[0];
        #pragma unroll
        for (int e=1;e<E_;e++) mx = fmaxf(mx, acc[e]);
        float p[E_], se=0.f;
        #pragma unroll
        for (int e=0;e<E_;e++){ p[e] = __expf(acc[e]-mx); se += p[e]; }
        float isv = 1.f/se;
        #pragma unroll
        for (int e=0;e<E_;e++){ p[e]*=isv; psum[e] += p[e]; }
        int e1=0;
        #pragma unroll
        for (int e=1;e<E_;e++) if (p[e] > p[e1]) e1=e;
        int e2 = (e1==0)?1:0;
        #pragma unroll
        for (int e=0;e<E_;e++) if (e!=e1 && p[e] > p[e2]) e2=e;
        #pragma unroll
        for (int e=0;e<E_;e++) cnt[e] += (e==e1?1:0) + (e==e2?1:0);
        if (lane==0) {
            float w1=p[e1], w2=p[e2], si=1.f/(w1+w2);
            tok_e[t*2]=e1; tok_e[t*2+1]=e2;
            tok_w[t*2]=w1*si; tok_w[t*2+1]=w2*si;
        }
    }
    if (lane==0) {
        #pragma unroll
        for (int e=0;e<E_;e++) {
            atomicAdd(&P_sum[e], psum[e]);
            atomicAdd(&counts[e], cnt[e]);
        }
    }
}

__global__ void router_finalize(
    const int* __restrict__ counts, const float* __restrict__ P_sum,
    int* __restrict__ base, int* __restrict__ cursor,
    int* __restrict__ cnt_pad, int* __restrict__ ntiles,
    int* __restrict__ slot_token, int* __restrict__ tile_expert,
    float* __restrict__ aux_out)
{
    __shared__ int sbase[E_+1];
    if (threadIdx.x == 0) {
        int bacc = 0;
        float aux = 0.f;
        for (int e=0;e<E_;e++) {
            sbase[e] = bacc; base[e] = bacc;
            int cp = (counts[e] + 127) & ~127;
            cnt_pad[e] = cp;
            bacc += cp;
            cursor[e] = 0;
            aux += ((float)counts[e]/(float)T_) * (P_sum[e]/(float)T_);
        }
        sbase[E_] = bacc;
        *ntiles = bacc >> 7;
        *aux_out = (float)E_ * aux;
    }
    __syncthreads();
    for (int sIdx = (int)threadIdx.x; sIdx < MAXSLOTS; sIdx += (int)blockDim.x)
        slot_token[sIdx] = -1;
    for (int tt = (int)threadIdx.x; tt < MAXTILES; tt += (int)blockDim.x) {
        int s = tt*128;
        int e = E_-1;
        for (int qe=0; qe<E_; ++qe) if (s < sbase[qe+1]) { e = qe; break; }
        tile_expert[tt] = e;
    }
}

__global__ void scatter_slots(
    const int* __restrict__ tok_e, const float* __restrict__ tok_w,
    const int* __restrict__ base, int* __restrict__ cursor,
    int* __restrict__ slot_token, float* __restrict__ slot_w)
{
    int t = blockIdx.x*blockDim.x + threadIdx.x;
    if (t >= T_) return;
    #pragma unroll
    for (int j=0;j<2;j++) {
        int e = tok_e[t*2+j];
        int pos = atomicAdd(&cursor[e], 1);
        int s = base[e] + pos;
        slot_token[s] = t;
        slot_w[s] = tok_w[t*2+j];
    }
}

extern "C" void kernel_launch(void* const* d_in, const int* in_sizes, int n_in,
                              void* d_out, int out_size, void* d_ws, size_t ws_size,
                              hipStream_t stream)
{
    const float* x    = (const float*)d_in[0];
    const float* Wq   = (const float*)d_in[1];
    const float* Wk   = (const float*)d_in[2];
    const float* Wv   = (const float*)d_in[3];
    const float* Wd   = (const float*)d_in[4];
    const float* bd   = (const float*)d_in[5];
    const float* ln1g = (const float*)d_in[6];
    const float* ln1b = (const float*)d_in[7];
    const float* Wg   = (const float*)d_in[8];
    const float* W1   = (const float*)d_in[9];
    const float* W2   = (const float*)d_in[10];
    const float* ln2g = (const float*)d_in[11];
    const float* ln2b = (const float*)d_in[12];
    float* out = (float*)d_out;

    float* f0 = (float*)d_ws;
    const size_t M1 = 1u << 20;
    float* qb   = f0;            // q -> attn_out
    float* kb   = f0 + 4*M1;     // k -> hs
    float* vb   = f0 + 8*M1;     // v -> moe_out
    float* ctxb = f0 + 12*M1;
    __hip_bfloat16* hs_b = (__hip_bfloat16*)(f0 + 16*M1);

    float* misc = f0 + 18*M1;
    int*   misc_i = (int*)misc;
    int*   tok_e   = misc_i;
    float* tok_w   = misc + 8192;
    int*   slot_tok= misc_i + 16384;
    float* slot_w  = misc + 25600;
    int*   counts  = misc_i + 34816;
    float* P_sum   = misc + 34824;
    int*   cursor  = misc_i + 34832;
    int*   basep   = misc_i + 34840;
    int*   cnt_pad = misc_i + 34848;
    int*   ntiles  = misc_i + 34856;
    int*   tile_ex = misc_i + 34857;

    float* off_p = f0 + 18*M1 + 65536;
    __hip_bfloat16* xa_hi = (__hip_bfloat16*)(off_p);
    __hip_bfloat16* xa_lo = (__hip_bfloat16*)(off_p + 2*M1);
    const size_t HM = M1/2;
    __hip_bfloat16* at_qh = (__hip_bfloat16*)(off_p + 4*M1);
    __hip_bfloat16* at_ql = (__hip_bfloat16*)(off_p + 6*M1);
    __hip_bfloat16* at_kh = (__hip_bfloat16*)(off_p + 8*M1);
    __hip_bfloat16* at_kl = (__hip_bfloat16*)(off_p + 10*M1);
    __hip_bfloat16* at_vh = (__hip_bfloat16*)(off_p + 12*M1);
    __hip_bfloat16* at_vl = (__hip_bfloat16*)(off_p + 14*M1);
    __hip_bfloat16* wq_h = (__hip_bfloat16*)(off_p + 16*M1);
    __hip_bfloat16* wq_l = (__hip_bfloat16*)(off_p + 16*M1 + HM);
    __hip_bfloat16* wk_h = (__hip_bfloat16*)(off_p + 17*M1);
    __hip_bfloat16* wk_l = (__hip_bfloat16*)(off_p + 17*M1 + HM);
    __hip_bfloat16* wv_h = (__hip_bfloat16*)(off_p + 18*M1);
    __hip_bfloat16* wv_l = (__hip_bfloat16*)(off_p + 18*M1 + HM);
    __hip_bfloat16* wd_h = (__hip_bfloat16*)(off_p + 19*M1);
    __hip_bfloat16* wd_l = (__hip_bfloat16*)(off_p + 19*M1 + HM);

    float* wreg = off_p + 4*M1;
    const bool FULL = ws_size >= (size_t)300*1024*1024;

    dim3 blk(256);

    split_bf16<<<(T_*H_/4)/256, blk, 0, stream>>>(x, xa_hi, xa_lo, T_*H_/4);
    transpose_split_bf16<<<dim3(16,16), blk, 0, stream>>>(Wq, wq_h, wq_l, H_, H_);
    transpose_split_bf16<<<dim3(16,16), blk, 0, stream>>>(Wk, wk_h, wk_l, H_, H_);
    transpose_split_bf16<<<dim3(16,16), blk, 0, stream>>>(Wv, wv_h, wv_l, H_, H_);
    transpose_split_bf16<<<dim3(16,16), blk, 0, stream>>>(Wd, wd_h, wd_l, H_, H_);

    gemm_bf16x3<false><<<dim3(H_/128, T_/128), blk, 0, stream>>>(xa_hi, xa_lo, wq_h, wq_l, qb, nullptr, H_, H_);
    gemm_bf16x3<false><<<dim3(H_/128, T_/128), blk, 0, stream>>>(xa_hi, xa_lo, wk_h, wk_l, kb, nullptr, H_, H_);
    gemm_bf16x3<false><<<dim3(H_/128, T_/128), blk, 0, stream>>>(xa_hi, xa_lo, wv_h, wv_l, vb, nullptr, H_, H_);

    rope_split_kernel<<<(T_*NH_*32)/256, blk, 0, stream>>>(qb, kb, at_qh, at_ql, at_kh, at_kl);
    vsplit_t_kernel<<<dim3(S_/64, NH_, B_), blk, 0, stream>>>(vb, at_vh, at_vl);

    attn_mfma<<<dim3(B_*NH_*(S_/64)), blk, 0, stream>>>(at_qh, at_ql, at_kh, at_kl, at_vh, at_vl, ctxb);

    split_bf16<<<(T_*H_/4)/256, blk, 0, stream>>>(ctxb, xa_hi, xa_lo, T_*H_/4);
    gemm_bf16x3<true><<<dim3(H_/128, T_/128), blk, 0, stream>>>(xa_hi, xa_lo, wd_h, wd_l, qb, bd, H_, H_);

    zero_kernel<<<(T_*H_)/256, blk, 0, stream>>>(vb, T_*H_);
    zero_kernel<<<1, blk, 0, stream>>>(misc + 34816, 16);

    ln_kernel<<<T_, blk, 0, stream>>>(qb, x, ln1g, ln1b, kb, hs_b);

    router_kernel<<<T_/64, blk, 0, stream>>>(kb, Wg, tok_e, tok_w, counts, P_sum);
    router_finalize<<<1, blk, 0, stream>>>(counts, P_sum, basep, cursor, cnt_pad, ntiles,
                                           slot_tok, tile_ex, out + (size_t)T_*H_);
    scatter_slots<<<T_/256, blk, 0, stream>>>(tok_e, tok_w, basep, cursor, slot_tok, slot_w);

    if (FULL) {
        __hip_bfloat16* W1t = (__hip_bfloat16*)wreg;
        __hip_bfloat16* W2t = (__hip_bfloat16*)(wreg + 16*M1);
        __hip_bfloat16* y1  = (__hip_bfloat16*)(wreg + 32*M1);
        transpose_bf16<<<dim3(I_/64, H_/64, E_), blk, 0, stream>>>(W1, W1t, H_, I_);
        transpose_bf16<<<dim3(H_/64, I_/64, E_), blk, 0, stream>>>(W2, W2t, I_, H_);
        moe_mfma<2,false><<<dim3(I_/128, MAXTILES), blk, 0, stream>>>(
            hs_b, W1t, y1, nullptr, slot_tok, slot_w, tile_ex, ntiles, nullptr, I_, H_);
        moe_mfma<3,false><<<dim3(H_/128, MAXTILES), blk, 0, stream>>>(
            y1, W2t, nullptr, vb, slot_tok, slot_w, tile_ex, ntiles, nullptr, H_, I_);
    } else {
        __hip_bfloat16* w1t = (__hip_bfloat16*)wreg;
        __hip_bfloat16* w2t = (__hip_bfloat16*)(wreg + 2*M1);
        __hip_bfloat16* y1  = (__hip_bfloat16*)(wreg + 4*M1);
        for (int e=0; e<E_; ++e) {
            transpose_bf16<<<dim3(I_/64, H_/64, 1), blk, 0, stream>>>(W1 + (size_t)e*H_*I_, w1t, H_, I_);
            moe_mfma<2,true><<<dim3(I_/128, 32), blk, 0, stream>>>(
                hs_b, w1t, y1, nullptr, slot_tok, slot_w, nullptr, cnt_pad+e, basep+e, I_, H_);
            transpose_bf16<<<dim3(H_/64, I_/64, 1), blk, 0, stream>>>(W2 + (size_t)e*I_*H_, w2t, I_, H_);
            moe_mfma<3,true><<<dim3(H_/128, 32), blk, 0, stream>>>(
                y1, w2t, nullptr, vb, slot_tok, slot_w, nullptr, cnt_pad+e, basep+e, H_, I_);
        }
    }

    ln_kernel<<<T_, blk, 0, stream>>>(vb, kb, ln2g, ln2b, out, nullptr);
}